// Round 17
// baseline (1190.077 us; speedup 1.0000x reference)
//
#include <hip/hip_runtime.h>
#include <hip/hip_bf16.h>

// Problem constants (from reference source)
#define REGION_R0 42033
#define REGION_R1 44630
#define RN        (REGION_R1 - REGION_R0)   // 2597
#define CH        64
#define KSPLIT    32
#define ROW_TILES ((RN + 31) / 32)          // 82
#define SCAN_B    256

// bucket-partition geometry
#define NB        64                         // range-blocks in pass1/pass2
#define T1        512                        // threads for pass1/pass2
#define BUCKET    64                         // heads per bucket
#define MAXBUK    2048                       // LDS hist/cursor capacity

// MFMA region-gemm geometry
#define KTT       82                         // ceil(RN/32) K-steps
#define KP        (KTT * 32)                 // 2624 padded K
#define PERCHUNK  6
#define KCHUNKS   14                         // ceil(82/6)
#define MT_TILES  163                        // ceil(RN/16)
#define MT_BLKS   41                         // ceil(163/4)

typedef unsigned short ushort_t;
typedef short  bfrag8 __attribute__((ext_vector_type(8)));
typedef float  f32x4v __attribute__((ext_vector_type(4)));

// =========================================================================
// Region blend init (region_ent = 0.8 * orig)
// =========================================================================
__global__ void region_init_kernel(const float* __restrict__ emb,
                                   float* __restrict__ region_ent) {
    const int gid = blockIdx.x * blockDim.x + threadIdx.x;
    if (gid >= RN * CH / 4) return;
    const float4 v = reinterpret_cast<const float4*>(emb + (size_t)REGION_R0 * CH)[gid];
    float4 o;
    o.x = 0.8f * v.x; o.y = 0.8f * v.y; o.z = 0.8f * v.z; o.w = 0.8f * v.w;
    reinterpret_cast<float4*>(region_ent)[gid] = o;
}

__device__ __forceinline__ unsigned pack2bf(float a, float b) {
    unsigned ua = __float_as_uint(a);
    unsigned ub = __float_as_uint(b);
    ua += 0x7fffu + ((ua >> 16) & 1u);   // RNE
    ub += 0x7fffu + ((ub >> 16) & 1u);
    return ((ua >> 16) & 0xffffu) | (ub & 0xffff0000u);
}

// =========================================================================
// e_t[c][k] = bf16(emb[R0+k][c]) (B operand, transposed, zero-padded)
// =========================================================================
__global__ void build_et_kernel(const float* __restrict__ emb,
                                ushort_t* __restrict__ e_t) {
    const int gid = blockIdx.x * blockDim.x + threadIdx.x;
    if (gid >= CH * (KP / 8)) return;
    const int c  = gid / (KP / 8);
    const int k8 = gid - c * (KP / 8);
    const int kb = k8 * 8;
    float v[8];
#pragma unroll
    for (int j = 0; j < 8; ++j) {
        const int k = kb + j;
        v[j] = (k < RN) ? emb[(size_t)(REGION_R0 + k) * CH + c] : 0.0f;
    }
    uint4 o;
    o.x = pack2bf(v[0], v[1]); o.y = pack2bf(v[2], v[3]);
    o.z = pack2bf(v[4], v[5]); o.w = pack2bf(v[6], v[7]);
    *reinterpret_cast<uint4*>(e_t + (size_t)c * KP + kb) = o;
}

// =========================================================================
// MFMA region GEMM (R14-verified, absmax 0.25)
// =========================================================================
__global__ void region_gemm_mfma_kernel(const float* __restrict__ W,
                                        const ushort_t* __restrict__ e_t,
                                        float* __restrict__ region_ent) {
    const int wv    = threadIdx.x >> 6;
    const int lane  = threadIdx.x & 63;
    const int blk_m = blockIdx.x / KCHUNKS;
    const int kc    = blockIdx.x - blk_m * KCHUNKS;
    const int mt    = blk_m * 4 + wv;
    if (mt >= MT_TILES) return;
    const int l15 = lane & 15;
    const int lg  = lane >> 4;

    int arow = mt * 16 + l15;
    if (arow >= RN) arow = RN - 1;
    const float* wrow = W + (size_t)arow * RN;

    const int kt0 = kc * PERCHUNK;
    const int kt1 = (kt0 + PERCHUNK < KTT) ? (kt0 + PERCHUNK) : KTT;

    f32x4v acc[4];
#pragma unroll
    for (int n = 0; n < 4; ++n) acc[n] = (f32x4v){0.f, 0.f, 0.f, 0.f};

    for (int kt = kt0; kt < kt1; ++kt) {
        const int kb = kt * 32 + lg * 8;
        union { uint4 u; bfrag8 f; } A;
        if (kb + 8 <= RN) {
            float v0 = wrow[kb + 0], v1 = wrow[kb + 1];
            float v2 = wrow[kb + 2], v3 = wrow[kb + 3];
            float v4 = wrow[kb + 4], v5 = wrow[kb + 5];
            float v6 = wrow[kb + 6], v7 = wrow[kb + 7];
            A.u.x = pack2bf(v0, v1); A.u.y = pack2bf(v2, v3);
            A.u.z = pack2bf(v4, v5); A.u.w = pack2bf(v6, v7);
        } else {
            float v[8];
#pragma unroll
            for (int j = 0; j < 8; ++j) {
                const int k = kb + j;
                v[j] = (k < RN) ? wrow[k] : 0.0f;
            }
            A.u.x = pack2bf(v[0], v[1]); A.u.y = pack2bf(v[2], v[3]);
            A.u.z = pack2bf(v[4], v[5]); A.u.w = pack2bf(v[6], v[7]);
        }
#pragma unroll
        for (int n = 0; n < 4; ++n) {
            const bfrag8 B = *reinterpret_cast<const bfrag8*>(
                e_t + (size_t)(n * 16 + l15) * KP + kb);
            acc[n] = __builtin_amdgcn_mfma_f32_16x16x32_bf16(A.f, B, acc[n], 0, 0, 0);
        }
    }

#pragma unroll
    for (int n = 0; n < 4; ++n) {
#pragma unroll
        for (int j = 0; j < 4; ++j) {
            const int row = mt * 16 + lg * 4 + j;
            if (row < RN)
                unsafeAtomicAdd(region_ent + (size_t)row * CH + n * 16 + l15,
                                0.2f * acc[n][j]);
        }
    }
}

// =========================================================================
// Old VALU region GEMM (small-ws fallback only)
// =========================================================================
__global__ void region_gemm_kernel(const float* __restrict__ emb,
                                   const float* __restrict__ W,
                                   float* __restrict__ region_ent) {
    const int wave = threadIdx.x >> 6;
    const int c    = threadIdx.x & 63;
    const int rt   = blockIdx.x / KSPLIT;
    const int ks   = blockIdx.x - rt * KSPLIT;
    const int base = rt * 32 + wave * 8;
    if (base >= RN) return;

    const int k0 = (RN * ks) / KSPLIT;
    const int k1 = (RN * (ks + 1)) / KSPLIT;

    const float* wp[8];
#pragma unroll
    for (int r = 0; r < 8; ++r) {
        int row = base + r;
        if (row >= RN) row = RN - 1;
        row = __builtin_amdgcn_readfirstlane(row);
        wp[r] = W + (size_t)row * RN;
    }
    const float* ep = emb + (size_t)REGION_R0 * CH + c;

    float acc[8];
#pragma unroll
    for (int r = 0; r < 8; ++r) acc[r] = 0.0f;

    int k = k0;
    for (; k + 4 <= k1; k += 4) {
        const float e0 = ep[(size_t)(k + 0) * CH];
        const float e1 = ep[(size_t)(k + 1) * CH];
        const float e2 = ep[(size_t)(k + 2) * CH];
        const float e3 = ep[(size_t)(k + 3) * CH];
#pragma unroll
        for (int r = 0; r < 8; ++r) {
            const float* wr = wp[r];
            float a = acc[r];
            a = fmaf(wr[k + 0], e0, a);
            a = fmaf(wr[k + 1], e1, a);
            a = fmaf(wr[k + 2], e2, a);
            a = fmaf(wr[k + 3], e3, a);
            acc[r] = a;
        }
    }
    for (; k < k1; ++k) {
        const float e = ep[(size_t)k * CH];
#pragma unroll
        for (int r = 0; r < 8; ++r) acc[r] = fmaf(wp[r][k], e, acc[r]);
    }
#pragma unroll
    for (int r = 0; r < 8; ++r) {
        const int row = base + r;
        if (row < RN)
            unsafeAtomicAdd(region_ent + (size_t)row * CH + c, 0.2f * acc[r]);
    }
}

__device__ __forceinline__ float ent_val(const float* __restrict__ emb,
                                         const float* __restrict__ region_ent,
                                         int row, int c) {
    const float* p = (row >= REGION_R0 && row < REGION_R1)
                         ? (region_ent + (size_t)(row - REGION_R0) * CH + c)
                         : (emb + (size_t)row * CH + c);
    return *p;
}

__device__ __forceinline__ const float* ent_row(const float* __restrict__ emb,
                                                const float* __restrict__ region_ent,
                                                int row) {
    return (row >= REGION_R0 && row < REGION_R1)
               ? (region_ent + (size_t)(row - REGION_R0) * CH)
               : (emb + (size_t)row * CH);
}

// =========================================================================
// bf16 entity table (region rows baked in)
// =========================================================================
__global__ void build_ebf_kernel(const float* __restrict__ emb,
                                 const float* __restrict__ region_ent,
                                 ushort_t* __restrict__ ebf,
                                 int n_entities) {
    const int gid = blockIdx.x * blockDim.x + threadIdx.x;
    if (gid >= n_entities * (CH / 8)) return;
    const int row = gid >> 3;
    const int co  = (gid & 7) * 8;
    const float* rp = ent_row(emb, region_ent, row) + co;
    const float4 a = *reinterpret_cast<const float4*>(rp);
    const float4 b = *reinterpret_cast<const float4*>(rp + 4);
    uint4 o;
    o.x = pack2bf(a.x, a.y);
    o.y = pack2bf(a.z, a.w);
    o.z = pack2bf(b.x, b.y);
    o.w = pack2bf(b.z, b.w);
    *reinterpret_cast<uint4*>(ebf + (size_t)row * CH + co) = o;
}

__device__ __forceinline__ float bf_lo(unsigned u) { return __uint_as_float(u << 16); }
__device__ __forceinline__ float bf_hi(unsigned u) { return __uint_as_float(u & 0xffff0000u); }

// =========================================================================
// Bucket partition. pass1: per-(block,bucket) histogram, LDS-accumulated.
// hist layout: hist[bucket*NB + block]  (bucket-major, block-minor)
// =========================================================================
__global__ void bucket_hist_kernel(const int* __restrict__ keys,
                                   int* __restrict__ hist, int n, int nbuk) {
    __shared__ int lh[MAXBUK];
    for (int i = threadIdx.x; i < nbuk; i += T1) lh[i] = 0;
    __syncthreads();
    const int chunk = (n + NB - 1) / NB;
    const int i0 = blockIdx.x * chunk;
    const int i1 = min(i0 + chunk, n);
    for (int i = i0 + (int)threadIdx.x; i < i1; i += T1)
        atomicAdd(&lh[keys[i] >> 6], 1);
    __syncthreads();
    for (int b = threadIdx.x; b < nbuk; b += T1)
        hist[(size_t)b * NB + blockIdx.x] = lh[b];
}

__global__ void scan_block_kernel(const int* __restrict__ counts, int* __restrict__ offs,
                                  int* __restrict__ bsums, int n) {
    __shared__ int s[SCAN_B];
    const int i = blockIdx.x * SCAN_B + threadIdx.x;
    s[threadIdx.x] = (i < n) ? counts[i] : 0;
    __syncthreads();
    for (int d = 1; d < SCAN_B; d <<= 1) {
        const int t = (threadIdx.x >= d) ? s[threadIdx.x - d] : 0;
        __syncthreads();
        s[threadIdx.x] += t;
        __syncthreads();
    }
    if (i < n) offs[i + 1] = s[threadIdx.x];
    if (threadIdx.x == SCAN_B - 1) bsums[blockIdx.x] = s[threadIdx.x];
    if (blockIdx.x == 0 && threadIdx.x == 0) offs[0] = 0;
}

__global__ void scan_top_kernel(int* __restrict__ bsums, int nb) {
    __shared__ int s[512];
    s[threadIdx.x] = (threadIdx.x < (unsigned)nb) ? bsums[threadIdx.x] : 0;
    __syncthreads();
    for (int d = 1; d < 512; d <<= 1) {
        const int t = (threadIdx.x >= d) ? s[threadIdx.x - d] : 0;
        __syncthreads();
        s[threadIdx.x] += t;
        __syncthreads();
    }
    if (threadIdx.x < (unsigned)nb) bsums[threadIdx.x] = s[threadIdx.x];
}

__global__ void scan_add_kernel(int* __restrict__ offs, const int* __restrict__ bsums, int n) {
    if (blockIdx.x == 0) return;
    const int i = blockIdx.x * SCAN_B + threadIdx.x;
    if (i < n) offs[i + 1] += bsums[blockIdx.x - 1];
}

// pass2 edges: pcode = (lh<<22)|(rel<<17)|tail — 4B, bucket-grouped,
// each (bucket,block) run exclusively owned by one block -> L2 combines.
__global__ void pass2_edges_kernel(const int* __restrict__ edge_index,
                                   const int* __restrict__ edge_type,
                                   const int* __restrict__ exbase,
                                   int* __restrict__ pcode,
                                   int E, int n_rel) {
    __shared__ int cur[MAXBUK];
    for (int i = threadIdx.x; i < MAXBUK; i += T1) cur[i] = 0;
    __syncthreads();
    const int chunk = (E + NB - 1) / NB;
    const int i0 = blockIdx.x * chunk;
    const int i1 = min(i0 + chunk, E);
    for (int e = i0 + (int)threadIdx.x; e < i1; e += T1) {
        const int h = edge_index[e];
        const int b = h >> 6;
        const int loc = atomicAdd(&cur[b], 1);
        const int pos = exbase[(size_t)b * NB + blockIdx.x] + loc;
        const int t = edge_index[(size_t)E + e];
        int r = edge_type[e] - 1;
        if (r < 0) r += n_rel;
        pcode[pos] = ((h & 63) << 22) | (r << 17) | t;
    }
}

// pass2 users: pcode_u = { (lr<<17)|col , bits(val) } — 8B
__global__ void pass2_users_kernel(const int* __restrict__ irows,
                                   const int* __restrict__ icols,
                                   const float* __restrict__ ivals,
                                   const int* __restrict__ exbase,
                                   uint2* __restrict__ pcode,
                                   int NNZ) {
    __shared__ int cur[MAXBUK];
    for (int i = threadIdx.x; i < MAXBUK; i += T1) cur[i] = 0;
    __syncthreads();
    const int chunk = (NNZ + NB - 1) / NB;
    const int i0 = blockIdx.x * chunk;
    const int i1 = min(i0 + chunk, NNZ);
    for (int i = i0 + (int)threadIdx.x; i < i1; i += T1) {
        const int u = irows[i];
        const int b = u >> 6;
        const int loc = atomicAdd(&cur[b], 1);
        const int pos = exbase[(size_t)b * NB + blockIdx.x] + loc;
        uint2 cv;
        cv.x = ((unsigned)(u & 63) << 17) | (unsigned)icols[i];
        cv.y = __float_as_uint(ivals[i]);
        pcode[pos] = cv;
    }
}

// =========================================================================
// Bucket gathers: one block per 64-head bucket; LDS accumulators (stride 68
// kills 4-way bank conflicts); per-head counts; coalesced row writes.
// =========================================================================
__global__ void kg_bucket_kernel(const int* __restrict__ pcode,
                                 const int* __restrict__ exbase,
                                 const float* __restrict__ weight,
                                 const ushort_t* __restrict__ ebf,
                                 float* __restrict__ out_ent,
                                 int n_entities, int n_rel) {
    __shared__ float wl[2048];       // n_rel*CH <= 2048
    __shared__ float acc[64 * 68];
    __shared__ int   cnt[64];
    for (int i = threadIdx.x; i < n_rel * CH; i += 256) wl[i] = weight[i];
    for (int i = threadIdx.x; i < 64 * 68; i += 256) acc[i] = 0.0f;
    if (threadIdx.x < 64) cnt[threadIdx.x] = 0;
    __syncthreads();
    const float4* wl4 = reinterpret_cast<const float4*>(wl);

    const int b  = blockIdx.x;
    const int h0 = b * 64;
    const int nh = min(64, n_entities - h0);
    const int bstart = exbase[(size_t)b * NB];
    const int bend   = exbase[(size_t)(b + 1) * NB];

    const int wv = threadIdx.x >> 6;
    const int g  = (threadIdx.x >> 4) & 3;
    const int q  = threadIdx.x & 15;

    for (int s = bstart + wv * 4; s < bend; s += 16) {
        const int e = s + g;
        const bool valid = (e < bend);
        const int p = valid ? pcode[e] : 0;
        const int lh   = p >> 22;
        const int rel  = (p >> 17) & 31;
        const int tail = p & 0x1FFFF;
        if (valid) {
            const uint2 row = *reinterpret_cast<const uint2*>(
                ebf + (size_t)tail * CH + q * 4);
            const float4 wv4 = wl4[rel * 16 + q];
            float* a = acc + lh * 68 + q * 4;
            atomicAdd(a + 0, bf_lo(row.x) * wv4.x);
            atomicAdd(a + 1, bf_hi(row.x) * wv4.y);
            atomicAdd(a + 2, bf_lo(row.y) * wv4.z);
            atomicAdd(a + 3, bf_hi(row.y) * wv4.w);
            if (q == 0) atomicAdd(&cnt[lh], 1);
        }
    }
    __syncthreads();

    for (int idx = threadIdx.x; idx < nh * 64; idx += 256) {
        const int lh = idx >> 6;
        const int c  = idx & 63;
        const int d  = cnt[lh];
        out_ent[(size_t)(h0 + lh) * CH + c] = acc[lh * 68 + c] / (float)(d > 0 ? d : 1);
    }
}

__global__ void user_bucket_kernel(const uint2* __restrict__ pcode,
                                   const int* __restrict__ exbase,
                                   const ushort_t* __restrict__ ebf,
                                   float* __restrict__ out_user,
                                   int n_users) {
    __shared__ float acc[64 * 68];
    for (int i = threadIdx.x; i < 64 * 68; i += 256) acc[i] = 0.0f;
    __syncthreads();

    const int b  = blockIdx.x;
    const int u0 = b * 64;
    const int nu = min(64, n_users - u0);
    const int bstart = exbase[(size_t)b * NB];
    const int bend   = exbase[(size_t)(b + 1) * NB];

    const int wv = threadIdx.x >> 6;
    const int g  = (threadIdx.x >> 4) & 3;
    const int q  = threadIdx.x & 15;

    for (int s = bstart + wv * 4; s < bend; s += 16) {
        const int e = s + g;
        const bool valid = (e < bend);
        uint2 cv;
        if (valid) cv = pcode[e];
        else       { cv.x = 0u; cv.y = 0u; }
        const int   lr  = (int)(cv.x >> 17);
        const int   col = (int)(cv.x & 0x1FFFF);
        const float v   = __uint_as_float(cv.y);
        if (valid) {
            const uint2 row = *reinterpret_cast<const uint2*>(
                ebf + (size_t)col * CH + q * 4);
            float* a = acc + lr * 68 + q * 4;
            atomicAdd(a + 0, v * bf_lo(row.x));
            atomicAdd(a + 1, v * bf_hi(row.x));
            atomicAdd(a + 2, v * bf_lo(row.y));
            atomicAdd(a + 3, v * bf_hi(row.y));
        }
    }
    __syncthreads();

    for (int idx = threadIdx.x; idx < nu * 64; idx += 256) {
        const int lr = idx >> 6;
        const int c  = idx & 63;
        out_user[(size_t)(u0 + lr) * CH + c] = acc[lr * 68 + c];
    }
}

// =========================================================================
// Fallback (small ws): packed-row atomic scatter
// =========================================================================
__global__ void kg_agg_atomic_kernel(const float* __restrict__ emb,
                                     const float* __restrict__ region_ent,
                                     const int* __restrict__ edge_index,
                                     const int* __restrict__ edge_type,
                                     const float* __restrict__ weight,
                                     float* __restrict__ out_ent,
                                     float* __restrict__ counts,
                                     int E, int n_rel) {
    const long long gid = (long long)blockIdx.x * blockDim.x + threadIdx.x;
    const long long e = gid >> 6;
    if (e >= E) return;
    const int c = (int)gid & 63;
    const int h = edge_index[e];
    const int t = edge_index[(size_t)E + e];
    int r = edge_type[e] - 1;
    if (r < 0) r += n_rel;
    const float v = ent_val(emb, region_ent, t, c) * weight[(size_t)r * CH + c];
    unsafeAtomicAdd(out_ent + (size_t)h * CH + c, v);
    if (c == 0) unsafeAtomicAdd(counts + h, 1.0f);
}

__global__ void user_agg_atomic_kernel(const float* __restrict__ emb,
                                       const float* __restrict__ region_ent,
                                       const int* __restrict__ irows,
                                       const int* __restrict__ icols,
                                       const float* __restrict__ ivals,
                                       float* __restrict__ out_user, int NNZ) {
    const long long gid = (long long)blockIdx.x * blockDim.x + threadIdx.x;
    const long long i = gid >> 6;
    if (i >= NNZ) return;
    const int c = (int)gid & 63;
    const float v = ivals[i] * ent_val(emb, region_ent, icols[i], c);
    unsafeAtomicAdd(out_user + (size_t)irows[i] * CH + c, v);
}

__global__ void finalize_kernel(float* __restrict__ out_ent,
                                const float* __restrict__ counts, int n_entities) {
    const int gid = blockIdx.x * blockDim.x + threadIdx.x;
    if (gid >= n_entities * CH) return;
    out_ent[gid] /= fmaxf(counts[gid >> 6], 1.0f);
}

// =========================================================================
extern "C" void kernel_launch(void* const* d_in, const int* in_sizes, int n_in,
                              void* d_out, int out_size, void* d_ws, size_t ws_size,
                              hipStream_t stream) {
    const float* entity_emb = (const float*)d_in[0];
    const int*   edge_index = (const int*)d_in[2];
    const int*   edge_type  = (const int*)d_in[3];
    const int*   irows      = (const int*)d_in[4];
    const int*   icols      = (const int*)d_in[5];
    const float* ivals      = (const float*)d_in[6];
    const float* Wreg       = (const float*)d_in[7];
    const float* weight     = (const float*)d_in[8];

    const int n_entities = in_sizes[0] / CH;
    const int n_users    = in_sizes[1] / CH;
    const int E          = in_sizes[3];
    const int NNZ        = in_sizes[4];
    const int n_rel      = in_sizes[8] / CH;

    float* out_ent  = (float*)d_out;
    float* out_user = out_ent + (size_t)n_entities * CH;

    const int NBUK_E = (n_entities + 63) >> 6;   // 1563
    const int NBUK_U = (n_users + 63) >> 6;      // 782
    const int n_e = NBUK_E * NB;                  // 100032
    const int n_u = NBUK_U * NB;                  // 50048
    const int nbse = (n_e + SCAN_B - 1) / SCAN_B; // 391
    const int nbsu = (n_u + SCAN_B - 1) / SCAN_B; // 196

    // ---- workspace layout (8B-aligned) ----
    char* w = (char*)d_ws;
    auto take = [&](size_t bytes) {
        char* p = w;
        w += (bytes + 7) & ~(size_t)7;
        return p;
    };
    float*    region_ent = (float*)take((size_t)RN * CH * 4);
    ushort_t* e_t        = (ushort_t*)take((size_t)CH * KP * 2);
    int*      hist_e     = (int*)take((size_t)n_e * 4);
    int*      exbase_e   = (int*)take((size_t)(n_e + 1) * 4);
    int*      hist_u     = (int*)take((size_t)n_u * 4);
    int*      exbase_u   = (int*)take((size_t)(n_u + 1) * 4);
    int*      bsums      = (int*)take(512 * 4);
    int*      pcode_e    = (int*)take((size_t)E * 4);
    uint2*    pcode_u    = (uint2*)take((size_t)NNZ * 8);
    ushort_t* ebf        = (ushort_t*)take((size_t)n_entities * CH * 2);
    const size_t need_bucket = (size_t)(w - (char*)d_ws);

    const bool use_bucket = (ws_size >= need_bucket) &&
                            (NBUK_E <= MAXBUK) && (NBUK_U <= MAXBUK) &&
                            (nbse <= 512) && (nbsu <= 512) &&
                            (n_entities < (1 << 17)) && (n_rel <= 32);

    // ---- region blend ----
    region_init_kernel<<<(RN * CH / 4 + 255) / 256, 256, 0, stream>>>(entity_emb, region_ent);

    if (use_bucket) {
        // MFMA region GEMM
        {
            const int tot = CH * (KP / 8);
            build_et_kernel<<<(tot + 255) / 256, 256, 0, stream>>>(entity_emb, e_t);
        }
        region_gemm_mfma_kernel<<<MT_BLKS * KCHUNKS, 256, 0, stream>>>(
            Wreg, e_t, region_ent);

        // bf16 entity table
        {
            const int tot = n_entities * (CH / 8);
            build_ebf_kernel<<<(tot + 255) / 256, 256, 0, stream>>>(
                entity_emb, region_ent, ebf, n_entities);
        }

        // ---- edges: hist -> scan -> reorder ----
        bucket_hist_kernel<<<NB, T1, 0, stream>>>(edge_index, hist_e, E, NBUK_E);
        scan_block_kernel<<<nbse, SCAN_B, 0, stream>>>(hist_e, exbase_e, bsums, n_e);
        scan_top_kernel<<<1, 512, 0, stream>>>(bsums, nbse);
        scan_add_kernel<<<nbse, SCAN_B, 0, stream>>>(exbase_e, bsums, n_e);
        pass2_edges_kernel<<<NB, T1, 0, stream>>>(
            edge_index, edge_type, exbase_e, pcode_e, E, n_rel);

        // ---- users: hist -> scan -> reorder ----
        bucket_hist_kernel<<<NB, T1, 0, stream>>>(irows, hist_u, NNZ, NBUK_U);
        scan_block_kernel<<<nbsu, SCAN_B, 0, stream>>>(hist_u, exbase_u, bsums, n_u);
        scan_top_kernel<<<1, 512, 0, stream>>>(bsums, nbsu);
        scan_add_kernel<<<nbsu, SCAN_B, 0, stream>>>(exbase_u, bsums, n_u);
        pass2_users_kernel<<<NB, T1, 0, stream>>>(
            irows, icols, ivals, exbase_u, pcode_u, NNZ);

        // ---- bucket gathers (write each output row exactly once) ----
        kg_bucket_kernel<<<NBUK_E, 256, 0, stream>>>(
            pcode_e, exbase_e, weight, ebf, out_ent, n_entities, n_rel);
        user_bucket_kernel<<<NBUK_U, 256, 0, stream>>>(
            pcode_u, exbase_u, ebf, out_user, n_users);
    } else {
        // fallback: VALU region gemm + packed-row atomics
        region_gemm_kernel<<<ROW_TILES * KSPLIT, 256, 0, stream>>>(
            entity_emb, Wreg, region_ent);

        float* counts = (float*)((char*)d_ws + (((size_t)RN * CH * 4 + 7) & ~(size_t)7)
                                 + (((size_t)CH * KP * 2 + 7) & ~(size_t)7));
        hipMemsetAsync(d_out, 0, (size_t)out_size * sizeof(float), stream);
        hipMemsetAsync(counts, 0, (size_t)n_entities * sizeof(float), stream);

        {
            const long long tot = (long long)E * CH;
            kg_agg_atomic_kernel<<<(int)((tot + 255) / 256), 256, 0, stream>>>(
                entity_emb, region_ent, edge_index, edge_type, weight,
                out_ent, counts, E, n_rel);
        }
        {
            const long long tot = (long long)NNZ * CH;
            user_agg_atomic_kernel<<<(int)((tot + 255) / 256), 256, 0, stream>>>(
                entity_emb, region_ent, irows, icols, ivals, out_user, NNZ);
        }
        finalize_kernel<<<(n_entities * CH + 255) / 256, 256, 0, stream>>>(
            out_ent, counts, n_entities);
    }
}

// Round 18
// 458.922 us; speedup vs baseline: 2.5932x; 2.5932x over previous
//
#include <hip/hip_runtime.h>
#include <hip/hip_bf16.h>

// Problem constants (from reference source)
#define REGION_R0 42033
#define REGION_R1 44630
#define RN        (REGION_R1 - REGION_R0)   // 2597
#define CH        64
#define KSPLIT    32
#define ROW_TILES ((RN + 31) / 32)          // 82
#define SCAN_B    256
#define NSLICE    8                          // XCD round-robin period
#define SLICE_RB  256                        // R14-proven grid: 8*256 = 2048 blocks

// MFMA region-gemm geometry
#define KTT       82
#define KP        (KTT * 32)                 // 2624
#define PERCHUNK  6
#define KCHUNKS   14
#define MT_TILES  163
#define MT_BLKS   41

typedef unsigned short ushort_t;
typedef short  bfrag8 __attribute__((ext_vector_type(8)));
typedef float  f32x4v __attribute__((ext_vector_type(4)));

__device__ __forceinline__ int ntload_i(const int* p) {
    return __builtin_nontemporal_load(p);
}
__device__ __forceinline__ float ntload_f(const float* p) {
    return __builtin_nontemporal_load(p);
}
__device__ __forceinline__ uint2 ntload_u2(const uint2* p) {
    const unsigned long long v =
        __builtin_nontemporal_load(reinterpret_cast<const unsigned long long*>(p));
    uint2 r;
    r.x = (unsigned)(v & 0xffffffffu);
    r.y = (unsigned)(v >> 32);
    return r;
}

// =========================================================================
// Region blend init (region_ent = 0.8 * orig)
// =========================================================================
__global__ void region_init_kernel(const float* __restrict__ emb,
                                   float* __restrict__ region_ent) {
    const int gid = blockIdx.x * blockDim.x + threadIdx.x;
    if (gid >= RN * CH / 4) return;
    const float4 v = reinterpret_cast<const float4*>(emb + (size_t)REGION_R0 * CH)[gid];
    float4 o;
    o.x = 0.8f * v.x; o.y = 0.8f * v.y; o.z = 0.8f * v.z; o.w = 0.8f * v.w;
    reinterpret_cast<float4*>(region_ent)[gid] = o;
}

__device__ __forceinline__ unsigned pack2bf(float a, float b) {
    unsigned ua = __float_as_uint(a);
    unsigned ub = __float_as_uint(b);
    ua += 0x7fffu + ((ua >> 16) & 1u);   // RNE
    ub += 0x7fffu + ((ub >> 16) & 1u);
    return ((ua >> 16) & 0xffffu) | (ub & 0xffff0000u);
}

// =========================================================================
// e_t[c][k] = bf16(emb[R0+k][c]) (B operand, transposed, zero-padded)
// =========================================================================
__global__ void build_et_kernel(const float* __restrict__ emb,
                                ushort_t* __restrict__ e_t) {
    const int gid = blockIdx.x * blockDim.x + threadIdx.x;
    if (gid >= CH * (KP / 8)) return;
    const int c  = gid / (KP / 8);
    const int k8 = gid - c * (KP / 8);
    const int kb = k8 * 8;
    float v[8];
#pragma unroll
    for (int j = 0; j < 8; ++j) {
        const int k = kb + j;
        v[j] = (k < RN) ? emb[(size_t)(REGION_R0 + k) * CH + c] : 0.0f;
    }
    uint4 o;
    o.x = pack2bf(v[0], v[1]); o.y = pack2bf(v[2], v[3]);
    o.z = pack2bf(v[4], v[5]); o.w = pack2bf(v[6], v[7]);
    *reinterpret_cast<uint4*>(e_t + (size_t)c * KP + kb) = o;
}

// =========================================================================
// MFMA region GEMM (R14-verified, absmax 0.25)
// =========================================================================
__global__ void region_gemm_mfma_kernel(const float* __restrict__ W,
                                        const ushort_t* __restrict__ e_t,
                                        float* __restrict__ region_ent) {
    const int wv    = threadIdx.x >> 6;
    const int lane  = threadIdx.x & 63;
    const int blk_m = blockIdx.x / KCHUNKS;
    const int kc    = blockIdx.x - blk_m * KCHUNKS;
    const int mt    = blk_m * 4 + wv;
    if (mt >= MT_TILES) return;
    const int l15 = lane & 15;
    const int lg  = lane >> 4;

    int arow = mt * 16 + l15;
    if (arow >= RN) arow = RN - 1;
    const float* wrow = W + (size_t)arow * RN;

    const int kt0 = kc * PERCHUNK;
    const int kt1 = (kt0 + PERCHUNK < KTT) ? (kt0 + PERCHUNK) : KTT;

    f32x4v acc[4];
#pragma unroll
    for (int n = 0; n < 4; ++n) acc[n] = (f32x4v){0.f, 0.f, 0.f, 0.f};

    for (int kt = kt0; kt < kt1; ++kt) {
        const int kb = kt * 32 + lg * 8;
        union { uint4 u; bfrag8 f; } A;
        if (kb + 8 <= RN) {
            float v0 = wrow[kb + 0], v1 = wrow[kb + 1];
            float v2 = wrow[kb + 2], v3 = wrow[kb + 3];
            float v4 = wrow[kb + 4], v5 = wrow[kb + 5];
            float v6 = wrow[kb + 6], v7 = wrow[kb + 7];
            A.u.x = pack2bf(v0, v1); A.u.y = pack2bf(v2, v3);
            A.u.z = pack2bf(v4, v5); A.u.w = pack2bf(v6, v7);
        } else {
            float v[8];
#pragma unroll
            for (int j = 0; j < 8; ++j) {
                const int k = kb + j;
                v[j] = (k < RN) ? wrow[k] : 0.0f;
            }
            A.u.x = pack2bf(v[0], v[1]); A.u.y = pack2bf(v[2], v[3]);
            A.u.z = pack2bf(v[4], v[5]); A.u.w = pack2bf(v[6], v[7]);
        }
#pragma unroll
        for (int n = 0; n < 4; ++n) {
            const bfrag8 B = *reinterpret_cast<const bfrag8*>(
                e_t + (size_t)(n * 16 + l15) * KP + kb);
            acc[n] = __builtin_amdgcn_mfma_f32_16x16x32_bf16(A.f, B, acc[n], 0, 0, 0);
        }
    }

#pragma unroll
    for (int n = 0; n < 4; ++n) {
#pragma unroll
        for (int j = 0; j < 4; ++j) {
            const int row = mt * 16 + lg * 4 + j;
            if (row < RN)
                unsafeAtomicAdd(region_ent + (size_t)row * CH + n * 16 + l15,
                                0.2f * acc[n][j]);
        }
    }
}

// =========================================================================
// Old VALU region GEMM (small-ws fallback only)
// =========================================================================
__global__ void region_gemm_kernel(const float* __restrict__ emb,
                                   const float* __restrict__ W,
                                   float* __restrict__ region_ent) {
    const int wave = threadIdx.x >> 6;
    const int c    = threadIdx.x & 63;
    const int rt   = blockIdx.x / KSPLIT;
    const int ks   = blockIdx.x - rt * KSPLIT;
    const int base = rt * 32 + wave * 8;
    if (base >= RN) return;

    const int k0 = (RN * ks) / KSPLIT;
    const int k1 = (RN * (ks + 1)) / KSPLIT;

    const float* wp[8];
#pragma unroll
    for (int r = 0; r < 8; ++r) {
        int row = base + r;
        if (row >= RN) row = RN - 1;
        row = __builtin_amdgcn_readfirstlane(row);
        wp[r] = W + (size_t)row * RN;
    }
    const float* ep = emb + (size_t)REGION_R0 * CH + c;

    float acc[8];
#pragma unroll
    for (int r = 0; r < 8; ++r) acc[r] = 0.0f;

    int k = k0;
    for (; k + 4 <= k1; k += 4) {
        const float e0 = ep[(size_t)(k + 0) * CH];
        const float e1 = ep[(size_t)(k + 1) * CH];
        const float e2 = ep[(size_t)(k + 2) * CH];
        const float e3 = ep[(size_t)(k + 3) * CH];
#pragma unroll
        for (int r = 0; r < 8; ++r) {
            const float* wr = wp[r];
            float a = acc[r];
            a = fmaf(wr[k + 0], e0, a);
            a = fmaf(wr[k + 1], e1, a);
            a = fmaf(wr[k + 2], e2, a);
            a = fmaf(wr[k + 3], e3, a);
            acc[r] = a;
        }
    }
    for (; k < k1; ++k) {
        const float e = ep[(size_t)k * CH];
#pragma unroll
        for (int r = 0; r < 8; ++r) acc[r] = fmaf(wp[r][k], e, acc[r]);
    }
#pragma unroll
    for (int r = 0; r < 8; ++r) {
        const int row = base + r;
        if (row < RN)
            unsafeAtomicAdd(region_ent + (size_t)row * CH + c, 0.2f * acc[r]);
    }
}

__device__ __forceinline__ float ent_val(const float* __restrict__ emb,
                                         const float* __restrict__ region_ent,
                                         int row, int c) {
    const float* p = (row >= REGION_R0 && row < REGION_R1)
                         ? (region_ent + (size_t)(row - REGION_R0) * CH + c)
                         : (emb + (size_t)row * CH + c);
    return *p;
}

__device__ __forceinline__ const float* ent_row(const float* __restrict__ emb,
                                                const float* __restrict__ region_ent,
                                                int row) {
    return (row >= REGION_R0 && row < REGION_R1)
               ? (region_ent + (size_t)(row - REGION_R0) * CH)
               : (emb + (size_t)row * CH);
}

// =========================================================================
// bf16 entity table (region rows baked in)
// =========================================================================
__global__ void build_ebf_kernel(const float* __restrict__ emb,
                                 const float* __restrict__ region_ent,
                                 ushort_t* __restrict__ ebf,
                                 int n_entities) {
    const int gid = blockIdx.x * blockDim.x + threadIdx.x;
    if (gid >= n_entities * (CH / 8)) return;
    const int row = gid >> 3;
    const int co  = (gid & 7) * 8;
    const float* rp = ent_row(emb, region_ent, row) + co;
    const float4 a = *reinterpret_cast<const float4*>(rp);
    const float4 b = *reinterpret_cast<const float4*>(rp + 4);
    uint4 o;
    o.x = pack2bf(a.x, a.y);
    o.y = pack2bf(a.z, a.w);
    o.z = pack2bf(b.x, b.y);
    o.w = pack2bf(b.z, b.w);
    *reinterpret_cast<uint4*>(ebf + (size_t)row * CH + co) = o;
}

__device__ __forceinline__ float bf_lo(unsigned u) { return __uint_as_float(u << 16); }
__device__ __forceinline__ float bf_hi(unsigned u) { return __uint_as_float(u & 0xffff0000u); }

// =========================================================================
// CSR build, XCD-sliced (R14 grid), R18: NON-TEMPORAL streaming reads so the
// 8x edge-array stream doesn't evict partially-filled scatter lines from L2.
// =========================================================================
__global__ void hist_sliced_kernel(const int* __restrict__ keys,
                                   int* __restrict__ counts, int n, unsigned smul) {
    const int slice = blockIdx.x & (NSLICE - 1);
    const int rb    = blockIdx.x >> 3;
    const int nrb   = gridDim.x >> 3;
    const int per   = (n + nrb - 1) / nrb;
    const int i0    = rb * per;
    const int i1    = min(i0 + per, n);
    for (int i = i0 + (int)threadIdx.x; i < i1; i += blockDim.x) {
        const int k = ntload_i(&keys[i]);
        if ((int)__umulhi((unsigned)k, smul) == slice)
            atomicAdd(&counts[k], 1);
    }
}

__global__ void scan_block_kernel(const int* __restrict__ counts, int* __restrict__ offs,
                                  int* __restrict__ bsums, int n) {
    __shared__ int s[SCAN_B];
    const int i = blockIdx.x * SCAN_B + threadIdx.x;
    s[threadIdx.x] = (i < n) ? counts[i] : 0;
    __syncthreads();
    for (int d = 1; d < SCAN_B; d <<= 1) {
        const int t = (threadIdx.x >= d) ? s[threadIdx.x - d] : 0;
        __syncthreads();
        s[threadIdx.x] += t;
        __syncthreads();
    }
    if (i < n) offs[i + 1] = s[threadIdx.x];
    if (threadIdx.x == SCAN_B - 1) bsums[blockIdx.x] = s[threadIdx.x];
    if (blockIdx.x == 0 && threadIdx.x == 0) offs[0] = 0;
}

__global__ void scan_top_kernel(int* __restrict__ bsums, int nb) {
    __shared__ int s[512];
    s[threadIdx.x] = (threadIdx.x < (unsigned)nb) ? bsums[threadIdx.x] : 0;
    __syncthreads();
    for (int d = 1; d < 512; d <<= 1) {
        const int t = (threadIdx.x >= d) ? s[threadIdx.x - d] : 0;
        __syncthreads();
        s[threadIdx.x] += t;
        __syncthreads();
    }
    if (threadIdx.x < (unsigned)nb) bsums[threadIdx.x] = s[threadIdx.x];
}

__global__ void scan_add_kernel(int* __restrict__ offs, const int* __restrict__ bsums, int n) {
    if (blockIdx.x == 0) return;
    const int i = blockIdx.x * SCAN_B + threadIdx.x;
    if (i < n) offs[i + 1] += bsums[blockIdx.x - 1];
}

// sorted_tr[pos] = tail | (rel<<17)  (tail<2^17, rel<2^5)
__global__ void scatter_e_sliced_kernel(const int* __restrict__ edge_index,
                                        const int* __restrict__ edge_type,
                                        const int* __restrict__ offs,
                                        int* __restrict__ cursor,
                                        int* __restrict__ sorted_tr,
                                        int E, int n_rel, unsigned smul) {
    const int slice = blockIdx.x & (NSLICE - 1);
    const int rb    = blockIdx.x >> 3;
    const int nrb   = gridDim.x >> 3;
    const int per   = (E + nrb - 1) / nrb;
    const int e0    = rb * per;
    const int e1    = min(e0 + per, E);
    for (int e = e0 + (int)threadIdx.x; e < e1; e += blockDim.x) {
        const int h = ntload_i(&edge_index[e]);
        if ((int)__umulhi((unsigned)h, smul) != slice) continue;
        const int t = ntload_i(&edge_index[(size_t)E + e]);
        int r = ntload_i(&edge_type[e]) - 1;
        if (r < 0) r += n_rel;
        const int pos = offs[h] + atomicAdd(&cursor[h], 1);
        sorted_tr[pos] = t | (r << 17);
    }
}

__global__ void scatter_u_sliced_kernel(const int* __restrict__ irows,
                                        const int* __restrict__ icols,
                                        const float* __restrict__ ivals,
                                        const int* __restrict__ offs,
                                        int* __restrict__ cursor,
                                        uint2* __restrict__ upack,
                                        int NNZ, unsigned smul) {
    const int slice = blockIdx.x & (NSLICE - 1);
    const int rb    = blockIdx.x >> 3;
    const int nrb   = gridDim.x >> 3;
    const int per   = (NNZ + nrb - 1) / nrb;
    const int i0    = rb * per;
    const int i1    = min(i0 + per, NNZ);
    for (int i = i0 + (int)threadIdx.x; i < i1; i += blockDim.x) {
        const int u = ntload_i(&irows[i]);
        if ((int)__umulhi((unsigned)u, smul) != slice) continue;
        const int pos = offs[u] + atomicAdd(&cursor[u], 1);
        uint2 cv;
        cv.x = (unsigned)ntload_i(&icols[i]);
        cv.y = __float_as_uint(ntload_f(&ivals[i]));
        upack[pos] = cv;
    }
}

// =========================================================================
// bf16 gather kernels: unroll x4 fully predicated; nt-load of the code
// streams (read-once) so ebf stays cached.
// =========================================================================
__global__ void kg_gather_bf_kernel(const ushort_t* __restrict__ ebf,
                                    const int* __restrict__ sorted_tr,
                                    const int* __restrict__ offs,
                                    const float* __restrict__ weight,
                                    float* __restrict__ out_ent,
                                    int n_entities, int n_rel) {
    extern __shared__ float wl[];   // n_rel * CH
    for (int i = threadIdx.x; i < n_rel * CH; i += blockDim.x) wl[i] = weight[i];
    __syncthreads();
    const float4* wl4 = reinterpret_cast<const float4*>(wl);

    const int wid  = (blockIdx.x * blockDim.x + threadIdx.x) >> 6;
    const int lane = threadIdx.x & 63;
    const int g    = lane >> 4;
    const int q    = lane & 15;
    if (wid >= n_entities) return;

    const int s0 = offs[wid], s1 = offs[wid + 1];
    float ax[4], ay[4], az[4], aw[4];
#pragma unroll
    for (int u = 0; u < 4; ++u) { ax[u] = 0.f; ay[u] = 0.f; az[u] = 0.f; aw[u] = 0.f; }

    for (int base = s0; base < s1; base += 16) {
#pragma unroll
        for (int u = 0; u < 4; ++u) {
            const int e = base + u * 4 + g;
            const bool valid = (e < s1);
            const int tr = valid ? ntload_i(&sorted_tr[e]) : 0;
            uint2 p; p.x = 0u; p.y = 0u;
            if (valid)
                p = *reinterpret_cast<const uint2*>(
                    ebf + (size_t)(tr & 0x1FFFF) * CH + q * 4);
            const float4 wv = wl4[(tr >> 17) * 16 + q];
            ax[u] = fmaf(bf_lo(p.x), wv.x, ax[u]);
            ay[u] = fmaf(bf_hi(p.x), wv.y, ay[u]);
            az[u] = fmaf(bf_lo(p.y), wv.z, az[u]);
            aw[u] = fmaf(bf_hi(p.y), wv.w, aw[u]);
        }
    }
    float AX = (ax[0] + ax[1]) + (ax[2] + ax[3]);
    float AY = (ay[0] + ay[1]) + (ay[2] + ay[3]);
    float AZ = (az[0] + az[1]) + (az[2] + az[3]);
    float AW = (aw[0] + aw[1]) + (aw[2] + aw[3]);

    AX += __shfl_xor(AX, 16); AY += __shfl_xor(AY, 16);
    AZ += __shfl_xor(AZ, 16); AW += __shfl_xor(AW, 16);
    AX += __shfl_xor(AX, 32); AY += __shfl_xor(AY, 32);
    AZ += __shfl_xor(AZ, 32); AW += __shfl_xor(AW, 32);

    if (g == 0) {
        const int deg = s1 - s0;
        const float inv = 1.0f / (float)(deg > 0 ? deg : 1);
        float4 o;
        o.x = AX * inv; o.y = AY * inv; o.z = AZ * inv; o.w = AW * inv;
        reinterpret_cast<float4*>(out_ent + (size_t)wid * CH)[q] = o;
    }
}

__global__ void user_gather_bf_kernel(const ushort_t* __restrict__ ebf,
                                      const uint2* __restrict__ upack,
                                      const int* __restrict__ offs,
                                      float* __restrict__ out_user,
                                      int n_users) {
    const int wid  = (blockIdx.x * blockDim.x + threadIdx.x) >> 6;
    const int lane = threadIdx.x & 63;
    const int g    = lane >> 4;
    const int q    = lane & 15;
    if (wid >= n_users) return;

    const int s0 = offs[wid], s1 = offs[wid + 1];
    float ax[4], ay[4], az[4], aw[4];
#pragma unroll
    for (int u = 0; u < 4; ++u) { ax[u] = 0.f; ay[u] = 0.f; az[u] = 0.f; aw[u] = 0.f; }

    for (int base = s0; base < s1; base += 16) {
#pragma unroll
        for (int u = 0; u < 4; ++u) {
            const int e = base + u * 4 + g;
            const bool valid = (e < s1);
            uint2 cv; cv.x = 0u; cv.y = 0u;
            if (valid) cv = ntload_u2(&upack[e]);
            const float v = __uint_as_float(cv.y);   // 0 when invalid
            const uint2 p = *reinterpret_cast<const uint2*>(
                ebf + (size_t)cv.x * CH + q * 4);    // row 0 is valid memory
            ax[u] = fmaf(v, bf_lo(p.x), ax[u]);
            ay[u] = fmaf(v, bf_hi(p.x), ay[u]);
            az[u] = fmaf(v, bf_lo(p.y), az[u]);
            aw[u] = fmaf(v, bf_hi(p.y), aw[u]);
        }
    }
    float AX = (ax[0] + ax[1]) + (ax[2] + ax[3]);
    float AY = (ay[0] + ay[1]) + (ay[2] + ay[3]);
    float AZ = (az[0] + az[1]) + (az[2] + az[3]);
    float AW = (aw[0] + aw[1]) + (aw[2] + aw[3]);

    AX += __shfl_xor(AX, 16); AY += __shfl_xor(AY, 16);
    AZ += __shfl_xor(AZ, 16); AW += __shfl_xor(AW, 16);
    AX += __shfl_xor(AX, 32); AY += __shfl_xor(AY, 32);
    AZ += __shfl_xor(AZ, 32); AW += __shfl_xor(AW, 32);

    if (g == 0) {
        float4 o; o.x = AX; o.y = AY; o.z = AZ; o.w = AW;
        reinterpret_cast<float4*>(out_user + (size_t)wid * CH)[q] = o;
    }
}

// =========================================================================
// fp32 gather kernels (fallback when ws can't fit ebf)
// =========================================================================
__global__ void kg_gather_kernel(const float* __restrict__ emb,
                                 const float* __restrict__ region_ent,
                                 const int* __restrict__ sorted_tr,
                                 const int* __restrict__ offs,
                                 const float* __restrict__ weight,
                                 float* __restrict__ out_ent,
                                 int n_entities, int n_rel) {
    extern __shared__ float wl[];
    for (int i = threadIdx.x; i < n_rel * CH; i += blockDim.x) wl[i] = weight[i];
    __syncthreads();
    const float4* wl4 = reinterpret_cast<const float4*>(wl);

    const int wid  = (blockIdx.x * blockDim.x + threadIdx.x) >> 6;
    const int lane = threadIdx.x & 63;
    const int g    = lane >> 4;
    const int q    = lane & 15;
    if (wid >= n_entities) return;

    const int s0 = offs[wid], s1 = offs[wid + 1];
    float ax = 0.0f, ay = 0.0f, az = 0.0f, aw = 0.0f;

    for (int base = s0; base < s1; base += 4) {
        const int e = base + g;
        const bool valid = (e < s1);
        const int tr   = valid ? sorted_tr[e] : 0;
        const int tail = tr & 0x1FFFF;
        const int rel  = tr >> 17;
        const float4* rp = reinterpret_cast<const float4*>(ent_row(emb, region_ent, tail));
        float4 ev;
        if (valid) ev = rp[q];
        else       { ev.x = 0.0f; ev.y = 0.0f; ev.z = 0.0f; ev.w = 0.0f; }
        const float4 wv = wl4[rel * 16 + q];
        ax = fmaf(ev.x, wv.x, ax);
        ay = fmaf(ev.y, wv.y, ay);
        az = fmaf(ev.z, wv.z, az);
        aw = fmaf(ev.w, wv.w, aw);
    }

    ax += __shfl_xor(ax, 16); ay += __shfl_xor(ay, 16);
    az += __shfl_xor(az, 16); aw += __shfl_xor(aw, 16);
    ax += __shfl_xor(ax, 32); ay += __shfl_xor(ay, 32);
    az += __shfl_xor(az, 32); aw += __shfl_xor(aw, 32);

    if (g == 0) {
        const int deg = s1 - s0;
        const float inv = 1.0f / (float)(deg > 0 ? deg : 1);
        float4 o;
        o.x = ax * inv; o.y = ay * inv; o.z = az * inv; o.w = aw * inv;
        reinterpret_cast<float4*>(out_ent + (size_t)wid * CH)[q] = o;
    }
}

__global__ void user_gather_kernel(const float* __restrict__ emb,
                                   const float* __restrict__ region_ent,
                                   const uint2* __restrict__ upack,
                                   const int* __restrict__ offs,
                                   float* __restrict__ out_user,
                                   int n_users) {
    const int wid  = (blockIdx.x * blockDim.x + threadIdx.x) >> 6;
    const int lane = threadIdx.x & 63;
    const int g    = lane >> 4;
    const int q    = lane & 15;
    if (wid >= n_users) return;

    const int s0 = offs[wid], s1 = offs[wid + 1];
    float ax = 0.0f, ay = 0.0f, az = 0.0f, aw = 0.0f;

    for (int base = s0; base < s1; base += 4) {
        const int e = base + g;
        const bool valid = (e < s1);
        uint2 cv;
        if (valid) cv = upack[e];
        else       { cv.x = 0u; cv.y = 0u; }
        const int   col = (int)cv.x;
        const float v   = __uint_as_float(cv.y);
        const float4* rp = reinterpret_cast<const float4*>(ent_row(emb, region_ent, col));
        const float4 ev = rp[q];
        ax = fmaf(v, ev.x, ax);
        ay = fmaf(v, ev.y, ay);
        az = fmaf(v, ev.z, az);
        aw = fmaf(v, ev.w, aw);
    }

    ax += __shfl_xor(ax, 16); ay += __shfl_xor(ay, 16);
    az += __shfl_xor(az, 16); aw += __shfl_xor(aw, 16);
    ax += __shfl_xor(ax, 32); ay += __shfl_xor(ay, 32);
    az += __shfl_xor(az, 32); aw += __shfl_xor(aw, 32);

    if (g == 0) {
        float4 o; o.x = ax; o.y = ay; o.z = az; o.w = aw;
        reinterpret_cast<float4*>(out_user + (size_t)wid * CH)[q] = o;
    }
}

// =========================================================================
// Fallback (small ws): packed-row atomic scatter
// =========================================================================
__global__ void kg_agg_atomic_kernel(const float* __restrict__ emb,
                                     const float* __restrict__ region_ent,
                                     const int* __restrict__ edge_index,
                                     const int* __restrict__ edge_type,
                                     const float* __restrict__ weight,
                                     float* __restrict__ out_ent,
                                     float* __restrict__ counts,
                                     int E, int n_rel) {
    const long long gid = (long long)blockIdx.x * blockDim.x + threadIdx.x;
    const long long e = gid >> 6;
    if (e >= E) return;
    const int c = (int)gid & 63;
    const int h = edge_index[e];
    const int t = edge_index[(size_t)E + e];
    int r = edge_type[e] - 1;
    if (r < 0) r += n_rel;
    const float v = ent_val(emb, region_ent, t, c) * weight[(size_t)r * CH + c];
    unsafeAtomicAdd(out_ent + (size_t)h * CH + c, v);
    if (c == 0) unsafeAtomicAdd(counts + h, 1.0f);
}

__global__ void user_agg_atomic_kernel(const float* __restrict__ emb,
                                       const float* __restrict__ region_ent,
                                       const int* __restrict__ irows,
                                       const int* __restrict__ icols,
                                       const float* __restrict__ ivals,
                                       float* __restrict__ out_user, int NNZ) {
    const long long gid = (long long)blockIdx.x * blockDim.x + threadIdx.x;
    const long long i = gid >> 6;
    if (i >= NNZ) return;
    const int c = (int)gid & 63;
    const float v = ivals[i] * ent_val(emb, region_ent, icols[i], c);
    unsafeAtomicAdd(out_user + (size_t)irows[i] * CH + c, v);
}

__global__ void finalize_kernel(float* __restrict__ out_ent,
                                const float* __restrict__ counts, int n_entities) {
    const int gid = blockIdx.x * blockDim.x + threadIdx.x;
    if (gid >= n_entities * CH) return;
    out_ent[gid] /= fmaxf(counts[gid >> 6], 1.0f);
}

// =========================================================================
extern "C" void kernel_launch(void* const* d_in, const int* in_sizes, int n_in,
                              void* d_out, int out_size, void* d_ws, size_t ws_size,
                              hipStream_t stream) {
    const float* entity_emb = (const float*)d_in[0];
    const int*   edge_index = (const int*)d_in[2];
    const int*   edge_type  = (const int*)d_in[3];
    const int*   irows      = (const int*)d_in[4];
    const int*   icols      = (const int*)d_in[5];
    const float* ivals      = (const float*)d_in[6];
    const float* Wreg       = (const float*)d_in[7];
    const float* weight     = (const float*)d_in[8];

    const int n_entities = in_sizes[0] / CH;
    const int n_users    = in_sizes[1] / CH;
    const int E          = in_sizes[3];
    const int NNZ        = in_sizes[4];
    const int n_rel      = in_sizes[8] / CH;

    float* out_ent  = (float*)d_out;
    float* out_user = out_ent + (size_t)n_entities * CH;

    // slice magics: slice(k) = umulhi(k, smul) in [0, 8)
    const unsigned smul_e = (unsigned)((8ULL << 32) / (unsigned long long)n_entities);
    const unsigned smul_u = (unsigned)((8ULL << 32) / (unsigned long long)n_users);

    // ---- workspace layout (8B-aligned) ----
    char* w = (char*)d_ws;
    auto take = [&](size_t bytes) {
        char* p = w;
        w += (bytes + 7) & ~(size_t)7;
        return p;
    };
    float*    region_ent = (float*)take((size_t)RN * CH * 4);
    int*      offs_e     = (int*)take((size_t)(n_entities + 1) * 4);
    int*      cursor_e   = (int*)take((size_t)n_entities * 4);
    int*      offs_u     = (int*)take((size_t)(n_users + 1) * 4);
    int*      cursor_u   = (int*)take((size_t)n_users * 4);
    int*      bsums      = (int*)take(512 * 4);
    int*      sorted_tr  = (int*)take((size_t)E * 4);
    uint2*    upack      = (uint2*)take((size_t)NNZ * 8);
    ushort_t* e_t        = (ushort_t*)take((size_t)CH * KP * 2);
    const size_t need_csr = (size_t)(w - (char*)d_ws);
    ushort_t* ebf        = (ushort_t*)take((size_t)n_entities * CH * 2);
    const size_t need_bf  = (size_t)(w - (char*)d_ws);

    const int nb_e = (n_entities + SCAN_B - 1) / SCAN_B;
    const int nb_u = (n_users + SCAN_B - 1) / SCAN_B;
    const bool use_csr = (ws_size >= need_csr) && (nb_e <= 512) && (nb_u <= 512) &&
                         (n_entities < (1 << 17)) && (n_rel <= 32);
    const bool use_bf  = use_csr && (ws_size >= need_bf);

    // ---- region blend ----
    region_init_kernel<<<(RN * CH / 4 + 255) / 256, 256, 0, stream>>>(entity_emb, region_ent);

    if (use_csr) {
        // MFMA region GEMM (bf16 inputs, fp32 accum)
        {
            const int tot = CH * (KP / 8);
            build_et_kernel<<<(tot + 255) / 256, 256, 0, stream>>>(entity_emb, e_t);
        }
        region_gemm_mfma_kernel<<<MT_BLKS * KCHUNKS, 256, 0, stream>>>(
            Wreg, e_t, region_ent);

        if (use_bf) {
            const int tot = n_entities * (CH / 8);
            build_ebf_kernel<<<(tot + 255) / 256, 256, 0, stream>>>(
                entity_emb, region_ent, ebf, n_entities);
        }

        hipMemsetAsync(cursor_e, 0, (size_t)n_entities * 4, stream);
        hipMemsetAsync(cursor_u, 0, (size_t)n_users * 4, stream);

        // sliced histograms (R14 grid)
        hist_sliced_kernel<<<NSLICE * SLICE_RB, 256, 0, stream>>>(
            edge_index, cursor_e, E, smul_e);
        hist_sliced_kernel<<<NSLICE * SLICE_RB, 256, 0, stream>>>(
            irows, cursor_u, NNZ, smul_u);

        scan_block_kernel<<<nb_e, SCAN_B, 0, stream>>>(cursor_e, offs_e, bsums, n_entities);
        scan_top_kernel<<<1, 512, 0, stream>>>(bsums, nb_e);
        scan_add_kernel<<<nb_e, SCAN_B, 0, stream>>>(offs_e, bsums, n_entities);

        scan_block_kernel<<<nb_u, SCAN_B, 0, stream>>>(cursor_u, offs_u, bsums, n_users);
        scan_top_kernel<<<1, 512, 0, stream>>>(bsums, nb_u);
        scan_add_kernel<<<nb_u, SCAN_B, 0, stream>>>(offs_u, bsums, n_users);

        hipMemsetAsync(cursor_e, 0, (size_t)n_entities * 4, stream);
        hipMemsetAsync(cursor_u, 0, (size_t)n_users * 4, stream);

        // sliced scatters (R14 grid, nt streaming reads)
        scatter_e_sliced_kernel<<<NSLICE * SLICE_RB, 256, 0, stream>>>(
            edge_index, edge_type, offs_e, cursor_e, sorted_tr, E, n_rel, smul_e);
        scatter_u_sliced_kernel<<<NSLICE * SLICE_RB, 256, 0, stream>>>(
            irows, icols, ivals, offs_u, cursor_u, upack, NNZ, smul_u);

        if (use_bf) {
            kg_gather_bf_kernel<<<(n_entities + 3) / 4, 256, n_rel * CH * 4, stream>>>(
                ebf, sorted_tr, offs_e, weight, out_ent, n_entities, n_rel);
            user_gather_bf_kernel<<<(n_users + 3) / 4, 256, 0, stream>>>(
                ebf, upack, offs_u, out_user, n_users);
        } else {
            kg_gather_kernel<<<(n_entities + 3) / 4, 256, n_rel * CH * 4, stream>>>(
                entity_emb, region_ent, sorted_tr, offs_e, weight, out_ent, n_entities, n_rel);
            user_gather_kernel<<<(n_users + 3) / 4, 256, 0, stream>>>(
                entity_emb, region_ent, upack, offs_u, out_user, n_users);
        }
    } else {
        // fallback: old VALU region gemm + packed-row atomics
        region_gemm_kernel<<<ROW_TILES * KSPLIT, 256, 0, stream>>>(
            entity_emb, Wreg, region_ent);

        float* counts = (float*)((char*)d_ws + (((size_t)RN * CH * 4 + 7) & ~(size_t)7));
        hipMemsetAsync(d_out, 0, (size_t)out_size * sizeof(float), stream);
        hipMemsetAsync(counts, 0, (size_t)n_entities * sizeof(float), stream);

        {
            const long long tot = (long long)E * CH;
            kg_agg_atomic_kernel<<<(int)((tot + 255) / 256), 256, 0, stream>>>(
                entity_emb, region_ent, edge_index, edge_type, weight,
                out_ent, counts, E, n_rel);
        }
        {
            const long long tot = (long long)NNZ * CH;
            user_agg_atomic_kernel<<<(int)((tot + 255) / 256), 256, 0, stream>>>(
                entity_emb, region_ent, irows, icols, ivals, out_user, NNZ);
        }
        finalize_kernel<<<(n_entities * CH + 255) / 256, 256, 0, stream>>>(
            out_ent, counts, n_entities);
    }
}

// Round 19
// 284.465 us; speedup vs baseline: 4.1836x; 1.6133x over previous
//
#include <hip/hip_runtime.h>
#include <hip/hip_bf16.h>

// Problem constants (from reference source)
#define REGION_R0 42033
#define REGION_R1 44630
#define RN        (REGION_R1 - REGION_R0)   // 2597
#define CH        64
#define KSPLIT    32
#define ROW_TILES ((RN + 31) / 32)          // 82
#define SCAN_B    256
#define NSLICE    8
#define SLICE_RB  256                        // tier-2 grid (R14-proven)

// bucket partition geometry
#define NB        64                         // range-blocks (keeps scan <=512 blocks)
#define T1        512
#define MAXBUK    2048

// MFMA region-gemm geometry
#define KTT       82
#define KP        (KTT * 32)                 // 2624
#define PERCHUNK  6
#define KCHUNKS   14
#define MT_TILES  163
#define MT_BLKS   41

typedef unsigned short ushort_t;
typedef short  bfrag8 __attribute__((ext_vector_type(8)));
typedef float  f32x4v __attribute__((ext_vector_type(4)));

// =========================================================================
// Region blend init (region_ent = 0.8 * orig)
// =========================================================================
__global__ void region_init_kernel(const float* __restrict__ emb,
                                   float* __restrict__ region_ent) {
    const int gid = blockIdx.x * blockDim.x + threadIdx.x;
    if (gid >= RN * CH / 4) return;
    const float4 v = reinterpret_cast<const float4*>(emb + (size_t)REGION_R0 * CH)[gid];
    float4 o;
    o.x = 0.8f * v.x; o.y = 0.8f * v.y; o.z = 0.8f * v.z; o.w = 0.8f * v.w;
    reinterpret_cast<float4*>(region_ent)[gid] = o;
}

__device__ __forceinline__ unsigned pack2bf(float a, float b) {
    unsigned ua = __float_as_uint(a);
    unsigned ub = __float_as_uint(b);
    ua += 0x7fffu + ((ua >> 16) & 1u);   // RNE
    ub += 0x7fffu + ((ub >> 16) & 1u);
    return ((ua >> 16) & 0xffffu) | (ub & 0xffff0000u);
}

// =========================================================================
// e_t[c][k] = bf16(emb[R0+k][c]) (B operand, transposed, zero-padded)
// =========================================================================
__global__ void build_et_kernel(const float* __restrict__ emb,
                                ushort_t* __restrict__ e_t) {
    const int gid = blockIdx.x * blockDim.x + threadIdx.x;
    if (gid >= CH * (KP / 8)) return;
    const int c  = gid / (KP / 8);
    const int k8 = gid - c * (KP / 8);
    const int kb = k8 * 8;
    float v[8];
#pragma unroll
    for (int j = 0; j < 8; ++j) {
        const int k = kb + j;
        v[j] = (k < RN) ? emb[(size_t)(REGION_R0 + k) * CH + c] : 0.0f;
    }
    uint4 o;
    o.x = pack2bf(v[0], v[1]); o.y = pack2bf(v[2], v[3]);
    o.z = pack2bf(v[4], v[5]); o.w = pack2bf(v[6], v[7]);
    *reinterpret_cast<uint4*>(e_t + (size_t)c * KP + kb) = o;
}

// =========================================================================
// MFMA region GEMM (R14-verified, absmax 0.25)
// =========================================================================
__global__ void region_gemm_mfma_kernel(const float* __restrict__ W,
                                        const ushort_t* __restrict__ e_t,
                                        float* __restrict__ region_ent) {
    const int wv    = threadIdx.x >> 6;
    const int lane  = threadIdx.x & 63;
    const int blk_m = blockIdx.x / KCHUNKS;
    const int kc    = blockIdx.x - blk_m * KCHUNKS;
    const int mt    = blk_m * 4 + wv;
    if (mt >= MT_TILES) return;
    const int l15 = lane & 15;
    const int lg  = lane >> 4;

    int arow = mt * 16 + l15;
    if (arow >= RN) arow = RN - 1;
    const float* wrow = W + (size_t)arow * RN;

    const int kt0 = kc * PERCHUNK;
    const int kt1 = (kt0 + PERCHUNK < KTT) ? (kt0 + PERCHUNK) : KTT;

    f32x4v acc[4];
#pragma unroll
    for (int n = 0; n < 4; ++n) acc[n] = (f32x4v){0.f, 0.f, 0.f, 0.f};

    for (int kt = kt0; kt < kt1; ++kt) {
        const int kb = kt * 32 + lg * 8;
        union { uint4 u; bfrag8 f; } A;
        if (kb + 8 <= RN) {
            float v0 = wrow[kb + 0], v1 = wrow[kb + 1];
            float v2 = wrow[kb + 2], v3 = wrow[kb + 3];
            float v4 = wrow[kb + 4], v5 = wrow[kb + 5];
            float v6 = wrow[kb + 6], v7 = wrow[kb + 7];
            A.u.x = pack2bf(v0, v1); A.u.y = pack2bf(v2, v3);
            A.u.z = pack2bf(v4, v5); A.u.w = pack2bf(v6, v7);
        } else {
            float v[8];
#pragma unroll
            for (int j = 0; j < 8; ++j) {
                const int k = kb + j;
                v[j] = (k < RN) ? wrow[k] : 0.0f;
            }
            A.u.x = pack2bf(v[0], v[1]); A.u.y = pack2bf(v[2], v[3]);
            A.u.z = pack2bf(v[4], v[5]); A.u.w = pack2bf(v[6], v[7]);
        }
#pragma unroll
        for (int n = 0; n < 4; ++n) {
            const bfrag8 B = *reinterpret_cast<const bfrag8*>(
                e_t + (size_t)(n * 16 + l15) * KP + kb);
            acc[n] = __builtin_amdgcn_mfma_f32_16x16x32_bf16(A.f, B, acc[n], 0, 0, 0);
        }
    }

#pragma unroll
    for (int n = 0; n < 4; ++n) {
#pragma unroll
        for (int j = 0; j < 4; ++j) {
            const int row = mt * 16 + lg * 4 + j;
            if (row < RN)
                unsafeAtomicAdd(region_ent + (size_t)row * CH + n * 16 + l15,
                                0.2f * acc[n][j]);
        }
    }
}

// =========================================================================
// VALU region GEMM (tier-3 fallback only)
// =========================================================================
__global__ void region_gemm_kernel(const float* __restrict__ emb,
                                   const float* __restrict__ W,
                                   float* __restrict__ region_ent) {
    const int wave = threadIdx.x >> 6;
    const int c    = threadIdx.x & 63;
    const int rt   = blockIdx.x / KSPLIT;
    const int ks   = blockIdx.x - rt * KSPLIT;
    const int base = rt * 32 + wave * 8;
    if (base >= RN) return;

    const int k0 = (RN * ks) / KSPLIT;
    const int k1 = (RN * (ks + 1)) / KSPLIT;

    const float* wp[8];
#pragma unroll
    for (int r = 0; r < 8; ++r) {
        int row = base + r;
        if (row >= RN) row = RN - 1;
        row = __builtin_amdgcn_readfirstlane(row);
        wp[r] = W + (size_t)row * RN;
    }
    const float* ep = emb + (size_t)REGION_R0 * CH + c;

    float acc[8];
#pragma unroll
    for (int r = 0; r < 8; ++r) acc[r] = 0.0f;

    int k = k0;
    for (; k + 4 <= k1; k += 4) {
        const float e0 = ep[(size_t)(k + 0) * CH];
        const float e1 = ep[(size_t)(k + 1) * CH];
        const float e2 = ep[(size_t)(k + 2) * CH];
        const float e3 = ep[(size_t)(k + 3) * CH];
#pragma unroll
        for (int r = 0; r < 8; ++r) {
            const float* wr = wp[r];
            float a = acc[r];
            a = fmaf(wr[k + 0], e0, a);
            a = fmaf(wr[k + 1], e1, a);
            a = fmaf(wr[k + 2], e2, a);
            a = fmaf(wr[k + 3], e3, a);
            acc[r] = a;
        }
    }
    for (; k < k1; ++k) {
        const float e = ep[(size_t)k * CH];
#pragma unroll
        for (int r = 0; r < 8; ++r) acc[r] = fmaf(wp[r][k], e, acc[r]);
    }
#pragma unroll
    for (int r = 0; r < 8; ++r) {
        const int row = base + r;
        if (row < RN)
            unsafeAtomicAdd(region_ent + (size_t)row * CH + c, 0.2f * acc[r]);
    }
}

__device__ __forceinline__ float ent_val(const float* __restrict__ emb,
                                         const float* __restrict__ region_ent,
                                         int row, int c) {
    const float* p = (row >= REGION_R0 && row < REGION_R1)
                         ? (region_ent + (size_t)(row - REGION_R0) * CH + c)
                         : (emb + (size_t)row * CH + c);
    return *p;
}

__device__ __forceinline__ const float* ent_row(const float* __restrict__ emb,
                                                const float* __restrict__ region_ent,
                                                int row) {
    return (row >= REGION_R0 && row < REGION_R1)
               ? (region_ent + (size_t)(row - REGION_R0) * CH)
               : (emb + (size_t)row * CH);
}

// =========================================================================
// bf16 entity table (region rows baked in)
// =========================================================================
__global__ void build_ebf_kernel(const float* __restrict__ emb,
                                 const float* __restrict__ region_ent,
                                 ushort_t* __restrict__ ebf,
                                 int n_entities) {
    const int gid = blockIdx.x * blockDim.x + threadIdx.x;
    if (gid >= n_entities * (CH / 8)) return;
    const int row = gid >> 3;
    const int co  = (gid & 7) * 8;
    const float* rp = ent_row(emb, region_ent, row) + co;
    const float4 a = *reinterpret_cast<const float4*>(rp);
    const float4 b = *reinterpret_cast<const float4*>(rp + 4);
    uint4 o;
    o.x = pack2bf(a.x, a.y);
    o.y = pack2bf(a.z, a.w);
    o.z = pack2bf(b.x, b.y);
    o.w = pack2bf(b.z, b.w);
    *reinterpret_cast<uint4*>(ebf + (size_t)row * CH + co) = o;
}

__device__ __forceinline__ float bf_lo(unsigned u) { return __uint_as_float(u << 16); }
__device__ __forceinline__ float bf_hi(unsigned u) { return __uint_as_float(u & 0xffff0000u); }

// =========================================================================
// Bucket partition (R17-proven pass1/pass2: exclusive (bucket,block) runs
// -> write-combined). bucket = key>>6.  hist[bucket*NB + block].
// =========================================================================
__global__ void bucket_hist_kernel(const int* __restrict__ keys,
                                   int* __restrict__ hist, int n, int nbuk) {
    __shared__ int lh[MAXBUK];
    for (int i = threadIdx.x; i < nbuk; i += T1) lh[i] = 0;
    __syncthreads();
    const int chunk = (n + NB - 1) / NB;
    const int i0 = blockIdx.x * chunk;
    const int i1 = min(i0 + chunk, n);
    for (int i = i0 + (int)threadIdx.x; i < i1; i += T1)
        atomicAdd(&lh[keys[i] >> 6], 1);
    __syncthreads();
    for (int b = threadIdx.x; b < nbuk; b += T1)
        hist[(size_t)b * NB + blockIdx.x] = lh[b];
}

__global__ void scan_block_kernel(const int* __restrict__ counts, int* __restrict__ offs,
                                  int* __restrict__ bsums, int n) {
    __shared__ int s[SCAN_B];
    const int i = blockIdx.x * SCAN_B + threadIdx.x;
    s[threadIdx.x] = (i < n) ? counts[i] : 0;
    __syncthreads();
    for (int d = 1; d < SCAN_B; d <<= 1) {
        const int t = (threadIdx.x >= d) ? s[threadIdx.x - d] : 0;
        __syncthreads();
        s[threadIdx.x] += t;
        __syncthreads();
    }
    if (i < n) offs[i + 1] = s[threadIdx.x];
    if (threadIdx.x == SCAN_B - 1) bsums[blockIdx.x] = s[threadIdx.x];
    if (blockIdx.x == 0 && threadIdx.x == 0) offs[0] = 0;
}

__global__ void scan_top_kernel(int* __restrict__ bsums, int nb) {
    __shared__ int s[512];
    s[threadIdx.x] = (threadIdx.x < (unsigned)nb) ? bsums[threadIdx.x] : 0;
    __syncthreads();
    for (int d = 1; d < 512; d <<= 1) {
        const int t = (threadIdx.x >= d) ? s[threadIdx.x - d] : 0;
        __syncthreads();
        s[threadIdx.x] += t;
        __syncthreads();
    }
    if (threadIdx.x < (unsigned)nb) bsums[threadIdx.x] = s[threadIdx.x];
}

__global__ void scan_add_kernel(int* __restrict__ offs, const int* __restrict__ bsums, int n) {
    if (blockIdx.x == 0) return;
    const int i = blockIdx.x * SCAN_B + threadIdx.x;
    if (i < n) offs[i + 1] += bsums[blockIdx.x - 1];
}

// pcode_e = (lh<<22)|(rel<<17)|tail  (lh=h&63)
__global__ void pass2_edges_kernel(const int* __restrict__ edge_index,
                                   const int* __restrict__ edge_type,
                                   const int* __restrict__ exbase,
                                   int* __restrict__ pcode,
                                   int E, int n_rel) {
    __shared__ int cur[MAXBUK];
    for (int i = threadIdx.x; i < MAXBUK; i += T1) cur[i] = 0;
    __syncthreads();
    const int chunk = (E + NB - 1) / NB;
    const int i0 = blockIdx.x * chunk;
    const int i1 = min(i0 + chunk, E);
    for (int e = i0 + (int)threadIdx.x; e < i1; e += T1) {
        const int h = edge_index[e];
        const int b = h >> 6;
        const int loc = atomicAdd(&cur[b], 1);
        const int pos = exbase[(size_t)b * NB + blockIdx.x] + loc;
        const int t = edge_index[(size_t)E + e];
        int r = edge_type[e] - 1;
        if (r < 0) r += n_rel;
        pcode[pos] = ((h & 63) << 22) | (r << 17) | t;
    }
}

// pcode_u = { (lr<<17)|col , bits(val) }
__global__ void pass2_users_kernel(const int* __restrict__ irows,
                                   const int* __restrict__ icols,
                                   const float* __restrict__ ivals,
                                   const int* __restrict__ exbase,
                                   uint2* __restrict__ pcode,
                                   int NNZ) {
    __shared__ int cur[MAXBUK];
    for (int i = threadIdx.x; i < MAXBUK; i += T1) cur[i] = 0;
    __syncthreads();
    const int chunk = (NNZ + NB - 1) / NB;
    const int i0 = blockIdx.x * chunk;
    const int i1 = min(i0 + chunk, NNZ);
    for (int i = i0 + (int)threadIdx.x; i < i1; i += T1) {
        const int u = irows[i];
        const int b = u >> 6;
        const int loc = atomicAdd(&cur[b], 1);
        const int pos = exbase[(size_t)b * NB + blockIdx.x] + loc;
        uint2 cv;
        cv.x = ((unsigned)(u & 63) << 17) | (unsigned)icols[i];
        cv.y = __float_as_uint(ivals[i]);
        pcode[pos] = cv;
    }
}

// =========================================================================
// Per-bucket LDS counting sort: bucket range is contiguous in pcode (read
// twice, cheap); output sorted-by-head runs + per-head offs. All stores land
// in a ~4KB window owned exclusively by this block -> write-combined.
// =========================================================================
__global__ void bucket_sort_e_kernel(const int* __restrict__ pcode,
                                     const int* __restrict__ exbase,
                                     int* __restrict__ sorted_tr,
                                     int* __restrict__ offs_e,
                                     int n_entities, int nbuk) {
    __shared__ int cnt[64];
    __shared__ int off[64];
    __shared__ int cur[64];
    const int b = blockIdx.x;
    const int bstart = exbase[(size_t)b * NB];
    const int bend   = exbase[(size_t)(b + 1) * NB];
    if (threadIdx.x < 64) { cnt[threadIdx.x] = 0; cur[threadIdx.x] = 0; }
    __syncthreads();
    for (int i = bstart + (int)threadIdx.x; i < bend; i += blockDim.x)
        atomicAdd(&cnt[(pcode[i] >> 22) & 63], 1);
    __syncthreads();
    if (threadIdx.x == 0) {
        int s = 0;
#pragma unroll
        for (int i = 0; i < 64; ++i) { off[i] = s; s += cnt[i]; }
    }
    __syncthreads();
    const int h0 = b * 64;
    if (threadIdx.x < 64) {
        const int h = h0 + (int)threadIdx.x;
        if (h < n_entities) offs_e[h] = bstart + off[threadIdx.x];
    }
    if (b == nbuk - 1 && threadIdx.x == 0) offs_e[n_entities] = bend;
    for (int i = bstart + (int)threadIdx.x; i < bend; i += blockDim.x) {
        const int p  = pcode[i];
        const int lh = (p >> 22) & 63;
        const int pos = bstart + off[lh] + atomicAdd(&cur[lh], 1);
        sorted_tr[pos] = p & 0x3FFFFF;          // tail | rel<<17
    }
}

__global__ void bucket_sort_u_kernel(const uint2* __restrict__ pcode,
                                     const int* __restrict__ exbase,
                                     uint2* __restrict__ upack,
                                     int* __restrict__ offs_u,
                                     int n_users, int nbuk) {
    __shared__ int cnt[64];
    __shared__ int off[64];
    __shared__ int cur[64];
    const int b = blockIdx.x;
    const int bstart = exbase[(size_t)b * NB];
    const int bend   = exbase[(size_t)(b + 1) * NB];
    if (threadIdx.x < 64) { cnt[threadIdx.x] = 0; cur[threadIdx.x] = 0; }
    __syncthreads();
    for (int i = bstart + (int)threadIdx.x; i < bend; i += blockDim.x)
        atomicAdd(&cnt[(pcode[i].x >> 17) & 63], 1);
    __syncthreads();
    if (threadIdx.x == 0) {
        int s = 0;
#pragma unroll
        for (int i = 0; i < 64; ++i) { off[i] = s; s += cnt[i]; }
    }
    __syncthreads();
    const int u0 = b * 64;
    if (threadIdx.x < 64) {
        const int u = u0 + (int)threadIdx.x;
        if (u < n_users) offs_u[u] = bstart + off[threadIdx.x];
    }
    if (b == nbuk - 1 && threadIdx.x == 0) offs_u[n_users] = bend;
    for (int i = bstart + (int)threadIdx.x; i < bend; i += blockDim.x) {
        const uint2 cv = pcode[i];
        const int lr = (int)(cv.x >> 17) & 63;
        const int pos = bstart + off[lr] + atomicAdd(&cur[lr], 1);
        uint2 o;
        o.x = cv.x & 0x1FFFFu;
        o.y = cv.y;
        upack[pos] = o;
    }
}

// =========================================================================
// bf16 gather kernels (R14-proven: x2 unroll, plain loads, 83us)
// =========================================================================
__global__ void kg_gather_bf_kernel(const ushort_t* __restrict__ ebf,
                                    const int* __restrict__ sorted_tr,
                                    const int* __restrict__ offs,
                                    const float* __restrict__ weight,
                                    float* __restrict__ out_ent,
                                    int n_entities, int n_rel) {
    extern __shared__ float wl[];   // n_rel * CH
    for (int i = threadIdx.x; i < n_rel * CH; i += blockDim.x) wl[i] = weight[i];
    __syncthreads();
    const float4* wl4 = reinterpret_cast<const float4*>(wl);

    const int wid  = (blockIdx.x * blockDim.x + threadIdx.x) >> 6;
    const int lane = threadIdx.x & 63;
    const int g    = lane >> 4;
    const int q    = lane & 15;
    if (wid >= n_entities) return;

    const int s0 = offs[wid], s1 = offs[wid + 1];
    float ax = 0.0f, ay = 0.0f, az = 0.0f, aw = 0.0f;
    float bx = 0.0f, by = 0.0f, bz = 0.0f, bw = 0.0f;

    int base = s0;
    for (; base + 8 <= s1; base += 8) {
        const int tr0 = sorted_tr[base + g];
        const int tr1 = sorted_tr[base + 4 + g];
        const uint2 p0 = *reinterpret_cast<const uint2*>(
            ebf + (size_t)(tr0 & 0x1FFFF) * CH + q * 4);
        const uint2 p1 = *reinterpret_cast<const uint2*>(
            ebf + (size_t)(tr1 & 0x1FFFF) * CH + q * 4);
        const float4 w0 = wl4[(tr0 >> 17) * 16 + q];
        const float4 w1 = wl4[(tr1 >> 17) * 16 + q];
        ax = fmaf(bf_lo(p0.x), w0.x, ax);
        ay = fmaf(bf_hi(p0.x), w0.y, ay);
        az = fmaf(bf_lo(p0.y), w0.z, az);
        aw = fmaf(bf_hi(p0.y), w0.w, aw);
        bx = fmaf(bf_lo(p1.x), w1.x, bx);
        by = fmaf(bf_hi(p1.x), w1.y, by);
        bz = fmaf(bf_lo(p1.y), w1.z, bz);
        bw = fmaf(bf_hi(p1.y), w1.w, bw);
    }
    for (; base < s1; base += 4) {
        const int e = base + g;
        const bool valid = (e < s1);
        const int tr = valid ? sorted_tr[e] : 0;
        uint2 p;
        if (valid) {
            p = *reinterpret_cast<const uint2*>(
                ebf + (size_t)(tr & 0x1FFFF) * CH + q * 4);
        } else { p.x = 0u; p.y = 0u; }
        const float4 wv = wl4[(tr >> 17) * 16 + q];
        ax = fmaf(bf_lo(p.x), wv.x, ax);
        ay = fmaf(bf_hi(p.x), wv.y, ay);
        az = fmaf(bf_lo(p.y), wv.z, az);
        aw = fmaf(bf_hi(p.y), wv.w, aw);
    }
    ax += bx; ay += by; az += bz; aw += bw;

    ax += __shfl_xor(ax, 16); ay += __shfl_xor(ay, 16);
    az += __shfl_xor(az, 16); aw += __shfl_xor(aw, 16);
    ax += __shfl_xor(ax, 32); ay += __shfl_xor(ay, 32);
    az += __shfl_xor(az, 32); aw += __shfl_xor(aw, 32);

    if (g == 0) {
        const int deg = s1 - s0;
        const float inv = 1.0f / (float)(deg > 0 ? deg : 1);
        float4 o;
        o.x = ax * inv; o.y = ay * inv; o.z = az * inv; o.w = aw * inv;
        reinterpret_cast<float4*>(out_ent + (size_t)wid * CH)[q] = o;
    }
}

__global__ void user_gather_bf_kernel(const ushort_t* __restrict__ ebf,
                                      const uint2* __restrict__ upack,
                                      const int* __restrict__ offs,
                                      float* __restrict__ out_user,
                                      int n_users) {
    const int wid  = (blockIdx.x * blockDim.x + threadIdx.x) >> 6;
    const int lane = threadIdx.x & 63;
    const int g    = lane >> 4;
    const int q    = lane & 15;
    if (wid >= n_users) return;

    const int s0 = offs[wid], s1 = offs[wid + 1];
    float ax = 0.0f, ay = 0.0f, az = 0.0f, aw = 0.0f;
    float bx = 0.0f, by = 0.0f, bz = 0.0f, bw = 0.0f;

    int base = s0;
    for (; base + 8 <= s1; base += 8) {
        const uint2 cv0 = upack[base + g];
        const uint2 cv1 = upack[base + 4 + g];
        const float v0 = __uint_as_float(cv0.y);
        const float v1 = __uint_as_float(cv1.y);
        const uint2 p0 = *reinterpret_cast<const uint2*>(
            ebf + (size_t)cv0.x * CH + q * 4);
        const uint2 p1 = *reinterpret_cast<const uint2*>(
            ebf + (size_t)cv1.x * CH + q * 4);
        ax = fmaf(v0, bf_lo(p0.x), ax);
        ay = fmaf(v0, bf_hi(p0.x), ay);
        az = fmaf(v0, bf_lo(p0.y), az);
        aw = fmaf(v0, bf_hi(p0.y), aw);
        bx = fmaf(v1, bf_lo(p1.x), bx);
        by = fmaf(v1, bf_hi(p1.x), by);
        bz = fmaf(v1, bf_lo(p1.y), bz);
        bw = fmaf(v1, bf_hi(p1.y), bw);
    }
    for (; base < s1; base += 4) {
        const int e = base + g;
        const bool valid = (e < s1);
        uint2 cv;
        if (valid) cv = upack[e];
        else       { cv.x = 0u; cv.y = 0u; }
        const float v = __uint_as_float(cv.y);
        const uint2 p = *reinterpret_cast<const uint2*>(
            ebf + (size_t)cv.x * CH + q * 4);
        ax = fmaf(v, bf_lo(p.x), ax);
        ay = fmaf(v, bf_hi(p.x), ay);
        az = fmaf(v, bf_lo(p.y), az);
        aw = fmaf(v, bf_hi(p.y), aw);
    }
    ax += bx; ay += by; az += bz; aw += bw;

    ax += __shfl_xor(ax, 16); ay += __shfl_xor(ay, 16);
    az += __shfl_xor(az, 16); aw += __shfl_xor(aw, 16);
    ax += __shfl_xor(ax, 32); ay += __shfl_xor(ay, 32);
    az += __shfl_xor(az, 32); aw += __shfl_xor(aw, 32);

    if (g == 0) {
        float4 o; o.x = ax; o.y = ay; o.z = az; o.w = aw;
        reinterpret_cast<float4*>(out_user + (size_t)wid * CH)[q] = o;
    }
}

// =========================================================================
// Tier-2 (R14 CSR path): sliced hist/scatter (plain loads)
// =========================================================================
__global__ void hist_sliced_kernel(const int* __restrict__ keys,
                                   int* __restrict__ counts, int n, unsigned smul) {
    const int slice = blockIdx.x & (NSLICE - 1);
    const int rb    = blockIdx.x >> 3;
    const int nrb   = gridDim.x >> 3;
    const int per   = (n + nrb - 1) / nrb;
    const int i0    = rb * per;
    const int i1    = min(i0 + per, n);
    for (int i = i0 + (int)threadIdx.x; i < i1; i += blockDim.x) {
        const int k = keys[i];
        if ((int)__umulhi((unsigned)k, smul) == slice)
            atomicAdd(&counts[k], 1);
    }
}

__global__ void scatter_e_sliced_kernel(const int* __restrict__ edge_index,
                                        const int* __restrict__ edge_type,
                                        const int* __restrict__ offs,
                                        int* __restrict__ cursor,
                                        int* __restrict__ sorted_tr,
                                        int E, int n_rel, unsigned smul) {
    const int slice = blockIdx.x & (NSLICE - 1);
    const int rb    = blockIdx.x >> 3;
    const int nrb   = gridDim.x >> 3;
    const int per   = (E + nrb - 1) / nrb;
    const int e0    = rb * per;
    const int e1    = min(e0 + per, E);
    for (int e = e0 + (int)threadIdx.x; e < e1; e += blockDim.x) {
        const int h = edge_index[e];
        if ((int)__umulhi((unsigned)h, smul) != slice) continue;
        const int t = edge_index[(size_t)E + e];
        int r = edge_type[e] - 1;
        if (r < 0) r += n_rel;
        const int pos = offs[h] + atomicAdd(&cursor[h], 1);
        sorted_tr[pos] = t | (r << 17);
    }
}

__global__ void scatter_u_sliced_kernel(const int* __restrict__ irows,
                                        const int* __restrict__ icols,
                                        const float* __restrict__ ivals,
                                        const int* __restrict__ offs,
                                        int* __restrict__ cursor,
                                        uint2* __restrict__ upack,
                                        int NNZ, unsigned smul) {
    const int slice = blockIdx.x & (NSLICE - 1);
    const int rb    = blockIdx.x >> 3;
    const int nrb   = gridDim.x >> 3;
    const int per   = (NNZ + nrb - 1) / nrb;
    const int i0    = rb * per;
    const int i1    = min(i0 + per, NNZ);
    for (int i = i0 + (int)threadIdx.x; i < i1; i += blockDim.x) {
        const int u = irows[i];
        if ((int)__umulhi((unsigned)u, smul) != slice) continue;
        const int pos = offs[u] + atomicAdd(&cursor[u], 1);
        uint2 cv;
        cv.x = (unsigned)icols[i];
        cv.y = __float_as_uint(ivals[i]);
        upack[pos] = cv;
    }
}

// =========================================================================
// Tier-3 (atomic fallback)
// =========================================================================
__global__ void kg_agg_atomic_kernel(const float* __restrict__ emb,
                                     const float* __restrict__ region_ent,
                                     const int* __restrict__ edge_index,
                                     const int* __restrict__ edge_type,
                                     const float* __restrict__ weight,
                                     float* __restrict__ out_ent,
                                     float* __restrict__ counts,
                                     int E, int n_rel) {
    const long long gid = (long long)blockIdx.x * blockDim.x + threadIdx.x;
    const long long e = gid >> 6;
    if (e >= E) return;
    const int c = (int)gid & 63;
    const int h = edge_index[e];
    const int t = edge_index[(size_t)E + e];
    int r = edge_type[e] - 1;
    if (r < 0) r += n_rel;
    const float v = ent_val(emb, region_ent, t, c) * weight[(size_t)r * CH + c];
    unsafeAtomicAdd(out_ent + (size_t)h * CH + c, v);
    if (c == 0) unsafeAtomicAdd(counts + h, 1.0f);
}

__global__ void user_agg_atomic_kernel(const float* __restrict__ emb,
                                       const float* __restrict__ region_ent,
                                       const int* __restrict__ irows,
                                       const int* __restrict__ icols,
                                       const float* __restrict__ ivals,
                                       float* __restrict__ out_user, int NNZ) {
    const long long gid = (long long)blockIdx.x * blockDim.x + threadIdx.x;
    const long long i = gid >> 6;
    if (i >= NNZ) return;
    const int c = (int)gid & 63;
    const float v = ivals[i] * ent_val(emb, region_ent, icols[i], c);
    unsafeAtomicAdd(out_user + (size_t)irows[i] * CH + c, v);
}

__global__ void finalize_kernel(float* __restrict__ out_ent,
                                const float* __restrict__ counts, int n_entities) {
    const int gid = blockIdx.x * blockDim.x + threadIdx.x;
    if (gid >= n_entities * CH) return;
    out_ent[gid] /= fmaxf(counts[gid >> 6], 1.0f);
}

// =========================================================================
extern "C" void kernel_launch(void* const* d_in, const int* in_sizes, int n_in,
                              void* d_out, int out_size, void* d_ws, size_t ws_size,
                              hipStream_t stream) {
    const float* entity_emb = (const float*)d_in[0];
    const int*   edge_index = (const int*)d_in[2];
    const int*   edge_type  = (const int*)d_in[3];
    const int*   irows      = (const int*)d_in[4];
    const int*   icols      = (const int*)d_in[5];
    const float* ivals      = (const float*)d_in[6];
    const float* Wreg       = (const float*)d_in[7];
    const float* weight     = (const float*)d_in[8];

    const int n_entities = in_sizes[0] / CH;
    const int n_users    = in_sizes[1] / CH;
    const int E          = in_sizes[3];
    const int NNZ        = in_sizes[4];
    const int n_rel      = in_sizes[8] / CH;

    float* out_ent  = (float*)d_out;
    float* out_user = out_ent + (size_t)n_entities * CH;

    const int NBUK_E = (n_entities + 63) >> 6;
    const int NBUK_U = (n_users + 63) >> 6;
    const int n_e = NBUK_E * NB;
    const int n_u = NBUK_U * NB;
    const int nbse = (n_e + SCAN_B - 1) / SCAN_B;
    const int nbsu = (n_u + SCAN_B - 1) / SCAN_B;

    // ---- tier-1 (bucket) layout ----
    char* w = (char*)d_ws;
    auto take = [&](size_t bytes) {
        char* p = w;
        w += (bytes + 7) & ~(size_t)7;
        return p;
    };
    float*    region_ent = (float*)take((size_t)RN * CH * 4);
    ushort_t* e_t        = (ushort_t*)take((size_t)CH * KP * 2);
    ushort_t* ebf        = (ushort_t*)take((size_t)n_entities * CH * 2);
    int*      sorted_tr  = (int*)take((size_t)E * 4);
    uint2*    upack      = (uint2*)take((size_t)NNZ * 8);
    int*      offs_e     = (int*)take((size_t)(n_entities + 1) * 4);
    int*      offs_u     = (int*)take((size_t)(n_users + 1) * 4);
    int*      bsums      = (int*)take(512 * 4);
    int*      hist_e     = (int*)take((size_t)n_e * 4);
    int*      exbase_e   = (int*)take((size_t)(n_e + 1) * 4);
    int*      hist_u     = (int*)take((size_t)n_u * 4);
    int*      exbase_u   = (int*)take((size_t)(n_u + 1) * 4);
    int*      pcode_e    = (int*)take((size_t)E * 4);
    uint2*    pcode_u    = (uint2*)take((size_t)NNZ * 8);
    const size_t need_bucket = (size_t)(w - (char*)d_ws);

    const bool common_ok = (n_entities < (1 << 17)) && (n_rel <= 32);
    const bool use_bucket = common_ok && (ws_size >= need_bucket) &&
                            (NBUK_E <= MAXBUK) && (NBUK_U <= MAXBUK) &&
                            (nbse <= 512) && (nbsu <= 512);

    // ---- tier-2 (csr) layout (R14-proven ~29.4MB) ----
    char* w2 = (char*)d_ws;
    auto take2 = [&](size_t bytes) {
        char* p = w2;
        w2 += (bytes + 7) & ~(size_t)7;
        return p;
    };
    float*    c_region  = (float*)take2((size_t)RN * CH * 4);
    int*      c_offs_e  = (int*)take2((size_t)(n_entities + 1) * 4);
    int*      c_cur_e   = (int*)take2((size_t)n_entities * 4);
    int*      c_offs_u  = (int*)take2((size_t)(n_users + 1) * 4);
    int*      c_cur_u   = (int*)take2((size_t)n_users * 4);
    int*      c_bsums   = (int*)take2(512 * 4);
    int*      c_sorted  = (int*)take2((size_t)E * 4);
    uint2*    c_upack   = (uint2*)take2((size_t)NNZ * 8);
    ushort_t* c_et      = (ushort_t*)take2((size_t)CH * KP * 2);
    ushort_t* c_ebf     = (ushort_t*)take2((size_t)n_entities * CH * 2);
    const size_t need_csr = (size_t)(w2 - (char*)d_ws);
    const int nb_e = (n_entities + SCAN_B - 1) / SCAN_B;
    const int nb_u = (n_users + SCAN_B - 1) / SCAN_B;
    const bool use_csr = common_ok && (ws_size >= need_csr) &&
                         (nb_e <= 512) && (nb_u <= 512);

    if (use_bucket) {
        region_init_kernel<<<(RN * CH / 4 + 255) / 256, 256, 0, stream>>>(entity_emb, region_ent);
        {
            const int tot = CH * (KP / 8);
            build_et_kernel<<<(tot + 255) / 256, 256, 0, stream>>>(entity_emb, e_t);
        }
        region_gemm_mfma_kernel<<<MT_BLKS * KCHUNKS, 256, 0, stream>>>(
            Wreg, e_t, region_ent);
        {
            const int tot = n_entities * (CH / 8);
            build_ebf_kernel<<<(tot + 255) / 256, 256, 0, stream>>>(
                entity_emb, region_ent, ebf, n_entities);
        }

        // edges: hist -> scan -> pass2 -> per-bucket sort
        bucket_hist_kernel<<<NB, T1, 0, stream>>>(edge_index, hist_e, E, NBUK_E);
        scan_block_kernel<<<nbse, SCAN_B, 0, stream>>>(hist_e, exbase_e, bsums, n_e);
        scan_top_kernel<<<1, 512, 0, stream>>>(bsums, nbse);
        scan_add_kernel<<<nbse, SCAN_B, 0, stream>>>(exbase_e, bsums, n_e);
        pass2_edges_kernel<<<NB, T1, 0, stream>>>(
            edge_index, edge_type, exbase_e, pcode_e, E, n_rel);
        bucket_sort_e_kernel<<<NBUK_E, 256, 0, stream>>>(
            pcode_e, exbase_e, sorted_tr, offs_e, n_entities, NBUK_E);

        // users
        bucket_hist_kernel<<<NB, T1, 0, stream>>>(irows, hist_u, NNZ, NBUK_U);
        scan_block_kernel<<<nbsu, SCAN_B, 0, stream>>>(hist_u, exbase_u, bsums, n_u);
        scan_top_kernel<<<1, 512, 0, stream>>>(bsums, nbsu);
        scan_add_kernel<<<nbsu, SCAN_B, 0, stream>>>(exbase_u, bsums, n_u);
        pass2_users_kernel<<<NB, T1, 0, stream>>>(
            irows, icols, ivals, exbase_u, pcode_u, NNZ);
        bucket_sort_u_kernel<<<NBUK_U, 256, 0, stream>>>(
            pcode_u, exbase_u, upack, offs_u, n_users, NBUK_U);

        // gathers (R14-proven)
        kg_gather_bf_kernel<<<(n_entities + 3) / 4, 256, n_rel * CH * 4, stream>>>(
            ebf, sorted_tr, offs_e, weight, out_ent, n_entities, n_rel);
        user_gather_bf_kernel<<<(n_users + 3) / 4, 256, 0, stream>>>(
            ebf, upack, offs_u, out_user, n_users);
    } else if (use_csr) {
        const unsigned smul_e = (unsigned)((8ULL << 32) / (unsigned long long)n_entities);
        const unsigned smul_u = (unsigned)((8ULL << 32) / (unsigned long long)n_users);

        region_init_kernel<<<(RN * CH / 4 + 255) / 256, 256, 0, stream>>>(entity_emb, c_region);
        {
            const int tot = CH * (KP / 8);
            build_et_kernel<<<(tot + 255) / 256, 256, 0, stream>>>(entity_emb, c_et);
        }
        region_gemm_mfma_kernel<<<MT_BLKS * KCHUNKS, 256, 0, stream>>>(
            Wreg, c_et, c_region);
        {
            const int tot = n_entities * (CH / 8);
            build_ebf_kernel<<<(tot + 255) / 256, 256, 0, stream>>>(
                entity_emb, c_region, c_ebf, n_entities);
        }

        hipMemsetAsync(c_cur_e, 0, (size_t)n_entities * 4, stream);
        hipMemsetAsync(c_cur_u, 0, (size_t)n_users * 4, stream);
        hist_sliced_kernel<<<NSLICE * SLICE_RB, 256, 0, stream>>>(
            edge_index, c_cur_e, E, smul_e);
        hist_sliced_kernel<<<NSLICE * SLICE_RB, 256, 0, stream>>>(
            irows, c_cur_u, NNZ, smul_u);

        scan_block_kernel<<<nb_e, SCAN_B, 0, stream>>>(c_cur_e, c_offs_e, c_bsums, n_entities);
        scan_top_kernel<<<1, 512, 0, stream>>>(c_bsums, nb_e);
        scan_add_kernel<<<nb_e, SCAN_B, 0, stream>>>(c_offs_e, c_bsums, n_entities);

        scan_block_kernel<<<nb_u, SCAN_B, 0, stream>>>(c_cur_u, c_offs_u, c_bsums, n_users);
        scan_top_kernel<<<1, 512, 0, stream>>>(c_bsums, nb_u);
        scan_add_kernel<<<nb_u, SCAN_B, 0, stream>>>(c_offs_u, c_bsums, n_users);

        hipMemsetAsync(c_cur_e, 0, (size_t)n_entities * 4, stream);
        hipMemsetAsync(c_cur_u, 0, (size_t)n_users * 4, stream);
        scatter_e_sliced_kernel<<<NSLICE * SLICE_RB, 256, 0, stream>>>(
            edge_index, edge_type, c_offs_e, c_cur_e, c_sorted, E, n_rel, smul_e);
        scatter_u_sliced_kernel<<<NSLICE * SLICE_RB, 256, 0, stream>>>(
            irows, icols, ivals, c_offs_u, c_cur_u, c_upack, NNZ, smul_u);

        kg_gather_bf_kernel<<<(n_entities + 3) / 4, 256, n_rel * CH * 4, stream>>>(
            c_ebf, c_sorted, c_offs_e, weight, out_ent, n_entities, n_rel);
        user_gather_bf_kernel<<<(n_users + 3) / 4, 256, 0, stream>>>(
            c_ebf, c_upack, c_offs_u, out_user, n_users);
    } else {
        // tier-3: atomic fallback
        float* region3 = (float*)d_ws;
        float* counts  = region3 + (size_t)RN * CH;
        region_init_kernel<<<(RN * CH / 4 + 255) / 256, 256, 0, stream>>>(entity_emb, region3);
        region_gemm_kernel<<<ROW_TILES * KSPLIT, 256, 0, stream>>>(
            entity_emb, Wreg, region3);
        hipMemsetAsync(d_out, 0, (size_t)out_size * sizeof(float), stream);
        hipMemsetAsync(counts, 0, (size_t)n_entities * sizeof(float), stream);
        {
            const long long tot = (long long)E * CH;
            kg_agg_atomic_kernel<<<(int)((tot + 255) / 256), 256, 0, stream>>>(
                entity_emb, region3, edge_index, edge_type, weight,
                out_ent, counts, E, n_rel);
        }
        {
            const long long tot = (long long)NNZ * CH;
            user_agg_atomic_kernel<<<(int)((tot + 255) / 256), 256, 0, stream>>>(
                entity_emb, region3, irows, icols, ivals, out_user, NNZ);
        }
        finalize_kernel<<<(n_entities * CH + 255) / 256, 256, 0, stream>>>(
            out_ent, counts, n_entities);
    }
}

// Round 20
// 242.135 us; speedup vs baseline: 4.9149x; 1.1748x over previous
//
#include <hip/hip_runtime.h>
#include <hip/hip_bf16.h>

// Problem constants (from reference source)
#define REGION_R0 42033
#define REGION_R1 44630
#define RN        (REGION_R1 - REGION_R0)   // 2597
#define CH        64
#define KSPLIT    32
#define ROW_TILES ((RN + 31) / 32)          // 82
#define SCAN_B    256
#define NSLICE    8
#define SLICE_RB  256                        // tier-2 grid (R14-proven)

// bucket partition geometry
#define NB        64                         // range-blocks: keeps 16-entry (64B) exclusive runs
#define T1        1024                       // R20: 512 -> 1024 (16 waves/block latency cover)
#define MAXBUK    2048

// MFMA region-gemm geometry
#define KTT       82
#define KP        (KTT * 32)                 // 2624
#define PERCHUNK  6
#define KCHUNKS   14
#define MT_TILES  163
#define MT_BLKS   41

typedef unsigned short ushort_t;
typedef short  bfrag8 __attribute__((ext_vector_type(8)));
typedef float  f32x4v __attribute__((ext_vector_type(4)));

// =========================================================================
// Region blend init (region_ent = 0.8 * orig)
// =========================================================================
__global__ void region_init_kernel(const float* __restrict__ emb,
                                   float* __restrict__ region_ent) {
    const int gid = blockIdx.x * blockDim.x + threadIdx.x;
    if (gid >= RN * CH / 4) return;
    const float4 v = reinterpret_cast<const float4*>(emb + (size_t)REGION_R0 * CH)[gid];
    float4 o;
    o.x = 0.8f * v.x; o.y = 0.8f * v.y; o.z = 0.8f * v.z; o.w = 0.8f * v.w;
    reinterpret_cast<float4*>(region_ent)[gid] = o;
}

__device__ __forceinline__ unsigned pack2bf(float a, float b) {
    unsigned ua = __float_as_uint(a);
    unsigned ub = __float_as_uint(b);
    ua += 0x7fffu + ((ua >> 16) & 1u);   // RNE
    ub += 0x7fffu + ((ub >> 16) & 1u);
    return ((ua >> 16) & 0xffffu) | (ub & 0xffff0000u);
}

// =========================================================================
// e_t[c][k] = bf16(emb[R0+k][c]) (B operand, transposed, zero-padded)
// =========================================================================
__global__ void build_et_kernel(const float* __restrict__ emb,
                                ushort_t* __restrict__ e_t) {
    const int gid = blockIdx.x * blockDim.x + threadIdx.x;
    if (gid >= CH * (KP / 8)) return;
    const int c  = gid / (KP / 8);
    const int k8 = gid - c * (KP / 8);
    const int kb = k8 * 8;
    float v[8];
#pragma unroll
    for (int j = 0; j < 8; ++j) {
        const int k = kb + j;
        v[j] = (k < RN) ? emb[(size_t)(REGION_R0 + k) * CH + c] : 0.0f;
    }
    uint4 o;
    o.x = pack2bf(v[0], v[1]); o.y = pack2bf(v[2], v[3]);
    o.z = pack2bf(v[4], v[5]); o.w = pack2bf(v[6], v[7]);
    *reinterpret_cast<uint4*>(e_t + (size_t)c * KP + kb) = o;
}

// =========================================================================
// MFMA region GEMM (R14-verified, absmax 0.25)
// =========================================================================
__global__ void region_gemm_mfma_kernel(const float* __restrict__ W,
                                        const ushort_t* __restrict__ e_t,
                                        float* __restrict__ region_ent) {
    const int wv    = threadIdx.x >> 6;
    const int lane  = threadIdx.x & 63;
    const int blk_m = blockIdx.x / KCHUNKS;
    const int kc    = blockIdx.x - blk_m * KCHUNKS;
    const int mt    = blk_m * 4 + wv;
    if (mt >= MT_TILES) return;
    const int l15 = lane & 15;
    const int lg  = lane >> 4;

    int arow = mt * 16 + l15;
    if (arow >= RN) arow = RN - 1;
    const float* wrow = W + (size_t)arow * RN;

    const int kt0 = kc * PERCHUNK;
    const int kt1 = (kt0 + PERCHUNK < KTT) ? (kt0 + PERCHUNK) : KTT;

    f32x4v acc[4];
#pragma unroll
    for (int n = 0; n < 4; ++n) acc[n] = (f32x4v){0.f, 0.f, 0.f, 0.f};

    for (int kt = kt0; kt < kt1; ++kt) {
        const int kb = kt * 32 + lg * 8;
        union { uint4 u; bfrag8 f; } A;
        if (kb + 8 <= RN) {
            float v0 = wrow[kb + 0], v1 = wrow[kb + 1];
            float v2 = wrow[kb + 2], v3 = wrow[kb + 3];
            float v4 = wrow[kb + 4], v5 = wrow[kb + 5];
            float v6 = wrow[kb + 6], v7 = wrow[kb + 7];
            A.u.x = pack2bf(v0, v1); A.u.y = pack2bf(v2, v3);
            A.u.z = pack2bf(v4, v5); A.u.w = pack2bf(v6, v7);
        } else {
            float v[8];
#pragma unroll
            for (int j = 0; j < 8; ++j) {
                const int k = kb + j;
                v[j] = (k < RN) ? wrow[k] : 0.0f;
            }
            A.u.x = pack2bf(v[0], v[1]); A.u.y = pack2bf(v[2], v[3]);
            A.u.z = pack2bf(v[4], v[5]); A.u.w = pack2bf(v[6], v[7]);
        }
#pragma unroll
        for (int n = 0; n < 4; ++n) {
            const bfrag8 B = *reinterpret_cast<const bfrag8*>(
                e_t + (size_t)(n * 16 + l15) * KP + kb);
            acc[n] = __builtin_amdgcn_mfma_f32_16x16x32_bf16(A.f, B, acc[n], 0, 0, 0);
        }
    }

#pragma unroll
    for (int n = 0; n < 4; ++n) {
#pragma unroll
        for (int j = 0; j < 4; ++j) {
            const int row = mt * 16 + lg * 4 + j;
            if (row < RN)
                unsafeAtomicAdd(region_ent + (size_t)row * CH + n * 16 + l15,
                                0.2f * acc[n][j]);
        }
    }
}

// =========================================================================
// VALU region GEMM (tier-3 fallback only)
// =========================================================================
__global__ void region_gemm_kernel(const float* __restrict__ emb,
                                   const float* __restrict__ W,
                                   float* __restrict__ region_ent) {
    const int wave = threadIdx.x >> 6;
    const int c    = threadIdx.x & 63;
    const int rt   = blockIdx.x / KSPLIT;
    const int ks   = blockIdx.x - rt * KSPLIT;
    const int base = rt * 32 + wave * 8;
    if (base >= RN) return;

    const int k0 = (RN * ks) / KSPLIT;
    const int k1 = (RN * (ks + 1)) / KSPLIT;

    const float* wp[8];
#pragma unroll
    for (int r = 0; r < 8; ++r) {
        int row = base + r;
        if (row >= RN) row = RN - 1;
        row = __builtin_amdgcn_readfirstlane(row);
        wp[r] = W + (size_t)row * RN;
    }
    const float* ep = emb + (size_t)REGION_R0 * CH + c;

    float acc[8];
#pragma unroll
    for (int r = 0; r < 8; ++r) acc[r] = 0.0f;

    int k = k0;
    for (; k + 4 <= k1; k += 4) {
        const float e0 = ep[(size_t)(k + 0) * CH];
        const float e1 = ep[(size_t)(k + 1) * CH];
        const float e2 = ep[(size_t)(k + 2) * CH];
        const float e3 = ep[(size_t)(k + 3) * CH];
#pragma unroll
        for (int r = 0; r < 8; ++r) {
            const float* wr = wp[r];
            float a = acc[r];
            a = fmaf(wr[k + 0], e0, a);
            a = fmaf(wr[k + 1], e1, a);
            a = fmaf(wr[k + 2], e2, a);
            a = fmaf(wr[k + 3], e3, a);
            acc[r] = a;
        }
    }
    for (; k < k1; ++k) {
        const float e = ep[(size_t)k * CH];
#pragma unroll
        for (int r = 0; r < 8; ++r) acc[r] = fmaf(wp[r][k], e, acc[r]);
    }
#pragma unroll
    for (int r = 0; r < 8; ++r) {
        const int row = base + r;
        if (row < RN)
            unsafeAtomicAdd(region_ent + (size_t)row * CH + c, 0.2f * acc[r]);
    }
}

__device__ __forceinline__ float ent_val(const float* __restrict__ emb,
                                         const float* __restrict__ region_ent,
                                         int row, int c) {
    const float* p = (row >= REGION_R0 && row < REGION_R1)
                         ? (region_ent + (size_t)(row - REGION_R0) * CH + c)
                         : (emb + (size_t)row * CH + c);
    return *p;
}

__device__ __forceinline__ const float* ent_row(const float* __restrict__ emb,
                                                const float* __restrict__ region_ent,
                                                int row) {
    return (row >= REGION_R0 && row < REGION_R1)
               ? (region_ent + (size_t)(row - REGION_R0) * CH)
               : (emb + (size_t)row * CH);
}

// =========================================================================
// bf16 entity table (region rows baked in)
// =========================================================================
__global__ void build_ebf_kernel(const float* __restrict__ emb,
                                 const float* __restrict__ region_ent,
                                 ushort_t* __restrict__ ebf,
                                 int n_entities) {
    const int gid = blockIdx.x * blockDim.x + threadIdx.x;
    if (gid >= n_entities * (CH / 8)) return;
    const int row = gid >> 3;
    const int co  = (gid & 7) * 8;
    const float* rp = ent_row(emb, region_ent, row) + co;
    const float4 a = *reinterpret_cast<const float4*>(rp);
    const float4 b = *reinterpret_cast<const float4*>(rp + 4);
    uint4 o;
    o.x = pack2bf(a.x, a.y);
    o.y = pack2bf(a.z, a.w);
    o.z = pack2bf(b.x, b.y);
    o.w = pack2bf(b.z, b.w);
    *reinterpret_cast<uint4*>(ebf + (size_t)row * CH + co) = o;
}

__device__ __forceinline__ float bf_lo(unsigned u) { return __uint_as_float(u << 16); }
__device__ __forceinline__ float bf_hi(unsigned u) { return __uint_as_float(u & 0xffff0000u); }

// =========================================================================
// Bucket partition. pass1: per-(block,bucket) histogram, LDS-accumulated.
// hist[bucket*NB + block]; bucket = key>>6.
// =========================================================================
__global__ void bucket_hist_kernel(const int* __restrict__ keys,
                                   int* __restrict__ hist, int n, int nbuk) {
    __shared__ int lh[MAXBUK];
    for (int i = threadIdx.x; i < nbuk; i += T1) lh[i] = 0;
    __syncthreads();
    const int chunk = (n + NB - 1) / NB;
    const int i0 = blockIdx.x * chunk;
    const int i1 = min(i0 + chunk, n);
    for (int i = i0 + (int)threadIdx.x; i < i1; i += T1)
        atomicAdd(&lh[keys[i] >> 6], 1);
    __syncthreads();
    for (int b = threadIdx.x; b < nbuk; b += T1)
        hist[(size_t)b * NB + blockIdx.x] = lh[b];
}

__global__ void scan_block_kernel(const int* __restrict__ counts, int* __restrict__ offs,
                                  int* __restrict__ bsums, int n) {
    __shared__ int s[SCAN_B];
    const int i = blockIdx.x * SCAN_B + threadIdx.x;
    s[threadIdx.x] = (i < n) ? counts[i] : 0;
    __syncthreads();
    for (int d = 1; d < SCAN_B; d <<= 1) {
        const int t = (threadIdx.x >= d) ? s[threadIdx.x - d] : 0;
        __syncthreads();
        s[threadIdx.x] += t;
        __syncthreads();
    }
    if (i < n) offs[i + 1] = s[threadIdx.x];
    if (threadIdx.x == SCAN_B - 1) bsums[blockIdx.x] = s[threadIdx.x];
    if (blockIdx.x == 0 && threadIdx.x == 0) offs[0] = 0;
}

__global__ void scan_top_kernel(int* __restrict__ bsums, int nb) {
    __shared__ int s[512];
    s[threadIdx.x] = (threadIdx.x < (unsigned)nb) ? bsums[threadIdx.x] : 0;
    __syncthreads();
    for (int d = 1; d < 512; d <<= 1) {
        const int t = (threadIdx.x >= d) ? s[threadIdx.x - d] : 0;
        __syncthreads();
        s[threadIdx.x] += t;
        __syncthreads();
    }
    if (threadIdx.x < (unsigned)nb) bsums[threadIdx.x] = s[threadIdx.x];
}

__global__ void scan_add_kernel(int* __restrict__ offs, const int* __restrict__ bsums, int n) {
    if (blockIdx.x == 0) return;
    const int i = blockIdx.x * SCAN_B + threadIdx.x;
    if (i < n) offs[i + 1] += bsums[blockIdx.x - 1];
}

// pcode_e = (lh<<22)|(rel<<17)|tail  (lh=h&63). exbase row cached in LDS.
__global__ void pass2_edges_kernel(const int* __restrict__ edge_index,
                                   const int* __restrict__ edge_type,
                                   const int* __restrict__ exbase,
                                   int* __restrict__ pcode,
                                   int E, int n_rel, int nbuk) {
    __shared__ int cur[MAXBUK];
    __shared__ int exb[MAXBUK];
    for (int i = threadIdx.x; i < nbuk; i += T1) {
        cur[i] = 0;
        exb[i] = exbase[(size_t)i * NB + blockIdx.x];
    }
    __syncthreads();
    const int chunk = (E + NB - 1) / NB;
    const int i0 = blockIdx.x * chunk;
    const int i1 = min(i0 + chunk, E);
    for (int e = i0 + (int)threadIdx.x; e < i1; e += T1) {
        const int h = edge_index[e];
        const int b = h >> 6;
        const int loc = atomicAdd(&cur[b], 1);
        const int pos = exb[b] + loc;
        const int t = edge_index[(size_t)E + e];
        int r = edge_type[e] - 1;
        if (r < 0) r += n_rel;
        pcode[pos] = ((h & 63) << 22) | (r << 17) | t;
    }
}

// pcode_u = { (lr<<17)|col , bits(val) }. exbase row cached in LDS.
__global__ void pass2_users_kernel(const int* __restrict__ irows,
                                   const int* __restrict__ icols,
                                   const float* __restrict__ ivals,
                                   const int* __restrict__ exbase,
                                   uint2* __restrict__ pcode,
                                   int NNZ, int nbuk) {
    __shared__ int cur[MAXBUK];
    __shared__ int exb[MAXBUK];
    for (int i = threadIdx.x; i < nbuk; i += T1) {
        cur[i] = 0;
        exb[i] = exbase[(size_t)i * NB + blockIdx.x];
    }
    __syncthreads();
    const int chunk = (NNZ + NB - 1) / NB;
    const int i0 = blockIdx.x * chunk;
    const int i1 = min(i0 + chunk, NNZ);
    for (int i = i0 + (int)threadIdx.x; i < i1; i += T1) {
        const int u = irows[i];
        const int b = u >> 6;
        const int loc = atomicAdd(&cur[b], 1);
        const int pos = exb[b] + loc;
        uint2 cv;
        cv.x = ((unsigned)(u & 63) << 17) | (unsigned)icols[i];
        cv.y = __float_as_uint(ivals[i]);
        pcode[pos] = cv;
    }
}

// =========================================================================
// Per-bucket LDS counting sort (R19-proven): contiguous bucket range, 4KB
// exclusive output window -> write-combined.
// =========================================================================
__global__ void bucket_sort_e_kernel(const int* __restrict__ pcode,
                                     const int* __restrict__ exbase,
                                     int* __restrict__ sorted_tr,
                                     int* __restrict__ offs_e,
                                     int n_entities, int nbuk) {
    __shared__ int cnt[64];
    __shared__ int off[64];
    __shared__ int cur[64];
    const int b = blockIdx.x;
    const int bstart = exbase[(size_t)b * NB];
    const int bend   = exbase[(size_t)(b + 1) * NB];
    if (threadIdx.x < 64) { cnt[threadIdx.x] = 0; cur[threadIdx.x] = 0; }
    __syncthreads();
    for (int i = bstart + (int)threadIdx.x; i < bend; i += blockDim.x)
        atomicAdd(&cnt[(pcode[i] >> 22) & 63], 1);
    __syncthreads();
    if (threadIdx.x == 0) {
        int s = 0;
#pragma unroll
        for (int i = 0; i < 64; ++i) { off[i] = s; s += cnt[i]; }
    }
    __syncthreads();
    const int h0 = b * 64;
    if (threadIdx.x < 64) {
        const int h = h0 + (int)threadIdx.x;
        if (h < n_entities) offs_e[h] = bstart + off[threadIdx.x];
    }
    if (b == nbuk - 1 && threadIdx.x == 0) offs_e[n_entities] = bend;
    for (int i = bstart + (int)threadIdx.x; i < bend; i += blockDim.x) {
        const int p  = pcode[i];
        const int lh = (p >> 22) & 63;
        const int pos = bstart + off[lh] + atomicAdd(&cur[lh], 1);
        sorted_tr[pos] = p & 0x3FFFFF;          // tail | rel<<17
    }
}

__global__ void bucket_sort_u_kernel(const uint2* __restrict__ pcode,
                                     const int* __restrict__ exbase,
                                     uint2* __restrict__ upack,
                                     int* __restrict__ offs_u,
                                     int n_users, int nbuk) {
    __shared__ int cnt[64];
    __shared__ int off[64];
    __shared__ int cur[64];
    const int b = blockIdx.x;
    const int bstart = exbase[(size_t)b * NB];
    const int bend   = exbase[(size_t)(b + 1) * NB];
    if (threadIdx.x < 64) { cnt[threadIdx.x] = 0; cur[threadIdx.x] = 0; }
    __syncthreads();
    for (int i = bstart + (int)threadIdx.x; i < bend; i += blockDim.x)
        atomicAdd(&cnt[(pcode[i].x >> 17) & 63], 1);
    __syncthreads();
    if (threadIdx.x == 0) {
        int s = 0;
#pragma unroll
        for (int i = 0; i < 64; ++i) { off[i] = s; s += cnt[i]; }
    }
    __syncthreads();
    const int u0 = b * 64;
    if (threadIdx.x < 64) {
        const int u = u0 + (int)threadIdx.x;
        if (u < n_users) offs_u[u] = bstart + off[threadIdx.x];
    }
    if (b == nbuk - 1 && threadIdx.x == 0) offs_u[n_users] = bend;
    for (int i = bstart + (int)threadIdx.x; i < bend; i += blockDim.x) {
        const uint2 cv = pcode[i];
        const int lr = (int)(cv.x >> 17) & 63;
        const int pos = bstart + off[lr] + atomicAdd(&cur[lr], 1);
        uint2 o;
        o.x = cv.x & 0x1FFFFu;
        o.y = cv.y;
        upack[pos] = o;
    }
}

// =========================================================================
// bf16 gather kernels (R14-proven: x2 unroll, plain loads)
// =========================================================================
__global__ void kg_gather_bf_kernel(const ushort_t* __restrict__ ebf,
                                    const int* __restrict__ sorted_tr,
                                    const int* __restrict__ offs,
                                    const float* __restrict__ weight,
                                    float* __restrict__ out_ent,
                                    int n_entities, int n_rel) {
    extern __shared__ float wl[];   // n_rel * CH
    for (int i = threadIdx.x; i < n_rel * CH; i += blockDim.x) wl[i] = weight[i];
    __syncthreads();
    const float4* wl4 = reinterpret_cast<const float4*>(wl);

    const int wid  = (blockIdx.x * blockDim.x + threadIdx.x) >> 6;
    const int lane = threadIdx.x & 63;
    const int g    = lane >> 4;
    const int q    = lane & 15;
    if (wid >= n_entities) return;

    const int s0 = offs[wid], s1 = offs[wid + 1];
    float ax = 0.0f, ay = 0.0f, az = 0.0f, aw = 0.0f;
    float bx = 0.0f, by = 0.0f, bz = 0.0f, bw = 0.0f;

    int base = s0;
    for (; base + 8 <= s1; base += 8) {
        const int tr0 = sorted_tr[base + g];
        const int tr1 = sorted_tr[base + 4 + g];
        const uint2 p0 = *reinterpret_cast<const uint2*>(
            ebf + (size_t)(tr0 & 0x1FFFF) * CH + q * 4);
        const uint2 p1 = *reinterpret_cast<const uint2*>(
            ebf + (size_t)(tr1 & 0x1FFFF) * CH + q * 4);
        const float4 w0 = wl4[(tr0 >> 17) * 16 + q];
        const float4 w1 = wl4[(tr1 >> 17) * 16 + q];
        ax = fmaf(bf_lo(p0.x), w0.x, ax);
        ay = fmaf(bf_hi(p0.x), w0.y, ay);
        az = fmaf(bf_lo(p0.y), w0.z, az);
        aw = fmaf(bf_hi(p0.y), w0.w, aw);
        bx = fmaf(bf_lo(p1.x), w1.x, bx);
        by = fmaf(bf_hi(p1.x), w1.y, by);
        bz = fmaf(bf_lo(p1.y), w1.z, bz);
        bw = fmaf(bf_hi(p1.y), w1.w, bw);
    }
    for (; base < s1; base += 4) {
        const int e = base + g;
        const bool valid = (e < s1);
        const int tr = valid ? sorted_tr[e] : 0;
        uint2 p;
        if (valid) {
            p = *reinterpret_cast<const uint2*>(
                ebf + (size_t)(tr & 0x1FFFF) * CH + q * 4);
        } else { p.x = 0u; p.y = 0u; }
        const float4 wv = wl4[(tr >> 17) * 16 + q];
        ax = fmaf(bf_lo(p.x), wv.x, ax);
        ay = fmaf(bf_hi(p.x), wv.y, ay);
        az = fmaf(bf_lo(p.y), wv.z, az);
        aw = fmaf(bf_hi(p.y), wv.w, aw);
    }
    ax += bx; ay += by; az += bz; aw += bw;

    ax += __shfl_xor(ax, 16); ay += __shfl_xor(ay, 16);
    az += __shfl_xor(az, 16); aw += __shfl_xor(aw, 16);
    ax += __shfl_xor(ax, 32); ay += __shfl_xor(ay, 32);
    az += __shfl_xor(az, 32); aw += __shfl_xor(aw, 32);

    if (g == 0) {
        const int deg = s1 - s0;
        const float inv = 1.0f / (float)(deg > 0 ? deg : 1);
        float4 o;
        o.x = ax * inv; o.y = ay * inv; o.z = az * inv; o.w = aw * inv;
        reinterpret_cast<float4*>(out_ent + (size_t)wid * CH)[q] = o;
    }
}

__global__ void user_gather_bf_kernel(const ushort_t* __restrict__ ebf,
                                      const uint2* __restrict__ upack,
                                      const int* __restrict__ offs,
                                      float* __restrict__ out_user,
                                      int n_users) {
    const int wid  = (blockIdx.x * blockDim.x + threadIdx.x) >> 6;
    const int lane = threadIdx.x & 63;
    const int g    = lane >> 4;
    const int q    = lane & 15;
    if (wid >= n_users) return;

    const int s0 = offs[wid], s1 = offs[wid + 1];
    float ax = 0.0f, ay = 0.0f, az = 0.0f, aw = 0.0f;
    float bx = 0.0f, by = 0.0f, bz = 0.0f, bw = 0.0f;

    int base = s0;
    for (; base + 8 <= s1; base += 8) {
        const uint2 cv0 = upack[base + g];
        const uint2 cv1 = upack[base + 4 + g];
        const float v0 = __uint_as_float(cv0.y);
        const float v1 = __uint_as_float(cv1.y);
        const uint2 p0 = *reinterpret_cast<const uint2*>(
            ebf + (size_t)cv0.x * CH + q * 4);
        const uint2 p1 = *reinterpret_cast<const uint2*>(
            ebf + (size_t)cv1.x * CH + q * 4);
        ax = fmaf(v0, bf_lo(p0.x), ax);
        ay = fmaf(v0, bf_hi(p0.x), ay);
        az = fmaf(v0, bf_lo(p0.y), az);
        aw = fmaf(v0, bf_hi(p0.y), aw);
        bx = fmaf(v1, bf_lo(p1.x), bx);
        by = fmaf(v1, bf_hi(p1.x), by);
        bz = fmaf(v1, bf_lo(p1.y), bz);
        bw = fmaf(v1, bf_hi(p1.y), bw);
    }
    for (; base < s1; base += 4) {
        const int e = base + g;
        const bool valid = (e < s1);
        uint2 cv;
        if (valid) cv = upack[e];
        else       { cv.x = 0u; cv.y = 0u; }
        const float v = __uint_as_float(cv.y);
        const uint2 p = *reinterpret_cast<const uint2*>(
            ebf + (size_t)cv.x * CH + q * 4);
        ax = fmaf(v, bf_lo(p.x), ax);
        ay = fmaf(v, bf_hi(p.x), ay);
        az = fmaf(v, bf_lo(p.y), az);
        aw = fmaf(v, bf_hi(p.y), aw);
    }
    ax += bx; ay += by; az += bz; aw += bw;

    ax += __shfl_xor(ax, 16); ay += __shfl_xor(ay, 16);
    az += __shfl_xor(az, 16); aw += __shfl_xor(aw, 16);
    ax += __shfl_xor(ax, 32); ay += __shfl_xor(ay, 32);
    az += __shfl_xor(az, 32); aw += __shfl_xor(aw, 32);

    if (g == 0) {
        float4 o; o.x = ax; o.y = ay; o.z = az; o.w = aw;
        reinterpret_cast<float4*>(out_user + (size_t)wid * CH)[q] = o;
    }
}

// =========================================================================
// Tier-2 (R14 CSR path): sliced hist/scatter
// =========================================================================
__global__ void hist_sliced_kernel(const int* __restrict__ keys,
                                   int* __restrict__ counts, int n, unsigned smul) {
    const int slice = blockIdx.x & (NSLICE - 1);
    const int rb    = blockIdx.x >> 3;
    const int nrb   = gridDim.x >> 3;
    const int per   = (n + nrb - 1) / nrb;
    const int i0    = rb * per;
    const int i1    = min(i0 + per, n);
    for (int i = i0 + (int)threadIdx.x; i < i1; i += blockDim.x) {
        const int k = keys[i];
        if ((int)__umulhi((unsigned)k, smul) == slice)
            atomicAdd(&counts[k], 1);
    }
}

__global__ void scatter_e_sliced_kernel(const int* __restrict__ edge_index,
                                        const int* __restrict__ edge_type,
                                        const int* __restrict__ offs,
                                        int* __restrict__ cursor,
                                        int* __restrict__ sorted_tr,
                                        int E, int n_rel, unsigned smul) {
    const int slice = blockIdx.x & (NSLICE - 1);
    const int rb    = blockIdx.x >> 3;
    const int nrb   = gridDim.x >> 3;
    const int per   = (E + nrb - 1) / nrb;
    const int e0    = rb * per;
    const int e1    = min(e0 + per, E);
    for (int e = e0 + (int)threadIdx.x; e < e1; e += blockDim.x) {
        const int h = edge_index[e];
        if ((int)__umulhi((unsigned)h, smul) != slice) continue;
        const int t = edge_index[(size_t)E + e];
        int r = edge_type[e] - 1;
        if (r < 0) r += n_rel;
        const int pos = offs[h] + atomicAdd(&cursor[h], 1);
        sorted_tr[pos] = t | (r << 17);
    }
}

__global__ void scatter_u_sliced_kernel(const int* __restrict__ irows,
                                        const int* __restrict__ icols,
                                        const float* __restrict__ ivals,
                                        const int* __restrict__ offs,
                                        int* __restrict__ cursor,
                                        uint2* __restrict__ upack,
                                        int NNZ, unsigned smul) {
    const int slice = blockIdx.x & (NSLICE - 1);
    const int rb    = blockIdx.x >> 3;
    const int nrb   = gridDim.x >> 3;
    const int per   = (NNZ + nrb - 1) / nrb;
    const int i0    = rb * per;
    const int i1    = min(i0 + per, NNZ);
    for (int i = i0 + (int)threadIdx.x; i < i1; i += blockDim.x) {
        const int u = irows[i];
        if ((int)__umulhi((unsigned)u, smul) != slice) continue;
        const int pos = offs[u] + atomicAdd(&cursor[u], 1);
        uint2 cv;
        cv.x = (unsigned)icols[i];
        cv.y = __float_as_uint(ivals[i]);
        upack[pos] = cv;
    }
}

// =========================================================================
// Tier-3 (atomic fallback)
// =========================================================================
__global__ void kg_agg_atomic_kernel(const float* __restrict__ emb,
                                     const float* __restrict__ region_ent,
                                     const int* __restrict__ edge_index,
                                     const int* __restrict__ edge_type,
                                     const float* __restrict__ weight,
                                     float* __restrict__ out_ent,
                                     float* __restrict__ counts,
                                     int E, int n_rel) {
    const long long gid = (long long)blockIdx.x * blockDim.x + threadIdx.x;
    const long long e = gid >> 6;
    if (e >= E) return;
    const int c = (int)gid & 63;
    const int h = edge_index[e];
    const int t = edge_index[(size_t)E + e];
    int r = edge_type[e] - 1;
    if (r < 0) r += n_rel;
    const float v = ent_val(emb, region_ent, t, c) * weight[(size_t)r * CH + c];
    unsafeAtomicAdd(out_ent + (size_t)h * CH + c, v);
    if (c == 0) unsafeAtomicAdd(counts + h, 1.0f);
}

__global__ void user_agg_atomic_kernel(const float* __restrict__ emb,
                                       const float* __restrict__ region_ent,
                                       const int* __restrict__ irows,
                                       const int* __restrict__ icols,
                                       const float* __restrict__ ivals,
                                       float* __restrict__ out_user, int NNZ) {
    const long long gid = (long long)blockIdx.x * blockDim.x + threadIdx.x;
    const long long i = gid >> 6;
    if (i >= NNZ) return;
    const int c = (int)gid & 63;
    const float v = ivals[i] * ent_val(emb, region_ent, icols[i], c);
    unsafeAtomicAdd(out_user + (size_t)irows[i] * CH + c, v);
}

__global__ void finalize_kernel(float* __restrict__ out_ent,
                                const float* __restrict__ counts, int n_entities) {
    const int gid = blockIdx.x * blockDim.x + threadIdx.x;
    if (gid >= n_entities * CH) return;
    out_ent[gid] /= fmaxf(counts[gid >> 6], 1.0f);
}

// =========================================================================
extern "C" void kernel_launch(void* const* d_in, const int* in_sizes, int n_in,
                              void* d_out, int out_size, void* d_ws, size_t ws_size,
                              hipStream_t stream) {
    const float* entity_emb = (const float*)d_in[0];
    const int*   edge_index = (const int*)d_in[2];
    const int*   edge_type  = (const int*)d_in[3];
    const int*   irows      = (const int*)d_in[4];
    const int*   icols      = (const int*)d_in[5];
    const float* ivals      = (const float*)d_in[6];
    const float* Wreg       = (const float*)d_in[7];
    const float* weight     = (const float*)d_in[8];

    const int n_entities = in_sizes[0] / CH;
    const int n_users    = in_sizes[1] / CH;
    const int E          = in_sizes[3];
    const int NNZ        = in_sizes[4];
    const int n_rel      = in_sizes[8] / CH;

    float* out_ent  = (float*)d_out;
    float* out_user = out_ent + (size_t)n_entities * CH;

    const int NBUK_E = (n_entities + 63) >> 6;
    const int NBUK_U = (n_users + 63) >> 6;
    const int n_e = NBUK_E * NB;
    const int n_u = NBUK_U * NB;
    const int nbse = (n_e + SCAN_B - 1) / SCAN_B;
    const int nbsu = (n_u + SCAN_B - 1) / SCAN_B;

    // ---- tier-1 (bucket) layout ----
    char* w = (char*)d_ws;
    auto take = [&](size_t bytes) {
        char* p = w;
        w += (bytes + 7) & ~(size_t)7;
        return p;
    };
    float*    region_ent = (float*)take((size_t)RN * CH * 4);
    ushort_t* e_t        = (ushort_t*)take((size_t)CH * KP * 2);
    ushort_t* ebf        = (ushort_t*)take((size_t)n_entities * CH * 2);
    int*      sorted_tr  = (int*)take((size_t)E * 4);
    uint2*    upack      = (uint2*)take((size_t)NNZ * 8);
    int*      offs_e     = (int*)take((size_t)(n_entities + 1) * 4);
    int*      offs_u     = (int*)take((size_t)(n_users + 1) * 4);
    int*      bsums      = (int*)take(512 * 4);
    int*      hist_e     = (int*)take((size_t)n_e * 4);
    int*      exbase_e   = (int*)take((size_t)(n_e + 1) * 4);
    int*      hist_u     = (int*)take((size_t)n_u * 4);
    int*      exbase_u   = (int*)take((size_t)(n_u + 1) * 4);
    int*      pcode_e    = (int*)take((size_t)E * 4);
    uint2*    pcode_u    = (uint2*)take((size_t)NNZ * 8);
    const size_t need_bucket = (size_t)(w - (char*)d_ws);

    const bool common_ok = (n_entities < (1 << 17)) && (n_rel <= 32);
    const bool use_bucket = common_ok && (ws_size >= need_bucket) &&
                            (NBUK_E <= MAXBUK) && (NBUK_U <= MAXBUK) &&
                            (nbse <= 512) && (nbsu <= 512);

    // ---- tier-2 (csr) layout ----
    char* w2 = (char*)d_ws;
    auto take2 = [&](size_t bytes) {
        char* p = w2;
        w2 += (bytes + 7) & ~(size_t)7;
        return p;
    };
    float*    c_region  = (float*)take2((size_t)RN * CH * 4);
    int*      c_offs_e  = (int*)take2((size_t)(n_entities + 1) * 4);
    int*      c_cur_e   = (int*)take2((size_t)n_entities * 4);
    int*      c_offs_u  = (int*)take2((size_t)(n_users + 1) * 4);
    int*      c_cur_u   = (int*)take2((size_t)n_users * 4);
    int*      c_bsums   = (int*)take2(512 * 4);
    int*      c_sorted  = (int*)take2((size_t)E * 4);
    uint2*    c_upack   = (uint2*)take2((size_t)NNZ * 8);
    ushort_t* c_et      = (ushort_t*)take2((size_t)CH * KP * 2);
    ushort_t* c_ebf     = (ushort_t*)take2((size_t)n_entities * CH * 2);
    const size_t need_csr = (size_t)(w2 - (char*)d_ws);
    const int nb_e = (n_entities + SCAN_B - 1) / SCAN_B;
    const int nb_u = (n_users + SCAN_B - 1) / SCAN_B;
    const bool use_csr = common_ok && (ws_size >= need_csr) &&
                         (nb_e <= 512) && (nb_u <= 512);

    if (use_bucket) {
        region_init_kernel<<<(RN * CH / 4 + 255) / 256, 256, 0, stream>>>(entity_emb, region_ent);
        {
            const int tot = CH * (KP / 8);
            build_et_kernel<<<(tot + 255) / 256, 256, 0, stream>>>(entity_emb, e_t);
        }
        region_gemm_mfma_kernel<<<MT_BLKS * KCHUNKS, 256, 0, stream>>>(
            Wreg, e_t, region_ent);
        {
            const int tot = n_entities * (CH / 8);
            build_ebf_kernel<<<(tot + 255) / 256, 256, 0, stream>>>(
                entity_emb, region_ent, ebf, n_entities);
        }

        // edges: hist -> scan -> pass2 -> per-bucket sort
        bucket_hist_kernel<<<NB, T1, 0, stream>>>(edge_index, hist_e, E, NBUK_E);
        scan_block_kernel<<<nbse, SCAN_B, 0, stream>>>(hist_e, exbase_e, bsums, n_e);
        scan_top_kernel<<<1, 512, 0, stream>>>(bsums, nbse);
        scan_add_kernel<<<nbse, SCAN_B, 0, stream>>>(exbase_e, bsums, n_e);
        pass2_edges_kernel<<<NB, T1, 0, stream>>>(
            edge_index, edge_type, exbase_e, pcode_e, E, n_rel, NBUK_E);
        bucket_sort_e_kernel<<<NBUK_E, 256, 0, stream>>>(
            pcode_e, exbase_e, sorted_tr, offs_e, n_entities, NBUK_E);

        // users
        bucket_hist_kernel<<<NB, T1, 0, stream>>>(irows, hist_u, NNZ, NBUK_U);
        scan_block_kernel<<<nbsu, SCAN_B, 0, stream>>>(hist_u, exbase_u, bsums, n_u);
        scan_top_kernel<<<1, 512, 0, stream>>>(bsums, nbsu);
        scan_add_kernel<<<nbsu, SCAN_B, 0, stream>>>(exbase_u, bsums, n_u);
        pass2_users_kernel<<<NB, T1, 0, stream>>>(
            irows, icols, ivals, exbase_u, pcode_u, NNZ, NBUK_U);
        bucket_sort_u_kernel<<<NBUK_U, 256, 0, stream>>>(
            pcode_u, exbase_u, upack, offs_u, n_users, NBUK_U);

        // gathers
        kg_gather_bf_kernel<<<(n_entities + 3) / 4, 256, n_rel * CH * 4, stream>>>(
            ebf, sorted_tr, offs_e, weight, out_ent, n_entities, n_rel);
        user_gather_bf_kernel<<<(n_users + 3) / 4, 256, 0, stream>>>(
            ebf, upack, offs_u, out_user, n_users);
    } else if (use_csr) {
        const unsigned smul_e = (unsigned)((8ULL << 32) / (unsigned long long)n_entities);
        const unsigned smul_u = (unsigned)((8ULL << 32) / (unsigned long long)n_users);

        region_init_kernel<<<(RN * CH / 4 + 255) / 256, 256, 0, stream>>>(entity_emb, c_region);
        {
            const int tot = CH * (KP / 8);
            build_et_kernel<<<(tot + 255) / 256, 256, 0, stream>>>(entity_emb, c_et);
        }
        region_gemm_mfma_kernel<<<MT_BLKS * KCHUNKS, 256, 0, stream>>>(
            Wreg, c_et, c_region);
        {
            const int tot = n_entities * (CH / 8);
            build_ebf_kernel<<<(tot + 255) / 256, 256, 0, stream>>>(
                entity_emb, c_region, c_ebf, n_entities);
        }

        hipMemsetAsync(c_cur_e, 0, (size_t)n_entities * 4, stream);
        hipMemsetAsync(c_cur_u, 0, (size_t)n_users * 4, stream);
        hist_sliced_kernel<<<NSLICE * SLICE_RB, 256, 0, stream>>>(
            edge_index, c_cur_e, E, smul_e);
        hist_sliced_kernel<<<NSLICE * SLICE_RB, 256, 0, stream>>>(
            irows, c_cur_u, NNZ, smul_u);

        scan_block_kernel<<<nb_e, SCAN_B, 0, stream>>>(c_cur_e, c_offs_e, c_bsums, n_entities);
        scan_top_kernel<<<1, 512, 0, stream>>>(c_bsums, nb_e);
        scan_add_kernel<<<nb_e, SCAN_B, 0, stream>>>(c_offs_e, c_bsums, n_entities);

        scan_block_kernel<<<nb_u, SCAN_B, 0, stream>>>(c_cur_u, c_offs_u, c_bsums, n_users);
        scan_top_kernel<<<1, 512, 0, stream>>>(c_bsums, nb_u);
        scan_add_kernel<<<nb_u, SCAN_B, 0, stream>>>(c_offs_u, c_bsums, n_users);

        hipMemsetAsync(c_cur_e, 0, (size_t)n_entities * 4, stream);
        hipMemsetAsync(c_cur_u, 0, (size_t)n_users * 4, stream);
        scatter_e_sliced_kernel<<<NSLICE * SLICE_RB, 256, 0, stream>>>(
            edge_index, edge_type, c_offs_e, c_cur_e, c_sorted, E, n_rel, smul_e);
        scatter_u_sliced_kernel<<<NSLICE * SLICE_RB, 256, 0, stream>>>(
            irows, icols, ivals, c_offs_u, c_cur_u, c_upack, NNZ, smul_u);

        kg_gather_bf_kernel<<<(n_entities + 3) / 4, 256, n_rel * CH * 4, stream>>>(
            c_ebf, c_sorted, c_offs_e, weight, out_ent, n_entities, n_rel);
        user_gather_bf_kernel<<<(n_users + 3) / 4, 256, 0, stream>>>(
            c_ebf, c_upack, c_offs_u, out_user, n_users);
    } else {
        // tier-3: atomic fallback
        float* region3 = (float*)d_ws;
        float* counts  = region3 + (size_t)RN * CH;
        region_init_kernel<<<(RN * CH / 4 + 255) / 256, 256, 0, stream>>>(entity_emb, region3);
        region_gemm_kernel<<<ROW_TILES * KSPLIT, 256, 0, stream>>>(
            entity_emb, Wreg, region3);
        hipMemsetAsync(d_out, 0, (size_t)out_size * sizeof(float), stream);
        hipMemsetAsync(counts, 0, (size_t)n_entities * sizeof(float), stream);
        {
            const long long tot = (long long)E * CH;
            kg_agg_atomic_kernel<<<(int)((tot + 255) / 256), 256, 0, stream>>>(
                entity_emb, region3, edge_index, edge_type, weight,
                out_ent, counts, E, n_rel);
        }
        {
            const long long tot = (long long)NNZ * CH;
            user_agg_atomic_kernel<<<(int)((tot + 255) / 256), 256, 0, stream>>>(
                entity_emb, region3, irows, icols, ivals, out_user, NNZ);
        }
        finalize_kernel<<<(n_entities * CH + 255) / 256, 256, 0, stream>>>(
            out_ent, counts, n_entities);
    }
}

// Round 21
// 213.943 us; speedup vs baseline: 5.5626x; 1.1318x over previous
//
#include <hip/hip_runtime.h>
#include <hip/hip_bf16.h>

// Problem constants (from reference source)
#define REGION_R0 42033
#define REGION_R1 44630
#define RN        (REGION_R1 - REGION_R0)   // 2597
#define CH        64
#define KSPLIT    32
#define ROW_TILES ((RN + 31) / 32)          // 82
#define SCAN_B    256
#define NSLICE    8
#define SLICE_RB  256                        // tier-2 grid

// bucket partition geometry
#define NB        64                         // range-blocks: 16-entry (64B) exclusive runs
#define T1        1024                       // 16 waves/block (R20-proven)
#define MAXBUK    2048

// MFMA region-gemm geometry
#define KTT       82
#define KP        (KTT * 32)                 // 2624
#define PERCHUNK  6
#define KCHUNKS   14
#define MT_TILES  163
#define MT_BLKS   41

typedef unsigned short ushort_t;
typedef short  bfrag8 __attribute__((ext_vector_type(8)));
typedef float  f32x4v __attribute__((ext_vector_type(4)));

// =========================================================================
// Region blend init (region_ent = 0.8 * orig)
// =========================================================================
__global__ void region_init_kernel(const float* __restrict__ emb,
                                   float* __restrict__ region_ent) {
    const int gid = blockIdx.x * blockDim.x + threadIdx.x;
    if (gid >= RN * CH / 4) return;
    const float4 v = reinterpret_cast<const float4*>(emb + (size_t)REGION_R0 * CH)[gid];
    float4 o;
    o.x = 0.8f * v.x; o.y = 0.8f * v.y; o.z = 0.8f * v.z; o.w = 0.8f * v.w;
    reinterpret_cast<float4*>(region_ent)[gid] = o;
}

__device__ __forceinline__ unsigned pack2bf(float a, float b) {
    unsigned ua = __float_as_uint(a);
    unsigned ub = __float_as_uint(b);
    ua += 0x7fffu + ((ua >> 16) & 1u);   // RNE
    ub += 0x7fffu + ((ub >> 16) & 1u);
    return ((ua >> 16) & 0xffffu) | (ub & 0xffff0000u);
}

// =========================================================================
// e_t[c][k] = bf16(emb[R0+k][c]) (B operand, transposed, zero-padded)
// =========================================================================
__global__ void build_et_kernel(const float* __restrict__ emb,
                                ushort_t* __restrict__ e_t) {
    const int gid = blockIdx.x * blockDim.x + threadIdx.x;
    if (gid >= CH * (KP / 8)) return;
    const int c  = gid / (KP / 8);
    const int k8 = gid - c * (KP / 8);
    const int kb = k8 * 8;
    float v[8];
#pragma unroll
    for (int j = 0; j < 8; ++j) {
        const int k = kb + j;
        v[j] = (k < RN) ? emb[(size_t)(REGION_R0 + k) * CH + c] : 0.0f;
    }
    uint4 o;
    o.x = pack2bf(v[0], v[1]); o.y = pack2bf(v[2], v[3]);
    o.z = pack2bf(v[4], v[5]); o.w = pack2bf(v[6], v[7]);
    *reinterpret_cast<uint4*>(e_t + (size_t)c * KP + kb) = o;
}

// =========================================================================
// MFMA region GEMM (R14-verified, absmax 0.25)
// =========================================================================
__global__ void region_gemm_mfma_kernel(const float* __restrict__ W,
                                        const ushort_t* __restrict__ e_t,
                                        float* __restrict__ region_ent) {
    const int wv    = threadIdx.x >> 6;
    const int lane  = threadIdx.x & 63;
    const int blk_m = blockIdx.x / KCHUNKS;
    const int kc    = blockIdx.x - blk_m * KCHUNKS;
    const int mt    = blk_m * 4 + wv;
    if (mt >= MT_TILES) return;
    const int l15 = lane & 15;
    const int lg  = lane >> 4;

    int arow = mt * 16 + l15;
    if (arow >= RN) arow = RN - 1;
    const float* wrow = W + (size_t)arow * RN;

    const int kt0 = kc * PERCHUNK;
    const int kt1 = (kt0 + PERCHUNK < KTT) ? (kt0 + PERCHUNK) : KTT;

    f32x4v acc[4];
#pragma unroll
    for (int n = 0; n < 4; ++n) acc[n] = (f32x4v){0.f, 0.f, 0.f, 0.f};

    for (int kt = kt0; kt < kt1; ++kt) {
        const int kb = kt * 32 + lg * 8;
        union { uint4 u; bfrag8 f; } A;
        if (kb + 8 <= RN) {
            float v0 = wrow[kb + 0], v1 = wrow[kb + 1];
            float v2 = wrow[kb + 2], v3 = wrow[kb + 3];
            float v4 = wrow[kb + 4], v5 = wrow[kb + 5];
            float v6 = wrow[kb + 6], v7 = wrow[kb + 7];
            A.u.x = pack2bf(v0, v1); A.u.y = pack2bf(v2, v3);
            A.u.z = pack2bf(v4, v5); A.u.w = pack2bf(v6, v7);
        } else {
            float v[8];
#pragma unroll
            for (int j = 0; j < 8; ++j) {
                const int k = kb + j;
                v[j] = (k < RN) ? wrow[k] : 0.0f;
            }
            A.u.x = pack2bf(v[0], v[1]); A.u.y = pack2bf(v[2], v[3]);
            A.u.z = pack2bf(v[4], v[5]); A.u.w = pack2bf(v[6], v[7]);
        }
#pragma unroll
        for (int n = 0; n < 4; ++n) {
            const bfrag8 B = *reinterpret_cast<const bfrag8*>(
                e_t + (size_t)(n * 16 + l15) * KP + kb);
            acc[n] = __builtin_amdgcn_mfma_f32_16x16x32_bf16(A.f, B, acc[n], 0, 0, 0);
        }
    }

#pragma unroll
    for (int n = 0; n < 4; ++n) {
#pragma unroll
        for (int j = 0; j < 4; ++j) {
            const int row = mt * 16 + lg * 4 + j;
            if (row < RN)
                unsafeAtomicAdd(region_ent + (size_t)row * CH + n * 16 + l15,
                                0.2f * acc[n][j]);
        }
    }
}

// =========================================================================
// VALU region GEMM (tier-3 fallback only)
// =========================================================================
__global__ void region_gemm_kernel(const float* __restrict__ emb,
                                   const float* __restrict__ W,
                                   float* __restrict__ region_ent) {
    const int wave = threadIdx.x >> 6;
    const int c    = threadIdx.x & 63;
    const int rt   = blockIdx.x / KSPLIT;
    const int ks   = blockIdx.x - rt * KSPLIT;
    const int base = rt * 32 + wave * 8;
    if (base >= RN) return;

    const int k0 = (RN * ks) / KSPLIT;
    const int k1 = (RN * (ks + 1)) / KSPLIT;

    const float* wp[8];
#pragma unroll
    for (int r = 0; r < 8; ++r) {
        int row = base + r;
        if (row >= RN) row = RN - 1;
        row = __builtin_amdgcn_readfirstlane(row);
        wp[r] = W + (size_t)row * RN;
    }
    const float* ep = emb + (size_t)REGION_R0 * CH + c;

    float acc[8];
#pragma unroll
    for (int r = 0; r < 8; ++r) acc[r] = 0.0f;

    int k = k0;
    for (; k + 4 <= k1; k += 4) {
        const float e0 = ep[(size_t)(k + 0) * CH];
        const float e1 = ep[(size_t)(k + 1) * CH];
        const float e2 = ep[(size_t)(k + 2) * CH];
        const float e3 = ep[(size_t)(k + 3) * CH];
#pragma unroll
        for (int r = 0; r < 8; ++r) {
            const float* wr = wp[r];
            float a = acc[r];
            a = fmaf(wr[k + 0], e0, a);
            a = fmaf(wr[k + 1], e1, a);
            a = fmaf(wr[k + 2], e2, a);
            a = fmaf(wr[k + 3], e3, a);
            acc[r] = a;
        }
    }
    for (; k < k1; ++k) {
        const float e = ep[(size_t)k * CH];
#pragma unroll
        for (int r = 0; r < 8; ++r) acc[r] = fmaf(wp[r][k], e, acc[r]);
    }
#pragma unroll
    for (int r = 0; r < 8; ++r) {
        const int row = base + r;
        if (row < RN)
            unsafeAtomicAdd(region_ent + (size_t)row * CH + c, 0.2f * acc[r]);
    }
}

__device__ __forceinline__ float ent_val(const float* __restrict__ emb,
                                         const float* __restrict__ region_ent,
                                         int row, int c) {
    const float* p = (row >= REGION_R0 && row < REGION_R1)
                         ? (region_ent + (size_t)(row - REGION_R0) * CH + c)
                         : (emb + (size_t)row * CH + c);
    return *p;
}

__device__ __forceinline__ const float* ent_row(const float* __restrict__ emb,
                                                const float* __restrict__ region_ent,
                                                int row) {
    return (row >= REGION_R0 && row < REGION_R1)
               ? (region_ent + (size_t)(row - REGION_R0) * CH)
               : (emb + (size_t)row * CH);
}

// =========================================================================
// bf16 entity table (region rows baked in)
// =========================================================================
__global__ void build_ebf_kernel(const float* __restrict__ emb,
                                 const float* __restrict__ region_ent,
                                 ushort_t* __restrict__ ebf,
                                 int n_entities) {
    const int gid = blockIdx.x * blockDim.x + threadIdx.x;
    if (gid >= n_entities * (CH / 8)) return;
    const int row = gid >> 3;
    const int co  = (gid & 7) * 8;
    const float* rp = ent_row(emb, region_ent, row) + co;
    const float4 a = *reinterpret_cast<const float4*>(rp);
    const float4 b = *reinterpret_cast<const float4*>(rp + 4);
    uint4 o;
    o.x = pack2bf(a.x, a.y);
    o.y = pack2bf(a.z, a.w);
    o.z = pack2bf(b.x, b.y);
    o.w = pack2bf(b.z, b.w);
    *reinterpret_cast<uint4*>(ebf + (size_t)row * CH + co) = o;
}

__device__ __forceinline__ float bf_lo(unsigned u) { return __uint_as_float(u << 16); }
__device__ __forceinline__ float bf_hi(unsigned u) { return __uint_as_float(u & 0xffff0000u); }

// =========================================================================
// Combined bucket hist: blocks [0,NB) = edges, [NB,2NB) = users.
// hist[bucket*NB + block]; bucket = key>>6.
// =========================================================================
__global__ void bucket_hist2_kernel(const int* __restrict__ ekeys, int ne, int nbe,
                                    const int* __restrict__ ukeys, int nu, int nbu,
                                    int* __restrict__ hist_e,
                                    int* __restrict__ hist_u) {
    __shared__ int lh[MAXBUK];
    const bool is_u = (blockIdx.x >= NB);
    const int  rb   = is_u ? (blockIdx.x - NB) : blockIdx.x;
    const int* keys = is_u ? ukeys : ekeys;
    const int  n    = is_u ? nu : ne;
    const int  nbuk = is_u ? nbu : nbe;
    int* hist       = is_u ? hist_u : hist_e;

    for (int i = threadIdx.x; i < nbuk; i += T1) lh[i] = 0;
    __syncthreads();
    const int chunk = (n + NB - 1) / NB;
    const int i0 = rb * chunk;
    const int i1 = min(i0 + chunk, n);
    for (int i = i0 + (int)threadIdx.x; i < i1; i += T1)
        atomicAdd(&lh[keys[i] >> 6], 1);
    __syncthreads();
    for (int b = threadIdx.x; b < nbuk; b += T1)
        hist[(size_t)b * NB + rb] = lh[b];
}

__global__ void scan_block_kernel(const int* __restrict__ counts, int* __restrict__ offs,
                                  int* __restrict__ bsums, int n) {
    __shared__ int s[SCAN_B];
    const int i = blockIdx.x * SCAN_B + threadIdx.x;
    s[threadIdx.x] = (i < n) ? counts[i] : 0;
    __syncthreads();
    for (int d = 1; d < SCAN_B; d <<= 1) {
        const int t = (threadIdx.x >= d) ? s[threadIdx.x - d] : 0;
        __syncthreads();
        s[threadIdx.x] += t;
        __syncthreads();
    }
    if (i < n) offs[i + 1] = s[threadIdx.x];
    if (threadIdx.x == SCAN_B - 1) bsums[blockIdx.x] = s[threadIdx.x];
    if (blockIdx.x == 0 && threadIdx.x == 0) offs[0] = 0;
}

__global__ void scan_top_kernel(int* __restrict__ bsums, int nb) {
    __shared__ int s[512];
    s[threadIdx.x] = (threadIdx.x < (unsigned)nb) ? bsums[threadIdx.x] : 0;
    __syncthreads();
    for (int d = 1; d < 512; d <<= 1) {
        const int t = (threadIdx.x >= d) ? s[threadIdx.x - d] : 0;
        __syncthreads();
        s[threadIdx.x] += t;
        __syncthreads();
    }
    if (threadIdx.x < (unsigned)nb) bsums[threadIdx.x] = s[threadIdx.x];
}

__global__ void scan_add_kernel(int* __restrict__ offs, const int* __restrict__ bsums, int n) {
    if (blockIdx.x == 0) return;
    const int i = blockIdx.x * SCAN_B + threadIdx.x;
    if (i < n) offs[i + 1] += bsums[blockIdx.x - 1];
}

// =========================================================================
// Combined pass2: blocks [0,NB) = edges (pcode_e = (lh<<22)|(rel<<17)|tail),
// [NB,2NB) = users (pcode_u = {(lr<<17)|col, val}). exbase row in LDS.
// =========================================================================
__global__ void pass2_combined_kernel(const int* __restrict__ edge_index,
                                      const int* __restrict__ edge_type,
                                      const int* __restrict__ exbase_e,
                                      int* __restrict__ pcode_e,
                                      int E, int n_rel, int nbe,
                                      const int* __restrict__ irows,
                                      const int* __restrict__ icols,
                                      const float* __restrict__ ivals,
                                      const int* __restrict__ exbase_u,
                                      uint2* __restrict__ pcode_u,
                                      int NNZ, int nbu) {
    __shared__ int cur[MAXBUK];
    __shared__ int exb[MAXBUK];
    const bool is_u = (blockIdx.x >= NB);
    const int  rb   = is_u ? (blockIdx.x - NB) : blockIdx.x;
    const int  nbuk = is_u ? nbu : nbe;
    const int* exbase = is_u ? exbase_u : exbase_e;

    for (int i = threadIdx.x; i < nbuk; i += T1) {
        cur[i] = 0;
        exb[i] = exbase[(size_t)i * NB + rb];
    }
    __syncthreads();

    if (!is_u) {
        const int chunk = (E + NB - 1) / NB;
        const int i0 = rb * chunk;
        const int i1 = min(i0 + chunk, E);
        for (int e = i0 + (int)threadIdx.x; e < i1; e += T1) {
            const int h = edge_index[e];
            const int b = h >> 6;
            const int loc = atomicAdd(&cur[b], 1);
            const int pos = exb[b] + loc;
            const int t = edge_index[(size_t)E + e];
            int r = edge_type[e] - 1;
            if (r < 0) r += n_rel;
            pcode_e[pos] = ((h & 63) << 22) | (r << 17) | t;
        }
    } else {
        const int chunk = (NNZ + NB - 1) / NB;
        const int i0 = rb * chunk;
        const int i1 = min(i0 + chunk, NNZ);
        for (int i = i0 + (int)threadIdx.x; i < i1; i += T1) {
            const int u = irows[i];
            const int b = u >> 6;
            const int loc = atomicAdd(&cur[b], 1);
            const int pos = exb[b] + loc;
            uint2 cv;
            cv.x = ((unsigned)(u & 63) << 17) | (unsigned)icols[i];
            cv.y = __float_as_uint(ivals[i]);
            pcode_u[pos] = cv;
        }
    }
}

// =========================================================================
// Combined per-bucket counting sort: blocks [0,NBUK_E) edges, rest users.
// =========================================================================
__global__ void bucket_sort2_kernel(const int* __restrict__ pcode_e,
                                    const int* __restrict__ exbase_e,
                                    int* __restrict__ sorted_tr,
                                    int* __restrict__ offs_e,
                                    int n_entities, int nbe,
                                    const uint2* __restrict__ pcode_u,
                                    const int* __restrict__ exbase_u,
                                    uint2* __restrict__ upack,
                                    int* __restrict__ offs_u,
                                    int n_users, int nbu) {
    __shared__ int cnt[64];
    __shared__ int off[64];
    __shared__ int cur[64];
    const bool is_u = (blockIdx.x >= (unsigned)nbe);
    const int  b    = is_u ? (blockIdx.x - nbe) : blockIdx.x;
    const int* exbase = is_u ? exbase_u : exbase_e;
    const int bstart = exbase[(size_t)b * NB];
    const int bend   = exbase[(size_t)(b + 1) * NB];
    if (threadIdx.x < 64) { cnt[threadIdx.x] = 0; cur[threadIdx.x] = 0; }
    __syncthreads();

    if (!is_u) {
        for (int i = bstart + (int)threadIdx.x; i < bend; i += blockDim.x)
            atomicAdd(&cnt[(pcode_e[i] >> 22) & 63], 1);
    } else {
        for (int i = bstart + (int)threadIdx.x; i < bend; i += blockDim.x)
            atomicAdd(&cnt[(pcode_u[i].x >> 17) & 63], 1);
    }
    __syncthreads();
    if (threadIdx.x == 0) {
        int s = 0;
#pragma unroll
        for (int i = 0; i < 64; ++i) { off[i] = s; s += cnt[i]; }
    }
    __syncthreads();

    if (!is_u) {
        const int h0 = b * 64;
        if (threadIdx.x < 64) {
            const int h = h0 + (int)threadIdx.x;
            if (h < n_entities) offs_e[h] = bstart + off[threadIdx.x];
        }
        if (b == nbe - 1 && threadIdx.x == 0) offs_e[n_entities] = bend;
        for (int i = bstart + (int)threadIdx.x; i < bend; i += blockDim.x) {
            const int p  = pcode_e[i];
            const int lh = (p >> 22) & 63;
            const int pos = bstart + off[lh] + atomicAdd(&cur[lh], 1);
            sorted_tr[pos] = p & 0x3FFFFF;
        }
    } else {
        const int u0 = b * 64;
        if (threadIdx.x < 64) {
            const int u = u0 + (int)threadIdx.x;
            if (u < n_users) offs_u[u] = bstart + off[threadIdx.x];
        }
        if (b == nbu - 1 && threadIdx.x == 0) offs_u[n_users] = bend;
        for (int i = bstart + (int)threadIdx.x; i < bend; i += blockDim.x) {
            const uint2 cv = pcode_u[i];
            const int lr = (int)(cv.x >> 17) & 63;
            const int pos = bstart + off[lr] + atomicAdd(&cur[lr], 1);
            uint2 o;
            o.x = cv.x & 0x1FFFFu;
            o.y = cv.y;
            upack[pos] = o;
        }
    }
}

// =========================================================================
// bf16 gather kernels (R14-proven: x2 unroll, plain loads)
// =========================================================================
__global__ void kg_gather_bf_kernel(const ushort_t* __restrict__ ebf,
                                    const int* __restrict__ sorted_tr,
                                    const int* __restrict__ offs,
                                    const float* __restrict__ weight,
                                    float* __restrict__ out_ent,
                                    int n_entities, int n_rel) {
    extern __shared__ float wl[];   // n_rel * CH
    for (int i = threadIdx.x; i < n_rel * CH; i += blockDim.x) wl[i] = weight[i];
    __syncthreads();
    const float4* wl4 = reinterpret_cast<const float4*>(wl);

    const int wid  = (blockIdx.x * blockDim.x + threadIdx.x) >> 6;
    const int lane = threadIdx.x & 63;
    const int g    = lane >> 4;
    const int q    = lane & 15;
    if (wid >= n_entities) return;

    const int s0 = offs[wid], s1 = offs[wid + 1];
    float ax = 0.0f, ay = 0.0f, az = 0.0f, aw = 0.0f;
    float bx = 0.0f, by = 0.0f, bz = 0.0f, bw = 0.0f;

    int base = s0;
    for (; base + 8 <= s1; base += 8) {
        const int tr0 = sorted_tr[base + g];
        const int tr1 = sorted_tr[base + 4 + g];
        const uint2 p0 = *reinterpret_cast<const uint2*>(
            ebf + (size_t)(tr0 & 0x1FFFF) * CH + q * 4);
        const uint2 p1 = *reinterpret_cast<const uint2*>(
            ebf + (size_t)(tr1 & 0x1FFFF) * CH + q * 4);
        const float4 w0 = wl4[(tr0 >> 17) * 16 + q];
        const float4 w1 = wl4[(tr1 >> 17) * 16 + q];
        ax = fmaf(bf_lo(p0.x), w0.x, ax);
        ay = fmaf(bf_hi(p0.x), w0.y, ay);
        az = fmaf(bf_lo(p0.y), w0.z, az);
        aw = fmaf(bf_hi(p0.y), w0.w, aw);
        bx = fmaf(bf_lo(p1.x), w1.x, bx);
        by = fmaf(bf_hi(p1.x), w1.y, by);
        bz = fmaf(bf_lo(p1.y), w1.z, bz);
        bw = fmaf(bf_hi(p1.y), w1.w, bw);
    }
    for (; base < s1; base += 4) {
        const int e = base + g;
        const bool valid = (e < s1);
        const int tr = valid ? sorted_tr[e] : 0;
        uint2 p;
        if (valid) {
            p = *reinterpret_cast<const uint2*>(
                ebf + (size_t)(tr & 0x1FFFF) * CH + q * 4);
        } else { p.x = 0u; p.y = 0u; }
        const float4 wv = wl4[(tr >> 17) * 16 + q];
        ax = fmaf(bf_lo(p.x), wv.x, ax);
        ay = fmaf(bf_hi(p.x), wv.y, ay);
        az = fmaf(bf_lo(p.y), wv.z, az);
        aw = fmaf(bf_hi(p.y), wv.w, aw);
    }
    ax += bx; ay += by; az += bz; aw += bw;

    ax += __shfl_xor(ax, 16); ay += __shfl_xor(ay, 16);
    az += __shfl_xor(az, 16); aw += __shfl_xor(aw, 16);
    ax += __shfl_xor(ax, 32); ay += __shfl_xor(ay, 32);
    az += __shfl_xor(az, 32); aw += __shfl_xor(aw, 32);

    if (g == 0) {
        const int deg = s1 - s0;
        const float inv = 1.0f / (float)(deg > 0 ? deg : 1);
        float4 o;
        o.x = ax * inv; o.y = ay * inv; o.z = az * inv; o.w = aw * inv;
        reinterpret_cast<float4*>(out_ent + (size_t)wid * CH)[q] = o;
    }
}

__global__ void user_gather_bf_kernel(const ushort_t* __restrict__ ebf,
                                      const uint2* __restrict__ upack,
                                      const int* __restrict__ offs,
                                      float* __restrict__ out_user,
                                      int n_users) {
    const int wid  = (blockIdx.x * blockDim.x + threadIdx.x) >> 6;
    const int lane = threadIdx.x & 63;
    const int g    = lane >> 4;
    const int q    = lane & 15;
    if (wid >= n_users) return;

    const int s0 = offs[wid], s1 = offs[wid + 1];
    float ax = 0.0f, ay = 0.0f, az = 0.0f, aw = 0.0f;
    float bx = 0.0f, by = 0.0f, bz = 0.0f, bw = 0.0f;

    int base = s0;
    for (; base + 8 <= s1; base += 8) {
        const uint2 cv0 = upack[base + g];
        const uint2 cv1 = upack[base + 4 + g];
        const float v0 = __uint_as_float(cv0.y);
        const float v1 = __uint_as_float(cv1.y);
        const uint2 p0 = *reinterpret_cast<const uint2*>(
            ebf + (size_t)cv0.x * CH + q * 4);
        const uint2 p1 = *reinterpret_cast<const uint2*>(
            ebf + (size_t)cv1.x * CH + q * 4);
        ax = fmaf(v0, bf_lo(p0.x), ax);
        ay = fmaf(v0, bf_hi(p0.x), ay);
        az = fmaf(v0, bf_lo(p0.y), az);
        aw = fmaf(v0, bf_hi(p0.y), aw);
        bx = fmaf(v1, bf_lo(p1.x), bx);
        by = fmaf(v1, bf_hi(p1.x), by);
        bz = fmaf(v1, bf_lo(p1.y), bz);
        bw = fmaf(v1, bf_hi(p1.y), bw);
    }
    for (; base < s1; base += 4) {
        const int e = base + g;
        const bool valid = (e < s1);
        uint2 cv;
        if (valid) cv = upack[e];
        else       { cv.x = 0u; cv.y = 0u; }
        const float v = __uint_as_float(cv.y);
        const uint2 p = *reinterpret_cast<const uint2*>(
            ebf + (size_t)cv.x * CH + q * 4);
        ax = fmaf(v, bf_lo(p.x), ax);
        ay = fmaf(v, bf_hi(p.x), ay);
        az = fmaf(v, bf_lo(p.y), az);
        aw = fmaf(v, bf_hi(p.y), aw);
    }
    ax += bx; ay += by; az += bz; aw += bw;

    ax += __shfl_xor(ax, 16); ay += __shfl_xor(ay, 16);
    az += __shfl_xor(az, 16); aw += __shfl_xor(aw, 16);
    ax += __shfl_xor(ax, 32); ay += __shfl_xor(ay, 32);
    az += __shfl_xor(az, 32); aw += __shfl_xor(aw, 32);

    if (g == 0) {
        float4 o; o.x = ax; o.y = ay; o.z = az; o.w = aw;
        reinterpret_cast<float4*>(out_user + (size_t)wid * CH)[q] = o;
    }
}

// =========================================================================
// Tier-2 (R14 CSR path): sliced hist/scatter
// =========================================================================
__global__ void hist_sliced_kernel(const int* __restrict__ keys,
                                   int* __restrict__ counts, int n, unsigned smul) {
    const int slice = blockIdx.x & (NSLICE - 1);
    const int rb    = blockIdx.x >> 3;
    const int nrb   = gridDim.x >> 3;
    const int per   = (n + nrb - 1) / nrb;
    const int i0    = rb * per;
    const int i1    = min(i0 + per, n);
    for (int i = i0 + (int)threadIdx.x; i < i1; i += blockDim.x) {
        const int k = keys[i];
        if ((int)__umulhi((unsigned)k, smul) == slice)
            atomicAdd(&counts[k], 1);
    }
}

__global__ void scatter_e_sliced_kernel(const int* __restrict__ edge_index,
                                        const int* __restrict__ edge_type,
                                        const int* __restrict__ offs,
                                        int* __restrict__ cursor,
                                        int* __restrict__ sorted_tr,
                                        int E, int n_rel, unsigned smul) {
    const int slice = blockIdx.x & (NSLICE - 1);
    const int rb    = blockIdx.x >> 3;
    const int nrb   = gridDim.x >> 3;
    const int per   = (E + nrb - 1) / nrb;
    const int e0    = rb * per;
    const int e1    = min(e0 + per, E);
    for (int e = e0 + (int)threadIdx.x; e < e1; e += blockDim.x) {
        const int h = edge_index[e];
        if ((int)__umulhi((unsigned)h, smul) != slice) continue;
        const int t = edge_index[(size_t)E + e];
        int r = edge_type[e] - 1;
        if (r < 0) r += n_rel;
        const int pos = offs[h] + atomicAdd(&cursor[h], 1);
        sorted_tr[pos] = t | (r << 17);
    }
}

__global__ void scatter_u_sliced_kernel(const int* __restrict__ irows,
                                        const int* __restrict__ icols,
                                        const float* __restrict__ ivals,
                                        const int* __restrict__ offs,
                                        int* __restrict__ cursor,
                                        uint2* __restrict__ upack,
                                        int NNZ, unsigned smul) {
    const int slice = blockIdx.x & (NSLICE - 1);
    const int rb    = blockIdx.x >> 3;
    const int nrb   = gridDim.x >> 3;
    const int per   = (NNZ + nrb - 1) / nrb;
    const int i0    = rb * per;
    const int i1    = min(i0 + per, NNZ);
    for (int i = i0 + (int)threadIdx.x; i < i1; i += blockDim.x) {
        const int u = irows[i];
        if ((int)__umulhi((unsigned)u, smul) != slice) continue;
        const int pos = offs[u] + atomicAdd(&cursor[u], 1);
        uint2 cv;
        cv.x = (unsigned)icols[i];
        cv.y = __float_as_uint(ivals[i]);
        upack[pos] = cv;
    }
}

// =========================================================================
// Tier-3 (atomic fallback)
// =========================================================================
__global__ void kg_agg_atomic_kernel(const float* __restrict__ emb,
                                     const float* __restrict__ region_ent,
                                     const int* __restrict__ edge_index,
                                     const int* __restrict__ edge_type,
                                     const float* __restrict__ weight,
                                     float* __restrict__ out_ent,
                                     float* __restrict__ counts,
                                     int E, int n_rel) {
    const long long gid = (long long)blockIdx.x * blockDim.x + threadIdx.x;
    const long long e = gid >> 6;
    if (e >= E) return;
    const int c = (int)gid & 63;
    const int h = edge_index[e];
    const int t = edge_index[(size_t)E + e];
    int r = edge_type[e] - 1;
    if (r < 0) r += n_rel;
    const float v = ent_val(emb, region_ent, t, c) * weight[(size_t)r * CH + c];
    unsafeAtomicAdd(out_ent + (size_t)h * CH + c, v);
    if (c == 0) unsafeAtomicAdd(counts + h, 1.0f);
}

__global__ void user_agg_atomic_kernel(const float* __restrict__ emb,
                                       const float* __restrict__ region_ent,
                                       const int* __restrict__ irows,
                                       const int* __restrict__ icols,
                                       const float* __restrict__ ivals,
                                       float* __restrict__ out_user, int NNZ) {
    const long long gid = (long long)blockIdx.x * blockDim.x + threadIdx.x;
    const long long i = gid >> 6;
    if (i >= NNZ) return;
    const int c = (int)gid & 63;
    const float v = ivals[i] * ent_val(emb, region_ent, icols[i], c);
    unsafeAtomicAdd(out_user + (size_t)irows[i] * CH + c, v);
}

__global__ void finalize_kernel(float* __restrict__ out_ent,
                                const float* __restrict__ counts, int n_entities) {
    const int gid = blockIdx.x * blockDim.x + threadIdx.x;
    if (gid >= n_entities * CH) return;
    out_ent[gid] /= fmaxf(counts[gid >> 6], 1.0f);
}

// =========================================================================
extern "C" void kernel_launch(void* const* d_in, const int* in_sizes, int n_in,
                              void* d_out, int out_size, void* d_ws, size_t ws_size,
                              hipStream_t stream) {
    const float* entity_emb = (const float*)d_in[0];
    const int*   edge_index = (const int*)d_in[2];
    const int*   edge_type  = (const int*)d_in[3];
    const int*   irows      = (const int*)d_in[4];
    const int*   icols      = (const int*)d_in[5];
    const float* ivals      = (const float*)d_in[6];
    const float* Wreg       = (const float*)d_in[7];
    const float* weight     = (const float*)d_in[8];

    const int n_entities = in_sizes[0] / CH;
    const int n_users    = in_sizes[1] / CH;
    const int E          = in_sizes[3];
    const int NNZ        = in_sizes[4];
    const int n_rel      = in_sizes[8] / CH;

    float* out_ent  = (float*)d_out;
    float* out_user = out_ent + (size_t)n_entities * CH;

    const int NBUK_E = (n_entities + 63) >> 6;
    const int NBUK_U = (n_users + 63) >> 6;
    const int n_e = NBUK_E * NB;
    const int n_u = NBUK_U * NB;
    const int nbse = (n_e + SCAN_B - 1) / SCAN_B;
    const int nbsu = (n_u + SCAN_B - 1) / SCAN_B;

    // ---- tier-1 (bucket) layout ----
    char* w = (char*)d_ws;
    auto take = [&](size_t bytes) {
        char* p = w;
        w += (bytes + 7) & ~(size_t)7;
        return p;
    };
    float*    region_ent = (float*)take((size_t)RN * CH * 4);
    ushort_t* e_t        = (ushort_t*)take((size_t)CH * KP * 2);
    ushort_t* ebf        = (ushort_t*)take((size_t)n_entities * CH * 2);
    int*      sorted_tr  = (int*)take((size_t)E * 4);
    uint2*    upack      = (uint2*)take((size_t)NNZ * 8);
    int*      offs_e     = (int*)take((size_t)(n_entities + 1) * 4);
    int*      offs_u     = (int*)take((size_t)(n_users + 1) * 4);
    int*      bsums      = (int*)take(512 * 4);
    int*      hist_e     = (int*)take((size_t)n_e * 4);
    int*      exbase_e   = (int*)take((size_t)(n_e + 1) * 4);
    int*      hist_u     = (int*)take((size_t)n_u * 4);
    int*      exbase_u   = (int*)take((size_t)(n_u + 1) * 4);
    int*      pcode_e    = (int*)take((size_t)E * 4);
    uint2*    pcode_u    = (uint2*)take((size_t)NNZ * 8);
    const size_t need_bucket = (size_t)(w - (char*)d_ws);

    const bool common_ok = (n_entities < (1 << 17)) && (n_rel <= 32);
    const bool use_bucket = common_ok && (ws_size >= need_bucket) &&
                            (NBUK_E <= MAXBUK) && (NBUK_U <= MAXBUK) &&
                            (nbse <= 512) && (nbsu <= 512);

    // ---- tier-2 (csr) layout ----
    char* w2 = (char*)d_ws;
    auto take2 = [&](size_t bytes) {
        char* p = w2;
        w2 += (bytes + 7) & ~(size_t)7;
        return p;
    };
    float*    c_region  = (float*)take2((size_t)RN * CH * 4);
    int*      c_offs_e  = (int*)take2((size_t)(n_entities + 1) * 4);
    int*      c_cur_e   = (int*)take2((size_t)n_entities * 4);
    int*      c_offs_u  = (int*)take2((size_t)(n_users + 1) * 4);
    int*      c_cur_u   = (int*)take2((size_t)n_users * 4);
    int*      c_bsums   = (int*)take2(512 * 4);
    int*      c_sorted  = (int*)take2((size_t)E * 4);
    uint2*    c_upack   = (uint2*)take2((size_t)NNZ * 8);
    ushort_t* c_et      = (ushort_t*)take2((size_t)CH * KP * 2);
    ushort_t* c_ebf     = (ushort_t*)take2((size_t)n_entities * CH * 2);
    const size_t need_csr = (size_t)(w2 - (char*)d_ws);
    const int nb_e = (n_entities + SCAN_B - 1) / SCAN_B;
    const int nb_u = (n_users + SCAN_B - 1) / SCAN_B;
    const bool use_csr = common_ok && (ws_size >= need_csr) &&
                         (nb_e <= 512) && (nb_u <= 512);

    if (use_bucket) {
        region_init_kernel<<<(RN * CH / 4 + 255) / 256, 256, 0, stream>>>(entity_emb, region_ent);
        {
            const int tot = CH * (KP / 8);
            build_et_kernel<<<(tot + 255) / 256, 256, 0, stream>>>(entity_emb, e_t);
        }
        region_gemm_mfma_kernel<<<MT_BLKS * KCHUNKS, 256, 0, stream>>>(
            Wreg, e_t, region_ent);
        {
            const int tot = n_entities * (CH / 8);
            build_ebf_kernel<<<(tot + 255) / 256, 256, 0, stream>>>(
                entity_emb, region_ent, ebf, n_entities);
        }

        // combined hist (edges + users in one launch)
        bucket_hist2_kernel<<<2 * NB, T1, 0, stream>>>(
            edge_index, E, NBUK_E, irows, NNZ, NBUK_U, hist_e, hist_u);

        // scans (small, sequential)
        scan_block_kernel<<<nbse, SCAN_B, 0, stream>>>(hist_e, exbase_e, bsums, n_e);
        scan_top_kernel<<<1, 512, 0, stream>>>(bsums, nbse);
        scan_add_kernel<<<nbse, SCAN_B, 0, stream>>>(exbase_e, bsums, n_e);

        scan_block_kernel<<<nbsu, SCAN_B, 0, stream>>>(hist_u, exbase_u, bsums, n_u);
        scan_top_kernel<<<1, 512, 0, stream>>>(bsums, nbsu);
        scan_add_kernel<<<nbsu, SCAN_B, 0, stream>>>(exbase_u, bsums, n_u);

        // combined pass2
        pass2_combined_kernel<<<2 * NB, T1, 0, stream>>>(
            edge_index, edge_type, exbase_e, pcode_e, E, n_rel, NBUK_E,
            irows, icols, ivals, exbase_u, pcode_u, NNZ, NBUK_U);

        // combined per-bucket sort
        bucket_sort2_kernel<<<NBUK_E + NBUK_U, 256, 0, stream>>>(
            pcode_e, exbase_e, sorted_tr, offs_e, n_entities, NBUK_E,
            pcode_u, exbase_u, upack, offs_u, n_users, NBUK_U);

        // gathers
        kg_gather_bf_kernel<<<(n_entities + 3) / 4, 256, n_rel * CH * 4, stream>>>(
            ebf, sorted_tr, offs_e, weight, out_ent, n_entities, n_rel);
        user_gather_bf_kernel<<<(n_users + 3) / 4, 256, 0, stream>>>(
            ebf, upack, offs_u, out_user, n_users);
    } else if (use_csr) {
        const unsigned smul_e = (unsigned)((8ULL << 32) / (unsigned long long)n_entities);
        const unsigned smul_u = (unsigned)((8ULL << 32) / (unsigned long long)n_users);

        region_init_kernel<<<(RN * CH / 4 + 255) / 256, 256, 0, stream>>>(entity_emb, c_region);
        {
            const int tot = CH * (KP / 8);
            build_et_kernel<<<(tot + 255) / 256, 256, 0, stream>>>(entity_emb, c_et);
        }
        region_gemm_mfma_kernel<<<MT_BLKS * KCHUNKS, 256, 0, stream>>>(
            Wreg, c_et, c_region);
        {
            const int tot = n_entities * (CH / 8);
            build_ebf_kernel<<<(tot + 255) / 256, 256, 0, stream>>>(
                entity_emb, c_region, c_ebf, n_entities);
        }

        hipMemsetAsync(c_cur_e, 0, (size_t)n_entities * 4, stream);
        hipMemsetAsync(c_cur_u, 0, (size_t)n_users * 4, stream);
        hist_sliced_kernel<<<NSLICE * SLICE_RB, 256, 0, stream>>>(
            edge_index, c_cur_e, E, smul_e);
        hist_sliced_kernel<<<NSLICE * SLICE_RB, 256, 0, stream>>>(
            irows, c_cur_u, NNZ, smul_u);

        scan_block_kernel<<<nb_e, SCAN_B, 0, stream>>>(c_cur_e, c_offs_e, c_bsums, n_entities);
        scan_top_kernel<<<1, 512, 0, stream>>>(c_bsums, nb_e);
        scan_add_kernel<<<nb_e, SCAN_B, 0, stream>>>(c_offs_e, c_bsums, n_entities);

        scan_block_kernel<<<nb_u, SCAN_B, 0, stream>>>(c_cur_u, c_offs_u, c_bsums, n_users);
        scan_top_kernel<<<1, 512, 0, stream>>>(c_bsums, nb_u);
        scan_add_kernel<<<nb_u, SCAN_B, 0, stream>>>(c_offs_u, c_bsums, n_users);

        hipMemsetAsync(c_cur_e, 0, (size_t)n_entities * 4, stream);
        hipMemsetAsync(c_cur_u, 0, (size_t)n_users * 4, stream);
        scatter_e_sliced_kernel<<<NSLICE * SLICE_RB, 256, 0, stream>>>(
            edge_index, edge_type, c_offs_e, c_cur_e, c_sorted, E, n_rel, smul_e);
        scatter_u_sliced_kernel<<<NSLICE * SLICE_RB, 256, 0, stream>>>(
            irows, icols, ivals, c_offs_u, c_cur_u, c_upack, NNZ, smul_u);

        kg_gather_bf_kernel<<<(n_entities + 3) / 4, 256, n_rel * CH * 4, stream>>>(
            c_ebf, c_sorted, c_offs_e, weight, out_ent, n_entities, n_rel);
        user_gather_bf_kernel<<<(n_users + 3) / 4, 256, 0, stream>>>(
            c_ebf, c_upack, c_offs_u, out_user, n_users);
    } else {
        // tier-3: atomic fallback
        float* region3 = (float*)d_ws;
        float* counts  = region3 + (size_t)RN * CH;
        region_init_kernel<<<(RN * CH / 4 + 255) / 256, 256, 0, stream>>>(entity_emb, region3);
        region_gemm_kernel<<<ROW_TILES * KSPLIT, 256, 0, stream>>>(
            entity_emb, Wreg, region3);
        hipMemsetAsync(d_out, 0, (size_t)out_size * sizeof(float), stream);
        hipMemsetAsync(counts, 0, (size_t)n_entities * sizeof(float), stream);
        {
            const long long tot = (long long)E * CH;
            kg_agg_atomic_kernel<<<(int)((tot + 255) / 256), 256, 0, stream>>>(
                entity_emb, region3, edge_index, edge_type, weight,
                out_ent, counts, E, n_rel);
        }
        {
            const long long tot = (long long)NNZ * CH;
            user_agg_atomic_kernel<<<(int)((tot + 255) / 256), 256, 0, stream>>>(
                entity_emb, region3, irows, icols, ivals, out_user, NNZ);
        }
        finalize_kernel<<<(n_entities * CH + 255) / 256, 256, 0, stream>>>(
            out_ent, counts, n_entities);
    }
}

// Round 22
// 202.340 us; speedup vs baseline: 5.8816x; 1.0573x over previous
//
#include <hip/hip_runtime.h>
#include <hip/hip_bf16.h>

// Problem constants (from reference source)
#define REGION_R0 42033
#define REGION_R1 44630
#define RN        (REGION_R1 - REGION_R0)   // 2597
#define CH        64
#define KSPLIT    32
#define ROW_TILES ((RN + 31) / 32)          // 82
#define SCAN_B    256
#define NSLICE    8
#define SLICE_RB  256                        // tier-2 grid

// bucket partition geometry
#define NB        64                         // range-blocks: 16-entry (64B) exclusive runs
#define T1        1024                       // 16 waves/block (R20-proven)
#define MAXBUK    2048

// MFMA region-gemm geometry
#define KTT       82
#define KP        (KTT * 32)                 // 2624
#define PERCHUNK  6
#define KCHUNKS   14
#define MT_TILES  163
#define MT_BLKS   41

typedef unsigned short ushort_t;
typedef short  bfrag8 __attribute__((ext_vector_type(8)));
typedef float  f32x4v __attribute__((ext_vector_type(4)));

// =========================================================================
// Region blend init (region_ent = 0.8 * orig)
// =========================================================================
__global__ void region_init_kernel(const float* __restrict__ emb,
                                   float* __restrict__ region_ent) {
    const int gid = blockIdx.x * blockDim.x + threadIdx.x;
    if (gid >= RN * CH / 4) return;
    const float4 v = reinterpret_cast<const float4*>(emb + (size_t)REGION_R0 * CH)[gid];
    float4 o;
    o.x = 0.8f * v.x; o.y = 0.8f * v.y; o.z = 0.8f * v.z; o.w = 0.8f * v.w;
    reinterpret_cast<float4*>(region_ent)[gid] = o;
}

__device__ __forceinline__ unsigned pack2bf(float a, float b) {
    unsigned ua = __float_as_uint(a);
    unsigned ub = __float_as_uint(b);
    ua += 0x7fffu + ((ua >> 16) & 1u);   // RNE
    ub += 0x7fffu + ((ub >> 16) & 1u);
    return ((ua >> 16) & 0xffffu) | (ub & 0xffff0000u);
}

// =========================================================================
// e_t[c][k] = bf16(emb[R0+k][c]) (B operand, transposed, zero-padded)
// =========================================================================
__global__ void build_et_kernel(const float* __restrict__ emb,
                                ushort_t* __restrict__ e_t) {
    const int gid = blockIdx.x * blockDim.x + threadIdx.x;
    if (gid >= CH * (KP / 8)) return;
    const int c  = gid / (KP / 8);
    const int k8 = gid - c * (KP / 8);
    const int kb = k8 * 8;
    float v[8];
#pragma unroll
    for (int j = 0; j < 8; ++j) {
        const int k = kb + j;
        v[j] = (k < RN) ? emb[(size_t)(REGION_R0 + k) * CH + c] : 0.0f;
    }
    uint4 o;
    o.x = pack2bf(v[0], v[1]); o.y = pack2bf(v[2], v[3]);
    o.z = pack2bf(v[4], v[5]); o.w = pack2bf(v[6], v[7]);
    *reinterpret_cast<uint4*>(e_t + (size_t)c * KP + kb) = o;
}

// =========================================================================
// MFMA region GEMM (R14-verified, absmax 0.25)
// =========================================================================
__global__ void region_gemm_mfma_kernel(const float* __restrict__ W,
                                        const ushort_t* __restrict__ e_t,
                                        float* __restrict__ region_ent) {
    const int wv    = threadIdx.x >> 6;
    const int lane  = threadIdx.x & 63;
    const int blk_m = blockIdx.x / KCHUNKS;
    const int kc    = blockIdx.x - blk_m * KCHUNKS;
    const int mt    = blk_m * 4 + wv;
    if (mt >= MT_TILES) return;
    const int l15 = lane & 15;
    const int lg  = lane >> 4;

    int arow = mt * 16 + l15;
    if (arow >= RN) arow = RN - 1;
    const float* wrow = W + (size_t)arow * RN;

    const int kt0 = kc * PERCHUNK;
    const int kt1 = (kt0 + PERCHUNK < KTT) ? (kt0 + PERCHUNK) : KTT;

    f32x4v acc[4];
#pragma unroll
    for (int n = 0; n < 4; ++n) acc[n] = (f32x4v){0.f, 0.f, 0.f, 0.f};

    for (int kt = kt0; kt < kt1; ++kt) {
        const int kb = kt * 32 + lg * 8;
        union { uint4 u; bfrag8 f; } A;
        if (kb + 8 <= RN) {
            float v0 = wrow[kb + 0], v1 = wrow[kb + 1];
            float v2 = wrow[kb + 2], v3 = wrow[kb + 3];
            float v4 = wrow[kb + 4], v5 = wrow[kb + 5];
            float v6 = wrow[kb + 6], v7 = wrow[kb + 7];
            A.u.x = pack2bf(v0, v1); A.u.y = pack2bf(v2, v3);
            A.u.z = pack2bf(v4, v5); A.u.w = pack2bf(v6, v7);
        } else {
            float v[8];
#pragma unroll
            for (int j = 0; j < 8; ++j) {
                const int k = kb + j;
                v[j] = (k < RN) ? wrow[k] : 0.0f;
            }
            A.u.x = pack2bf(v[0], v[1]); A.u.y = pack2bf(v[2], v[3]);
            A.u.z = pack2bf(v[4], v[5]); A.u.w = pack2bf(v[6], v[7]);
        }
#pragma unroll
        for (int n = 0; n < 4; ++n) {
            const bfrag8 B = *reinterpret_cast<const bfrag8*>(
                e_t + (size_t)(n * 16 + l15) * KP + kb);
            acc[n] = __builtin_amdgcn_mfma_f32_16x16x32_bf16(A.f, B, acc[n], 0, 0, 0);
        }
    }

#pragma unroll
    for (int n = 0; n < 4; ++n) {
#pragma unroll
        for (int j = 0; j < 4; ++j) {
            const int row = mt * 16 + lg * 4 + j;
            if (row < RN)
                unsafeAtomicAdd(region_ent + (size_t)row * CH + n * 16 + l15,
                                0.2f * acc[n][j]);
        }
    }
}

// =========================================================================
// VALU region GEMM (tier-3 fallback only)
// =========================================================================
__global__ void region_gemm_kernel(const float* __restrict__ emb,
                                   const float* __restrict__ W,
                                   float* __restrict__ region_ent) {
    const int wave = threadIdx.x >> 6;
    const int c    = threadIdx.x & 63;
    const int rt   = blockIdx.x / KSPLIT;
    const int ks   = blockIdx.x - rt * KSPLIT;
    const int base = rt * 32 + wave * 8;
    if (base >= RN) return;

    const int k0 = (RN * ks) / KSPLIT;
    const int k1 = (RN * (ks + 1)) / KSPLIT;

    const float* wp[8];
#pragma unroll
    for (int r = 0; r < 8; ++r) {
        int row = base + r;
        if (row >= RN) row = RN - 1;
        row = __builtin_amdgcn_readfirstlane(row);
        wp[r] = W + (size_t)row * RN;
    }
    const float* ep = emb + (size_t)REGION_R0 * CH + c;

    float acc[8];
#pragma unroll
    for (int r = 0; r < 8; ++r) acc[r] = 0.0f;

    int k = k0;
    for (; k + 4 <= k1; k += 4) {
        const float e0 = ep[(size_t)(k + 0) * CH];
        const float e1 = ep[(size_t)(k + 1) * CH];
        const float e2 = ep[(size_t)(k + 2) * CH];
        const float e3 = ep[(size_t)(k + 3) * CH];
#pragma unroll
        for (int r = 0; r < 8; ++r) {
            const float* wr = wp[r];
            float a = acc[r];
            a = fmaf(wr[k + 0], e0, a);
            a = fmaf(wr[k + 1], e1, a);
            a = fmaf(wr[k + 2], e2, a);
            a = fmaf(wr[k + 3], e3, a);
            acc[r] = a;
        }
    }
    for (; k < k1; ++k) {
        const float e = ep[(size_t)k * CH];
#pragma unroll
        for (int r = 0; r < 8; ++r) acc[r] = fmaf(wp[r][k], e, acc[r]);
    }
#pragma unroll
    for (int r = 0; r < 8; ++r) {
        const int row = base + r;
        if (row < RN)
            unsafeAtomicAdd(region_ent + (size_t)row * CH + c, 0.2f * acc[r]);
    }
}

__device__ __forceinline__ float ent_val(const float* __restrict__ emb,
                                         const float* __restrict__ region_ent,
                                         int row, int c) {
    const float* p = (row >= REGION_R0 && row < REGION_R1)
                         ? (region_ent + (size_t)(row - REGION_R0) * CH + c)
                         : (emb + (size_t)row * CH + c);
    return *p;
}

__device__ __forceinline__ const float* ent_row(const float* __restrict__ emb,
                                                const float* __restrict__ region_ent,
                                                int row) {
    return (row >= REGION_R0 && row < REGION_R1)
               ? (region_ent + (size_t)(row - REGION_R0) * CH)
               : (emb + (size_t)row * CH);
}

// =========================================================================
// bf16 entity table (region rows baked in)
// =========================================================================
__global__ void build_ebf_kernel(const float* __restrict__ emb,
                                 const float* __restrict__ region_ent,
                                 ushort_t* __restrict__ ebf,
                                 int n_entities) {
    const int gid = blockIdx.x * blockDim.x + threadIdx.x;
    if (gid >= n_entities * (CH / 8)) return;
    const int row = gid >> 3;
    const int co  = (gid & 7) * 8;
    const float* rp = ent_row(emb, region_ent, row) + co;
    const float4 a = *reinterpret_cast<const float4*>(rp);
    const float4 b = *reinterpret_cast<const float4*>(rp + 4);
    uint4 o;
    o.x = pack2bf(a.x, a.y);
    o.y = pack2bf(a.z, a.w);
    o.z = pack2bf(b.x, b.y);
    o.w = pack2bf(b.z, b.w);
    *reinterpret_cast<uint4*>(ebf + (size_t)row * CH + co) = o;
}

__device__ __forceinline__ float bf_lo(unsigned u) { return __uint_as_float(u << 16); }
__device__ __forceinline__ float bf_hi(unsigned u) { return __uint_as_float(u & 0xffff0000u); }

// =========================================================================
// Combined bucket hist: blocks [0,NB) = edges, [NB,2NB) = users.
// =========================================================================
__global__ void bucket_hist2_kernel(const int* __restrict__ ekeys, int ne, int nbe,
                                    const int* __restrict__ ukeys, int nu, int nbu,
                                    int* __restrict__ hist_e,
                                    int* __restrict__ hist_u) {
    __shared__ int lh[MAXBUK];
    const bool is_u = (blockIdx.x >= NB);
    const int  rb   = is_u ? (blockIdx.x - NB) : blockIdx.x;
    const int* keys = is_u ? ukeys : ekeys;
    const int  n    = is_u ? nu : ne;
    const int  nbuk = is_u ? nbu : nbe;
    int* hist       = is_u ? hist_u : hist_e;

    for (int i = threadIdx.x; i < nbuk; i += T1) lh[i] = 0;
    __syncthreads();
    const int chunk = (n + NB - 1) / NB;
    const int i0 = rb * chunk;
    const int i1 = min(i0 + chunk, n);
    for (int i = i0 + (int)threadIdx.x; i < i1; i += T1)
        atomicAdd(&lh[keys[i] >> 6], 1);
    __syncthreads();
    for (int b = threadIdx.x; b < nbuk; b += T1)
        hist[(size_t)b * NB + rb] = lh[b];
}

__global__ void scan_block_kernel(const int* __restrict__ counts, int* __restrict__ offs,
                                  int* __restrict__ bsums, int n) {
    __shared__ int s[SCAN_B];
    const int i = blockIdx.x * SCAN_B + threadIdx.x;
    s[threadIdx.x] = (i < n) ? counts[i] : 0;
    __syncthreads();
    for (int d = 1; d < SCAN_B; d <<= 1) {
        const int t = (threadIdx.x >= d) ? s[threadIdx.x - d] : 0;
        __syncthreads();
        s[threadIdx.x] += t;
        __syncthreads();
    }
    if (i < n) offs[i + 1] = s[threadIdx.x];
    if (threadIdx.x == SCAN_B - 1) bsums[blockIdx.x] = s[threadIdx.x];
    if (blockIdx.x == 0 && threadIdx.x == 0) offs[0] = 0;
}

__global__ void scan_top_kernel(int* __restrict__ bsums, int nb) {
    __shared__ int s[512];
    s[threadIdx.x] = (threadIdx.x < (unsigned)nb) ? bsums[threadIdx.x] : 0;
    __syncthreads();
    for (int d = 1; d < 512; d <<= 1) {
        const int t = (threadIdx.x >= d) ? s[threadIdx.x - d] : 0;
        __syncthreads();
        s[threadIdx.x] += t;
        __syncthreads();
    }
    if (threadIdx.x < (unsigned)nb) bsums[threadIdx.x] = s[threadIdx.x];
}

__global__ void scan_add_kernel(int* __restrict__ offs, const int* __restrict__ bsums, int n) {
    if (blockIdx.x == 0) return;
    const int i = blockIdx.x * SCAN_B + threadIdx.x;
    if (i < n) offs[i + 1] += bsums[blockIdx.x - 1];
}

// =========================================================================
// Combined pass2 (R20-proven; exbase row in LDS)
// =========================================================================
__global__ void pass2_combined_kernel(const int* __restrict__ edge_index,
                                      const int* __restrict__ edge_type,
                                      const int* __restrict__ exbase_e,
                                      int* __restrict__ pcode_e,
                                      int E, int n_rel, int nbe,
                                      const int* __restrict__ irows,
                                      const int* __restrict__ icols,
                                      const float* __restrict__ ivals,
                                      const int* __restrict__ exbase_u,
                                      uint2* __restrict__ pcode_u,
                                      int NNZ, int nbu) {
    __shared__ int cur[MAXBUK];
    __shared__ int exb[MAXBUK];
    const bool is_u = (blockIdx.x >= NB);
    const int  rb   = is_u ? (blockIdx.x - NB) : blockIdx.x;
    const int  nbuk = is_u ? nbu : nbe;
    const int* exbase = is_u ? exbase_u : exbase_e;

    for (int i = threadIdx.x; i < nbuk; i += T1) {
        cur[i] = 0;
        exb[i] = exbase[(size_t)i * NB + rb];
    }
    __syncthreads();

    if (!is_u) {
        const int chunk = (E + NB - 1) / NB;
        const int i0 = rb * chunk;
        const int i1 = min(i0 + chunk, E);
        for (int e = i0 + (int)threadIdx.x; e < i1; e += T1) {
            const int h = edge_index[e];
            const int b = h >> 6;
            const int loc = atomicAdd(&cur[b], 1);
            const int pos = exb[b] + loc;
            const int t = edge_index[(size_t)E + e];
            int r = edge_type[e] - 1;
            if (r < 0) r += n_rel;
            pcode_e[pos] = ((h & 63) << 22) | (r << 17) | t;
        }
    } else {
        const int chunk = (NNZ + NB - 1) / NB;
        const int i0 = rb * chunk;
        const int i1 = min(i0 + chunk, NNZ);
        for (int i = i0 + (int)threadIdx.x; i < i1; i += T1) {
            const int u = irows[i];
            const int b = u >> 6;
            const int loc = atomicAdd(&cur[b], 1);
            const int pos = exb[b] + loc;
            uint2 cv;
            cv.x = ((unsigned)(u & 63) << 17) | (unsigned)icols[i];
            cv.y = __float_as_uint(ivals[i]);
            pcode_u[pos] = cv;
        }
    }
}

// =========================================================================
// Combined per-bucket counting sort (R20-proven)
// =========================================================================
__global__ void bucket_sort2_kernel(const int* __restrict__ pcode_e,
                                    const int* __restrict__ exbase_e,
                                    int* __restrict__ sorted_tr,
                                    int* __restrict__ offs_e,
                                    int n_entities, int nbe,
                                    const uint2* __restrict__ pcode_u,
                                    const int* __restrict__ exbase_u,
                                    uint2* __restrict__ upack,
                                    int* __restrict__ offs_u,
                                    int n_users, int nbu) {
    __shared__ int cnt[64];
    __shared__ int off[64];
    __shared__ int cur[64];
    const bool is_u = (blockIdx.x >= (unsigned)nbe);
    const int  b    = is_u ? (blockIdx.x - nbe) : blockIdx.x;
    const int* exbase = is_u ? exbase_u : exbase_e;
    const int bstart = exbase[(size_t)b * NB];
    const int bend   = exbase[(size_t)(b + 1) * NB];
    if (threadIdx.x < 64) { cnt[threadIdx.x] = 0; cur[threadIdx.x] = 0; }
    __syncthreads();

    if (!is_u) {
        for (int i = bstart + (int)threadIdx.x; i < bend; i += blockDim.x)
            atomicAdd(&cnt[(pcode_e[i] >> 22) & 63], 1);
    } else {
        for (int i = bstart + (int)threadIdx.x; i < bend; i += blockDim.x)
            atomicAdd(&cnt[(pcode_u[i].x >> 17) & 63], 1);
    }
    __syncthreads();
    if (threadIdx.x == 0) {
        int s = 0;
#pragma unroll
        for (int i = 0; i < 64; ++i) { off[i] = s; s += cnt[i]; }
    }
    __syncthreads();

    if (!is_u) {
        const int h0 = b * 64;
        if (threadIdx.x < 64) {
            const int h = h0 + (int)threadIdx.x;
            if (h < n_entities) offs_e[h] = bstart + off[threadIdx.x];
        }
        if (b == nbe - 1 && threadIdx.x == 0) offs_e[n_entities] = bend;
        for (int i = bstart + (int)threadIdx.x; i < bend; i += blockDim.x) {
            const int p  = pcode_e[i];
            const int lh = (p >> 22) & 63;
            const int pos = bstart + off[lh] + atomicAdd(&cur[lh], 1);
            sorted_tr[pos] = p & 0x3FFFFF;
        }
    } else {
        const int u0 = b * 64;
        if (threadIdx.x < 64) {
            const int u = u0 + (int)threadIdx.x;
            if (u < n_users) offs_u[u] = bstart + off[threadIdx.x];
        }
        if (b == nbu - 1 && threadIdx.x == 0) offs_u[n_users] = bend;
        for (int i = bstart + (int)threadIdx.x; i < bend; i += blockDim.x) {
            const uint2 cv = pcode_u[i];
            const int lr = (int)(cv.x >> 17) & 63;
            const int pos = bstart + off[lr] + atomicAdd(&cur[lr], 1);
            uint2 o;
            o.x = cv.x & 0x1FFFFu;
            o.y = cv.y;
            upack[pos] = o;
        }
    }
}

// =========================================================================
// bf16 gather kernels v3: 8 lanes/row x uint4 (16B), 8 edges per wave-load,
// 16 edges in flight (x2 unroll). lane = (g = lane>>3 edge slot, q8 = lane&7).
// =========================================================================
__global__ void kg_gather_bf_kernel(const ushort_t* __restrict__ ebf,
                                    const int* __restrict__ sorted_tr,
                                    const int* __restrict__ offs,
                                    const float* __restrict__ weight,
                                    float* __restrict__ out_ent,
                                    int n_entities, int n_rel) {
    extern __shared__ float wl[];   // n_rel * CH
    for (int i = threadIdx.x; i < n_rel * CH; i += blockDim.x) wl[i] = weight[i];
    __syncthreads();
    const float4* wl4 = reinterpret_cast<const float4*>(wl);

    const int wid  = (blockIdx.x * blockDim.x + threadIdx.x) >> 6;
    const int lane = threadIdx.x & 63;
    const int g    = lane >> 3;     // edge slot 0..7
    const int q8   = lane & 7;      // channel octet 0..7
    if (wid >= n_entities) return;

    const int s0 = offs[wid], s1 = offs[wid + 1];
    float a0[8], a1[8];
#pragma unroll
    for (int j = 0; j < 8; ++j) { a0[j] = 0.f; a1[j] = 0.f; }

    int base = s0;
    for (; base + 16 <= s1; base += 16) {
        const int tr0 = sorted_tr[base + g];
        const int tr1 = sorted_tr[base + 8 + g];
        const uint4 p0 = *reinterpret_cast<const uint4*>(
            ebf + (size_t)(tr0 & 0x1FFFF) * CH + q8 * 8);
        const uint4 p1 = *reinterpret_cast<const uint4*>(
            ebf + (size_t)(tr1 & 0x1FFFF) * CH + q8 * 8);
        const float4 w0a = wl4[(tr0 >> 17) * 16 + q8 * 2];
        const float4 w0b = wl4[(tr0 >> 17) * 16 + q8 * 2 + 1];
        const float4 w1a = wl4[(tr1 >> 17) * 16 + q8 * 2];
        const float4 w1b = wl4[(tr1 >> 17) * 16 + q8 * 2 + 1];
        a0[0] = fmaf(bf_lo(p0.x), w0a.x, a0[0]);
        a0[1] = fmaf(bf_hi(p0.x), w0a.y, a0[1]);
        a0[2] = fmaf(bf_lo(p0.y), w0a.z, a0[2]);
        a0[3] = fmaf(bf_hi(p0.y), w0a.w, a0[3]);
        a0[4] = fmaf(bf_lo(p0.z), w0b.x, a0[4]);
        a0[5] = fmaf(bf_hi(p0.z), w0b.y, a0[5]);
        a0[6] = fmaf(bf_lo(p0.w), w0b.z, a0[6]);
        a0[7] = fmaf(bf_hi(p0.w), w0b.w, a0[7]);
        a1[0] = fmaf(bf_lo(p1.x), w1a.x, a1[0]);
        a1[1] = fmaf(bf_hi(p1.x), w1a.y, a1[1]);
        a1[2] = fmaf(bf_lo(p1.y), w1a.z, a1[2]);
        a1[3] = fmaf(bf_hi(p1.y), w1a.w, a1[3]);
        a1[4] = fmaf(bf_lo(p1.z), w1b.x, a1[4]);
        a1[5] = fmaf(bf_hi(p1.z), w1b.y, a1[5]);
        a1[6] = fmaf(bf_lo(p1.w), w1b.z, a1[6]);
        a1[7] = fmaf(bf_hi(p1.w), w1b.w, a1[7]);
    }
    for (; base < s1; base += 8) {
        const int e = base + g;
        const bool valid = (e < s1);
        const int tr = valid ? sorted_tr[e] : 0;
        uint4 p; p.x = 0u; p.y = 0u; p.z = 0u; p.w = 0u;
        if (valid)
            p = *reinterpret_cast<const uint4*>(
                ebf + (size_t)(tr & 0x1FFFF) * CH + q8 * 8);
        const float4 wa = wl4[(tr >> 17) * 16 + q8 * 2];
        const float4 wb = wl4[(tr >> 17) * 16 + q8 * 2 + 1];
        a0[0] = fmaf(bf_lo(p.x), wa.x, a0[0]);
        a0[1] = fmaf(bf_hi(p.x), wa.y, a0[1]);
        a0[2] = fmaf(bf_lo(p.y), wa.z, a0[2]);
        a0[3] = fmaf(bf_hi(p.y), wa.w, a0[3]);
        a0[4] = fmaf(bf_lo(p.z), wb.x, a0[4]);
        a0[5] = fmaf(bf_hi(p.z), wb.y, a0[5]);
        a0[6] = fmaf(bf_lo(p.w), wb.z, a0[6]);
        a0[7] = fmaf(bf_hi(p.w), wb.w, a0[7]);
    }
#pragma unroll
    for (int j = 0; j < 8; ++j) a0[j] += a1[j];

    // reduce across the 8 edge slots (lanes differing in bits 3..5)
#pragma unroll
    for (int j = 0; j < 8; ++j) {
        a0[j] += __shfl_xor(a0[j], 8);
        a0[j] += __shfl_xor(a0[j], 16);
        a0[j] += __shfl_xor(a0[j], 32);
    }

    if (g == 0) {
        const int deg = s1 - s0;
        const float inv = 1.0f / (float)(deg > 0 ? deg : 1);
        float4 o0, o1;
        o0.x = a0[0] * inv; o0.y = a0[1] * inv; o0.z = a0[2] * inv; o0.w = a0[3] * inv;
        o1.x = a0[4] * inv; o1.y = a0[5] * inv; o1.z = a0[6] * inv; o1.w = a0[7] * inv;
        float* op = out_ent + (size_t)wid * CH + q8 * 8;
        *reinterpret_cast<float4*>(op)     = o0;
        *reinterpret_cast<float4*>(op + 4) = o1;
    }
}

__global__ void user_gather_bf_kernel(const ushort_t* __restrict__ ebf,
                                      const uint2* __restrict__ upack,
                                      const int* __restrict__ offs,
                                      float* __restrict__ out_user,
                                      int n_users) {
    const int wid  = (blockIdx.x * blockDim.x + threadIdx.x) >> 6;
    const int lane = threadIdx.x & 63;
    const int g    = lane >> 3;
    const int q8   = lane & 7;
    if (wid >= n_users) return;

    const int s0 = offs[wid], s1 = offs[wid + 1];
    float a0[8], a1[8];
#pragma unroll
    for (int j = 0; j < 8; ++j) { a0[j] = 0.f; a1[j] = 0.f; }

    int base = s0;
    for (; base + 16 <= s1; base += 16) {
        const uint2 cv0 = upack[base + g];
        const uint2 cv1 = upack[base + 8 + g];
        const float v0 = __uint_as_float(cv0.y);
        const float v1 = __uint_as_float(cv1.y);
        const uint4 p0 = *reinterpret_cast<const uint4*>(
            ebf + (size_t)cv0.x * CH + q8 * 8);
        const uint4 p1 = *reinterpret_cast<const uint4*>(
            ebf + (size_t)cv1.x * CH + q8 * 8);
        a0[0] = fmaf(v0, bf_lo(p0.x), a0[0]);
        a0[1] = fmaf(v0, bf_hi(p0.x), a0[1]);
        a0[2] = fmaf(v0, bf_lo(p0.y), a0[2]);
        a0[3] = fmaf(v0, bf_hi(p0.y), a0[3]);
        a0[4] = fmaf(v0, bf_lo(p0.z), a0[4]);
        a0[5] = fmaf(v0, bf_hi(p0.z), a0[5]);
        a0[6] = fmaf(v0, bf_lo(p0.w), a0[6]);
        a0[7] = fmaf(v0, bf_hi(p0.w), a0[7]);
        a1[0] = fmaf(v1, bf_lo(p1.x), a1[0]);
        a1[1] = fmaf(v1, bf_hi(p1.x), a1[1]);
        a1[2] = fmaf(v1, bf_lo(p1.y), a1[2]);
        a1[3] = fmaf(v1, bf_hi(p1.y), a1[3]);
        a1[4] = fmaf(v1, bf_lo(p1.z), a1[4]);
        a1[5] = fmaf(v1, bf_hi(p1.z), a1[5]);
        a1[6] = fmaf(v1, bf_lo(p1.w), a1[6]);
        a1[7] = fmaf(v1, bf_hi(p1.w), a1[7]);
    }
    for (; base < s1; base += 8) {
        const int e = base + g;
        const bool valid = (e < s1);
        uint2 cv; cv.x = 0u; cv.y = 0u;
        if (valid) cv = upack[e];
        const float v = __uint_as_float(cv.y);   // 0 when invalid
        const uint4 p = *reinterpret_cast<const uint4*>(
            ebf + (size_t)cv.x * CH + q8 * 8);   // row 0 valid memory
        a0[0] = fmaf(v, bf_lo(p.x), a0[0]);
        a0[1] = fmaf(v, bf_hi(p.x), a0[1]);
        a0[2] = fmaf(v, bf_lo(p.y), a0[2]);
        a0[3] = fmaf(v, bf_hi(p.y), a0[3]);
        a0[4] = fmaf(v, bf_lo(p.z), a0[4]);
        a0[5] = fmaf(v, bf_hi(p.z), a0[5]);
        a0[6] = fmaf(v, bf_lo(p.w), a0[6]);
        a0[7] = fmaf(v, bf_hi(p.w), a0[7]);
    }
#pragma unroll
    for (int j = 0; j < 8; ++j) a0[j] += a1[j];

#pragma unroll
    for (int j = 0; j < 8; ++j) {
        a0[j] += __shfl_xor(a0[j], 8);
        a0[j] += __shfl_xor(a0[j], 16);
        a0[j] += __shfl_xor(a0[j], 32);
    }

    if (g == 0) {
        float4 o0, o1;
        o0.x = a0[0]; o0.y = a0[1]; o0.z = a0[2]; o0.w = a0[3];
        o1.x = a0[4]; o1.y = a0[5]; o1.z = a0[6]; o1.w = a0[7];
        float* op = out_user + (size_t)wid * CH + q8 * 8;
        *reinterpret_cast<float4*>(op)     = o0;
        *reinterpret_cast<float4*>(op + 4) = o1;
    }
}

// =========================================================================
// Tier-2 (R14 CSR path): sliced hist/scatter
// =========================================================================
__global__ void hist_sliced_kernel(const int* __restrict__ keys,
                                   int* __restrict__ counts, int n, unsigned smul) {
    const int slice = blockIdx.x & (NSLICE - 1);
    const int rb    = blockIdx.x >> 3;
    const int nrb   = gridDim.x >> 3;
    const int per   = (n + nrb - 1) / nrb;
    const int i0    = rb * per;
    const int i1    = min(i0 + per, n);
    for (int i = i0 + (int)threadIdx.x; i < i1; i += blockDim.x) {
        const int k = keys[i];
        if ((int)__umulhi((unsigned)k, smul) == slice)
            atomicAdd(&counts[k], 1);
    }
}

__global__ void scatter_e_sliced_kernel(const int* __restrict__ edge_index,
                                        const int* __restrict__ edge_type,
                                        const int* __restrict__ offs,
                                        int* __restrict__ cursor,
                                        int* __restrict__ sorted_tr,
                                        int E, int n_rel, unsigned smul) {
    const int slice = blockIdx.x & (NSLICE - 1);
    const int rb    = blockIdx.x >> 3;
    const int nrb   = gridDim.x >> 3;
    const int per   = (E + nrb - 1) / nrb;
    const int e0    = rb * per;
    const int e1    = min(e0 + per, E);
    for (int e = e0 + (int)threadIdx.x; e < e1; e += blockDim.x) {
        const int h = edge_index[e];
        if ((int)__umulhi((unsigned)h, smul) != slice) continue;
        const int t = edge_index[(size_t)E + e];
        int r = edge_type[e] - 1;
        if (r < 0) r += n_rel;
        const int pos = offs[h] + atomicAdd(&cursor[h], 1);
        sorted_tr[pos] = t | (r << 17);
    }
}

__global__ void scatter_u_sliced_kernel(const int* __restrict__ irows,
                                        const int* __restrict__ icols,
                                        const float* __restrict__ ivals,
                                        const int* __restrict__ offs,
                                        int* __restrict__ cursor,
                                        uint2* __restrict__ upack,
                                        int NNZ, unsigned smul) {
    const int slice = blockIdx.x & (NSLICE - 1);
    const int rb    = blockIdx.x >> 3;
    const int nrb   = gridDim.x >> 3;
    const int per   = (NNZ + nrb - 1) / nrb;
    const int i0    = rb * per;
    const int i1    = min(i0 + per, NNZ);
    for (int i = i0 + (int)threadIdx.x; i < i1; i += blockDim.x) {
        const int u = irows[i];
        if ((int)__umulhi((unsigned)u, smul) != slice) continue;
        const int pos = offs[u] + atomicAdd(&cursor[u], 1);
        uint2 cv;
        cv.x = (unsigned)icols[i];
        cv.y = __float_as_uint(ivals[i]);
        upack[pos] = cv;
    }
}

// =========================================================================
// Tier-3 (atomic fallback)
// =========================================================================
__global__ void kg_agg_atomic_kernel(const float* __restrict__ emb,
                                     const float* __restrict__ region_ent,
                                     const int* __restrict__ edge_index,
                                     const int* __restrict__ edge_type,
                                     const float* __restrict__ weight,
                                     float* __restrict__ out_ent,
                                     float* __restrict__ counts,
                                     int E, int n_rel) {
    const long long gid = (long long)blockIdx.x * blockDim.x + threadIdx.x;
    const long long e = gid >> 6;
    if (e >= E) return;
    const int c = (int)gid & 63;
    const int h = edge_index[e];
    const int t = edge_index[(size_t)E + e];
    int r = edge_type[e] - 1;
    if (r < 0) r += n_rel;
    const float v = ent_val(emb, region_ent, t, c) * weight[(size_t)r * CH + c];
    unsafeAtomicAdd(out_ent + (size_t)h * CH + c, v);
    if (c == 0) unsafeAtomicAdd(counts + h, 1.0f);
}

__global__ void user_agg_atomic_kernel(const float* __restrict__ emb,
                                       const float* __restrict__ region_ent,
                                       const int* __restrict__ irows,
                                       const int* __restrict__ icols,
                                       const float* __restrict__ ivals,
                                       float* __restrict__ out_user, int NNZ) {
    const long long gid = (long long)blockIdx.x * blockDim.x + threadIdx.x;
    const long long i = gid >> 6;
    if (i >= NNZ) return;
    const int c = (int)gid & 63;
    const float v = ivals[i] * ent_val(emb, region_ent, icols[i], c);
    unsafeAtomicAdd(out_user + (size_t)irows[i] * CH + c, v);
}

__global__ void finalize_kernel(float* __restrict__ out_ent,
                                const float* __restrict__ counts, int n_entities) {
    const int gid = blockIdx.x * blockDim.x + threadIdx.x;
    if (gid >= n_entities * CH) return;
    out_ent[gid] /= fmaxf(counts[gid >> 6], 1.0f);
}

// =========================================================================
extern "C" void kernel_launch(void* const* d_in, const int* in_sizes, int n_in,
                              void* d_out, int out_size, void* d_ws, size_t ws_size,
                              hipStream_t stream) {
    const float* entity_emb = (const float*)d_in[0];
    const int*   edge_index = (const int*)d_in[2];
    const int*   edge_type  = (const int*)d_in[3];
    const int*   irows      = (const int*)d_in[4];
    const int*   icols      = (const int*)d_in[5];
    const float* ivals      = (const float*)d_in[6];
    const float* Wreg       = (const float*)d_in[7];
    const float* weight     = (const float*)d_in[8];

    const int n_entities = in_sizes[0] / CH;
    const int n_users    = in_sizes[1] / CH;
    const int E          = in_sizes[3];
    const int NNZ        = in_sizes[4];
    const int n_rel      = in_sizes[8] / CH;

    float* out_ent  = (float*)d_out;
    float* out_user = out_ent + (size_t)n_entities * CH;

    const int NBUK_E = (n_entities + 63) >> 6;
    const int NBUK_U = (n_users + 63) >> 6;
    const int n_e = NBUK_E * NB;
    const int n_u = NBUK_U * NB;
    const int nbse = (n_e + SCAN_B - 1) / SCAN_B;
    const int nbsu = (n_u + SCAN_B - 1) / SCAN_B;

    // ---- tier-1 (bucket) layout ----
    char* w = (char*)d_ws;
    auto take = [&](size_t bytes) {
        char* p = w;
        w += (bytes + 7) & ~(size_t)7;
        return p;
    };
    float*    region_ent = (float*)take((size_t)RN * CH * 4);
    ushort_t* e_t        = (ushort_t*)take((size_t)CH * KP * 2);
    ushort_t* ebf        = (ushort_t*)take((size_t)n_entities * CH * 2);
    int*      sorted_tr  = (int*)take((size_t)E * 4);
    uint2*    upack      = (uint2*)take((size_t)NNZ * 8);
    int*      offs_e     = (int*)take((size_t)(n_entities + 1) * 4);
    int*      offs_u     = (int*)take((size_t)(n_users + 1) * 4);
    int*      bsums      = (int*)take(512 * 4);
    int*      hist_e     = (int*)take((size_t)n_e * 4);
    int*      exbase_e   = (int*)take((size_t)(n_e + 1) * 4);
    int*      hist_u     = (int*)take((size_t)n_u * 4);
    int*      exbase_u   = (int*)take((size_t)(n_u + 1) * 4);
    int*      pcode_e    = (int*)take((size_t)E * 4);
    uint2*    pcode_u    = (uint2*)take((size_t)NNZ * 8);
    const size_t need_bucket = (size_t)(w - (char*)d_ws);

    const bool common_ok = (n_entities < (1 << 17)) && (n_rel <= 32);
    const bool use_bucket = common_ok && (ws_size >= need_bucket) &&
                            (NBUK_E <= MAXBUK) && (NBUK_U <= MAXBUK) &&
                            (nbse <= 512) && (nbsu <= 512);

    // ---- tier-2 (csr) layout ----
    char* w2 = (char*)d_ws;
    auto take2 = [&](size_t bytes) {
        char* p = w2;
        w2 += (bytes + 7) & ~(size_t)7;
        return p;
    };
    float*    c_region  = (float*)take2((size_t)RN * CH * 4);
    int*      c_offs_e  = (int*)take2((size_t)(n_entities + 1) * 4);
    int*      c_cur_e   = (int*)take2((size_t)n_entities * 4);
    int*      c_offs_u  = (int*)take2((size_t)(n_users + 1) * 4);
    int*      c_cur_u   = (int*)take2((size_t)n_users * 4);
    int*      c_bsums   = (int*)take2(512 * 4);
    int*      c_sorted  = (int*)take2((size_t)E * 4);
    uint2*    c_upack   = (uint2*)take2((size_t)NNZ * 8);
    ushort_t* c_et      = (ushort_t*)take2((size_t)CH * KP * 2);
    ushort_t* c_ebf     = (ushort_t*)take2((size_t)n_entities * CH * 2);
    const size_t need_csr = (size_t)(w2 - (char*)d_ws);
    const int nb_e = (n_entities + SCAN_B - 1) / SCAN_B;
    const int nb_u = (n_users + SCAN_B - 1) / SCAN_B;
    const bool use_csr = common_ok && (ws_size >= need_csr) &&
                         (nb_e <= 512) && (nb_u <= 512);

    if (use_bucket) {
        region_init_kernel<<<(RN * CH / 4 + 255) / 256, 256, 0, stream>>>(entity_emb, region_ent);
        {
            const int tot = CH * (KP / 8);
            build_et_kernel<<<(tot + 255) / 256, 256, 0, stream>>>(entity_emb, e_t);
        }
        region_gemm_mfma_kernel<<<MT_BLKS * KCHUNKS, 256, 0, stream>>>(
            Wreg, e_t, region_ent);
        {
            const int tot = n_entities * (CH / 8);
            build_ebf_kernel<<<(tot + 255) / 256, 256, 0, stream>>>(
                entity_emb, region_ent, ebf, n_entities);
        }

        bucket_hist2_kernel<<<2 * NB, T1, 0, stream>>>(
            edge_index, E, NBUK_E, irows, NNZ, NBUK_U, hist_e, hist_u);

        scan_block_kernel<<<nbse, SCAN_B, 0, stream>>>(hist_e, exbase_e, bsums, n_e);
        scan_top_kernel<<<1, 512, 0, stream>>>(bsums, nbse);
        scan_add_kernel<<<nbse, SCAN_B, 0, stream>>>(exbase_e, bsums, n_e);

        scan_block_kernel<<<nbsu, SCAN_B, 0, stream>>>(hist_u, exbase_u, bsums, n_u);
        scan_top_kernel<<<1, 512, 0, stream>>>(bsums, nbsu);
        scan_add_kernel<<<nbsu, SCAN_B, 0, stream>>>(exbase_u, bsums, n_u);

        pass2_combined_kernel<<<2 * NB, T1, 0, stream>>>(
            edge_index, edge_type, exbase_e, pcode_e, E, n_rel, NBUK_E,
            irows, icols, ivals, exbase_u, pcode_u, NNZ, NBUK_U);

        bucket_sort2_kernel<<<NBUK_E + NBUK_U, 256, 0, stream>>>(
            pcode_e, exbase_e, sorted_tr, offs_e, n_entities, NBUK_E,
            pcode_u, exbase_u, upack, offs_u, n_users, NBUK_U);

        kg_gather_bf_kernel<<<(n_entities + 3) / 4, 256, n_rel * CH * 4, stream>>>(
            ebf, sorted_tr, offs_e, weight, out_ent, n_entities, n_rel);
        user_gather_bf_kernel<<<(n_users + 3) / 4, 256, 0, stream>>>(
            ebf, upack, offs_u, out_user, n_users);
    } else if (use_csr) {
        const unsigned smul_e = (unsigned)((8ULL << 32) / (unsigned long long)n_entities);
        const unsigned smul_u = (unsigned)((8ULL << 32) / (unsigned long long)n_users);

        region_init_kernel<<<(RN * CH / 4 + 255) / 256, 256, 0, stream>>>(entity_emb, c_region);
        {
            const int tot = CH * (KP / 8);
            build_et_kernel<<<(tot + 255) / 256, 256, 0, stream>>>(entity_emb, c_et);
        }
        region_gemm_mfma_kernel<<<MT_BLKS * KCHUNKS, 256, 0, stream>>>(
            Wreg, c_et, c_region);
        {
            const int tot = n_entities * (CH / 8);
            build_ebf_kernel<<<(tot + 255) / 256, 256, 0, stream>>>(
                entity_emb, c_region, c_ebf, n_entities);
        }

        hipMemsetAsync(c_cur_e, 0, (size_t)n_entities * 4, stream);
        hipMemsetAsync(c_cur_u, 0, (size_t)n_users * 4, stream);
        hist_sliced_kernel<<<NSLICE * SLICE_RB, 256, 0, stream>>>(
            edge_index, c_cur_e, E, smul_e);
        hist_sliced_kernel<<<NSLICE * SLICE_RB, 256, 0, stream>>>(
            irows, c_cur_u, NNZ, smul_u);

        scan_block_kernel<<<nb_e, SCAN_B, 0, stream>>>(c_cur_e, c_offs_e, c_bsums, n_entities);
        scan_top_kernel<<<1, 512, 0, stream>>>(c_bsums, nb_e);
        scan_add_kernel<<<nb_e, SCAN_B, 0, stream>>>(c_offs_e, c_bsums, n_entities);

        scan_block_kernel<<<nb_u, SCAN_B, 0, stream>>>(c_cur_u, c_offs_u, c_bsums, n_users);
        scan_top_kernel<<<1, 512, 0, stream>>>(c_bsums, nb_u);
        scan_add_kernel<<<nb_u, SCAN_B, 0, stream>>>(c_offs_u, c_bsums, n_users);

        hipMemsetAsync(c_cur_e, 0, (size_t)n_entities * 4, stream);
        hipMemsetAsync(c_cur_u, 0, (size_t)n_users * 4, stream);
        scatter_e_sliced_kernel<<<NSLICE * SLICE_RB, 256, 0, stream>>>(
            edge_index, edge_type, c_offs_e, c_cur_e, c_sorted, E, n_rel, smul_e);
        scatter_u_sliced_kernel<<<NSLICE * SLICE_RB, 256, 0, stream>>>(
            irows, icols, ivals, c_offs_u, c_cur_u, c_upack, NNZ, smul_u);

        kg_gather_bf_kernel<<<(n_entities + 3) / 4, 256, n_rel * CH * 4, stream>>>(
            c_ebf, c_sorted, c_offs_e, weight, out_ent, n_entities, n_rel);
        user_gather_bf_kernel<<<(n_users + 3) / 4, 256, 0, stream>>>(
            c_ebf, c_upack, c_offs_u, out_user, n_users);
    } else {
        // tier-3: atomic fallback
        float* region3 = (float*)d_ws;
        float* counts  = region3 + (size_t)RN * CH;
        region_init_kernel<<<(RN * CH / 4 + 255) / 256, 256, 0, stream>>>(entity_emb, region3);
        region_gemm_kernel<<<ROW_TILES * KSPLIT, 256, 0, stream>>>(
            entity_emb, Wreg, region3);
        hipMemsetAsync(d_out, 0, (size_t)out_size * sizeof(float), stream);
        hipMemsetAsync(counts, 0, (size_t)n_entities * sizeof(float), stream);
        {
            const long long tot = (long long)E * CH;
            kg_agg_atomic_kernel<<<(int)((tot + 255) / 256), 256, 0, stream>>>(
                entity_emb, region3, edge_index, edge_type, weight,
                out_ent, counts, E, n_rel);
        }
        {
            const long long tot = (long long)NNZ * CH;
            user_agg_atomic_kernel<<<(int)((tot + 255) / 256), 256, 0, stream>>>(
                entity_emb, region3, irows, icols, ivals, out_user, NNZ);
        }
        finalize_kernel<<<(n_entities * CH + 255) / 256, 256, 0, stream>>>(
            out_ent, counts, n_entities);
    }
}

// Round 23
// 195.033 us; speedup vs baseline: 6.1019x; 1.0375x over previous
//
#include <hip/hip_runtime.h>
#include <hip/hip_bf16.h>

// Problem constants (from reference source)
#define REGION_R0 42033
#define REGION_R1 44630
#define RN        (REGION_R1 - REGION_R0)   // 2597
#define CH        64
#define KSPLIT    32
#define ROW_TILES ((RN + 31) / 32)          // 82
#define SCAN_B    256
#define NSLICE    8
#define SLICE_RB  256                        // tier-2 grid

// bucket partition geometry
#define NB        64                         // range-blocks: 16-entry (64B) exclusive runs
#define T1        1024                       // 16 waves/block
#define MAXBUK    2048

// MFMA region-gemm geometry
#define KTT       82
#define KP        (KTT * 32)                 // 2624
#define PERCHUNK  6
#define KCHUNKS   14
#define MT_TILES  163
#define MT_BLKS   41

typedef unsigned short ushort_t;
typedef short  bfrag8 __attribute__((ext_vector_type(8)));
typedef float  f32x4v __attribute__((ext_vector_type(4)));

// =========================================================================
// Region blend init (region_ent = 0.8 * orig)
// =========================================================================
__global__ void region_init_kernel(const float* __restrict__ emb,
                                   float* __restrict__ region_ent) {
    const int gid = blockIdx.x * blockDim.x + threadIdx.x;
    if (gid >= RN * CH / 4) return;
    const float4 v = reinterpret_cast<const float4*>(emb + (size_t)REGION_R0 * CH)[gid];
    float4 o;
    o.x = 0.8f * v.x; o.y = 0.8f * v.y; o.z = 0.8f * v.z; o.w = 0.8f * v.w;
    reinterpret_cast<float4*>(region_ent)[gid] = o;
}

__device__ __forceinline__ unsigned pack2bf(float a, float b) {
    unsigned ua = __float_as_uint(a);
    unsigned ub = __float_as_uint(b);
    ua += 0x7fffu + ((ua >> 16) & 1u);   // RNE
    ub += 0x7fffu + ((ub >> 16) & 1u);
    return ((ua >> 16) & 0xffffu) | (ub & 0xffff0000u);
}

// =========================================================================
// e_t[c][k] = bf16(emb[R0+k][c]) (B operand, transposed, zero-padded)
// =========================================================================
__global__ void build_et_kernel(const float* __restrict__ emb,
                                ushort_t* __restrict__ e_t) {
    const int gid = blockIdx.x * blockDim.x + threadIdx.x;
    if (gid >= CH * (KP / 8)) return;
    const int c  = gid / (KP / 8);
    const int k8 = gid - c * (KP / 8);
    const int kb = k8 * 8;
    float v[8];
#pragma unroll
    for (int j = 0; j < 8; ++j) {
        const int k = kb + j;
        v[j] = (k < RN) ? emb[(size_t)(REGION_R0 + k) * CH + c] : 0.0f;
    }
    uint4 o;
    o.x = pack2bf(v[0], v[1]); o.y = pack2bf(v[2], v[3]);
    o.z = pack2bf(v[4], v[5]); o.w = pack2bf(v[6], v[7]);
    *reinterpret_cast<uint4*>(e_t + (size_t)c * KP + kb) = o;
}

// =========================================================================
// MFMA region GEMM (R14-verified, absmax 0.25)
// =========================================================================
__global__ void region_gemm_mfma_kernel(const float* __restrict__ W,
                                        const ushort_t* __restrict__ e_t,
                                        float* __restrict__ region_ent) {
    const int wv    = threadIdx.x >> 6;
    const int lane  = threadIdx.x & 63;
    const int blk_m = blockIdx.x / KCHUNKS;
    const int kc    = blockIdx.x - blk_m * KCHUNKS;
    const int mt    = blk_m * 4 + wv;
    if (mt >= MT_TILES) return;
    const int l15 = lane & 15;
    const int lg  = lane >> 4;

    int arow = mt * 16 + l15;
    if (arow >= RN) arow = RN - 1;
    const float* wrow = W + (size_t)arow * RN;

    const int kt0 = kc * PERCHUNK;
    const int kt1 = (kt0 + PERCHUNK < KTT) ? (kt0 + PERCHUNK) : KTT;

    f32x4v acc[4];
#pragma unroll
    for (int n = 0; n < 4; ++n) acc[n] = (f32x4v){0.f, 0.f, 0.f, 0.f};

    for (int kt = kt0; kt < kt1; ++kt) {
        const int kb = kt * 32 + lg * 8;
        union { uint4 u; bfrag8 f; } A;
        if (kb + 8 <= RN) {
            float v0 = wrow[kb + 0], v1 = wrow[kb + 1];
            float v2 = wrow[kb + 2], v3 = wrow[kb + 3];
            float v4 = wrow[kb + 4], v5 = wrow[kb + 5];
            float v6 = wrow[kb + 6], v7 = wrow[kb + 7];
            A.u.x = pack2bf(v0, v1); A.u.y = pack2bf(v2, v3);
            A.u.z = pack2bf(v4, v5); A.u.w = pack2bf(v6, v7);
        } else {
            float v[8];
#pragma unroll
            for (int j = 0; j < 8; ++j) {
                const int k = kb + j;
                v[j] = (k < RN) ? wrow[k] : 0.0f;
            }
            A.u.x = pack2bf(v[0], v[1]); A.u.y = pack2bf(v[2], v[3]);
            A.u.z = pack2bf(v[4], v[5]); A.u.w = pack2bf(v[6], v[7]);
        }
#pragma unroll
        for (int n = 0; n < 4; ++n) {
            const bfrag8 B = *reinterpret_cast<const bfrag8*>(
                e_t + (size_t)(n * 16 + l15) * KP + kb);
            acc[n] = __builtin_amdgcn_mfma_f32_16x16x32_bf16(A.f, B, acc[n], 0, 0, 0);
        }
    }

#pragma unroll
    for (int n = 0; n < 4; ++n) {
#pragma unroll
        for (int j = 0; j < 4; ++j) {
            const int row = mt * 16 + lg * 4 + j;
            if (row < RN)
                unsafeAtomicAdd(region_ent + (size_t)row * CH + n * 16 + l15,
                                0.2f * acc[n][j]);
        }
    }
}

// =========================================================================
// VALU region GEMM (tier-3 fallback only)
// =========================================================================
__global__ void region_gemm_kernel(const float* __restrict__ emb,
                                   const float* __restrict__ W,
                                   float* __restrict__ region_ent) {
    const int wave = threadIdx.x >> 6;
    const int c    = threadIdx.x & 63;
    const int rt   = blockIdx.x / KSPLIT;
    const int ks   = blockIdx.x - rt * KSPLIT;
    const int base = rt * 32 + wave * 8;
    if (base >= RN) return;

    const int k0 = (RN * ks) / KSPLIT;
    const int k1 = (RN * (ks + 1)) / KSPLIT;

    const float* wp[8];
#pragma unroll
    for (int r = 0; r < 8; ++r) {
        int row = base + r;
        if (row >= RN) row = RN - 1;
        row = __builtin_amdgcn_readfirstlane(row);
        wp[r] = W + (size_t)row * RN;
    }
    const float* ep = emb + (size_t)REGION_R0 * CH + c;

    float acc[8];
#pragma unroll
    for (int r = 0; r < 8; ++r) acc[r] = 0.0f;

    int k = k0;
    for (; k + 4 <= k1; k += 4) {
        const float e0 = ep[(size_t)(k + 0) * CH];
        const float e1 = ep[(size_t)(k + 1) * CH];
        const float e2 = ep[(size_t)(k + 2) * CH];
        const float e3 = ep[(size_t)(k + 3) * CH];
#pragma unroll
        for (int r = 0; r < 8; ++r) {
            const float* wr = wp[r];
            float a = acc[r];
            a = fmaf(wr[k + 0], e0, a);
            a = fmaf(wr[k + 1], e1, a);
            a = fmaf(wr[k + 2], e2, a);
            a = fmaf(wr[k + 3], e3, a);
            acc[r] = a;
        }
    }
    for (; k < k1; ++k) {
        const float e = ep[(size_t)k * CH];
#pragma unroll
        for (int r = 0; r < 8; ++r) acc[r] = fmaf(wp[r][k], e, acc[r]);
    }
#pragma unroll
    for (int r = 0; r < 8; ++r) {
        const int row = base + r;
        if (row < RN)
            unsafeAtomicAdd(region_ent + (size_t)row * CH + c, 0.2f * acc[r]);
    }
}

__device__ __forceinline__ float ent_val(const float* __restrict__ emb,
                                         const float* __restrict__ region_ent,
                                         int row, int c) {
    const float* p = (row >= REGION_R0 && row < REGION_R1)
                         ? (region_ent + (size_t)(row - REGION_R0) * CH + c)
                         : (emb + (size_t)row * CH + c);
    return *p;
}

__device__ __forceinline__ const float* ent_row(const float* __restrict__ emb,
                                                const float* __restrict__ region_ent,
                                                int row) {
    return (row >= REGION_R0 && row < REGION_R1)
               ? (region_ent + (size_t)(row - REGION_R0) * CH)
               : (emb + (size_t)row * CH);
}

// =========================================================================
// bf16 entity table (region rows baked in)
// =========================================================================
__global__ void build_ebf_kernel(const float* __restrict__ emb,
                                 const float* __restrict__ region_ent,
                                 ushort_t* __restrict__ ebf,
                                 int n_entities) {
    const int gid = blockIdx.x * blockDim.x + threadIdx.x;
    if (gid >= n_entities * (CH / 8)) return;
    const int row = gid >> 3;
    const int co  = (gid & 7) * 8;
    const float* rp = ent_row(emb, region_ent, row) + co;
    const float4 a = *reinterpret_cast<const float4*>(rp);
    const float4 b = *reinterpret_cast<const float4*>(rp + 4);
    uint4 o;
    o.x = pack2bf(a.x, a.y);
    o.y = pack2bf(a.z, a.w);
    o.z = pack2bf(b.x, b.y);
    o.w = pack2bf(b.z, b.w);
    *reinterpret_cast<uint4*>(ebf + (size_t)row * CH + co) = o;
}

__device__ __forceinline__ float bf_lo(unsigned u) { return __uint_as_float(u << 16); }
__device__ __forceinline__ float bf_hi(unsigned u) { return __uint_as_float(u & 0xffff0000u); }

// =========================================================================
// Combined bucket hist (R23: x4 unrolled key loads)
// =========================================================================
__global__ void bucket_hist2_kernel(const int* __restrict__ ekeys, int ne, int nbe,
                                    const int* __restrict__ ukeys, int nu, int nbu,
                                    int* __restrict__ hist_e,
                                    int* __restrict__ hist_u) {
    __shared__ int lh[MAXBUK];
    const bool is_u = (blockIdx.x >= NB);
    const int  rb   = is_u ? (blockIdx.x - NB) : blockIdx.x;
    const int* keys = is_u ? ukeys : ekeys;
    const int  n    = is_u ? nu : ne;
    const int  nbuk = is_u ? nbu : nbe;
    int* hist       = is_u ? hist_u : hist_e;

    for (int i = threadIdx.x; i < nbuk; i += T1) lh[i] = 0;
    __syncthreads();
    const int chunk = (n + NB - 1) / NB;
    const int i0 = rb * chunk;
    const int i1 = min(i0 + chunk, n);
    int i = i0 + (int)threadIdx.x;
    for (; i + 3 * T1 < i1; i += 4 * T1) {
        const int k0 = keys[i];
        const int k1 = keys[i + T1];
        const int k2 = keys[i + 2 * T1];
        const int k3 = keys[i + 3 * T1];
        atomicAdd(&lh[k0 >> 6], 1);
        atomicAdd(&lh[k1 >> 6], 1);
        atomicAdd(&lh[k2 >> 6], 1);
        atomicAdd(&lh[k3 >> 6], 1);
    }
    for (; i < i1; i += T1)
        atomicAdd(&lh[keys[i] >> 6], 1);
    __syncthreads();
    for (int b = threadIdx.x; b < nbuk; b += T1)
        hist[(size_t)b * NB + rb] = lh[b];
}

__global__ void scan_block_kernel(const int* __restrict__ counts, int* __restrict__ offs,
                                  int* __restrict__ bsums, int n) {
    __shared__ int s[SCAN_B];
    const int i = blockIdx.x * SCAN_B + threadIdx.x;
    s[threadIdx.x] = (i < n) ? counts[i] : 0;
    __syncthreads();
    for (int d = 1; d < SCAN_B; d <<= 1) {
        const int t = (threadIdx.x >= d) ? s[threadIdx.x - d] : 0;
        __syncthreads();
        s[threadIdx.x] += t;
        __syncthreads();
    }
    if (i < n) offs[i + 1] = s[threadIdx.x];
    if (threadIdx.x == SCAN_B - 1) bsums[blockIdx.x] = s[threadIdx.x];
    if (blockIdx.x == 0 && threadIdx.x == 0) offs[0] = 0;
}

__global__ void scan_top_kernel(int* __restrict__ bsums, int nb) {
    __shared__ int s[512];
    s[threadIdx.x] = (threadIdx.x < (unsigned)nb) ? bsums[threadIdx.x] : 0;
    __syncthreads();
    for (int d = 1; d < 512; d <<= 1) {
        const int t = (threadIdx.x >= d) ? s[threadIdx.x - d] : 0;
        __syncthreads();
        s[threadIdx.x] += t;
        __syncthreads();
    }
    if (threadIdx.x < (unsigned)nb) bsums[threadIdx.x] = s[threadIdx.x];
}

__global__ void scan_add_kernel(int* __restrict__ offs, const int* __restrict__ bsums, int n) {
    if (blockIdx.x == 0) return;
    const int i = blockIdx.x * SCAN_B + threadIdx.x;
    if (i < n) offs[i + 1] += bsums[blockIdx.x - 1];
}

// =========================================================================
// Combined pass2 (R23: x4 unrolled — 4 independent load->atomic->store chains)
// =========================================================================
__global__ void pass2_combined_kernel(const int* __restrict__ edge_index,
                                      const int* __restrict__ edge_type,
                                      const int* __restrict__ exbase_e,
                                      int* __restrict__ pcode_e,
                                      int E, int n_rel, int nbe,
                                      const int* __restrict__ irows,
                                      const int* __restrict__ icols,
                                      const float* __restrict__ ivals,
                                      const int* __restrict__ exbase_u,
                                      uint2* __restrict__ pcode_u,
                                      int NNZ, int nbu) {
    __shared__ int cur[MAXBUK];
    __shared__ int exb[MAXBUK];
    const bool is_u = (blockIdx.x >= NB);
    const int  rb   = is_u ? (blockIdx.x - NB) : blockIdx.x;
    const int  nbuk = is_u ? nbu : nbe;
    const int* exbase = is_u ? exbase_u : exbase_e;

    for (int i = threadIdx.x; i < nbuk; i += T1) {
        cur[i] = 0;
        exb[i] = exbase[(size_t)i * NB + rb];
    }
    __syncthreads();

    if (!is_u) {
        const int chunk = (E + NB - 1) / NB;
        const int i0 = rb * chunk;
        const int i1 = min(i0 + chunk, E);
        int e = i0 + (int)threadIdx.x;
        for (; e + 3 * T1 < i1; e += 4 * T1) {
            const int h0 = edge_index[e];
            const int h1 = edge_index[e + T1];
            const int h2 = edge_index[e + 2 * T1];
            const int h3 = edge_index[e + 3 * T1];
            const int t0 = edge_index[(size_t)E + e];
            const int t1 = edge_index[(size_t)E + e + T1];
            const int t2 = edge_index[(size_t)E + e + 2 * T1];
            const int t3 = edge_index[(size_t)E + e + 3 * T1];
            int r0 = edge_type[e] - 1;             if (r0 < 0) r0 += n_rel;
            int r1 = edge_type[e + T1] - 1;        if (r1 < 0) r1 += n_rel;
            int r2 = edge_type[e + 2 * T1] - 1;    if (r2 < 0) r2 += n_rel;
            int r3 = edge_type[e + 3 * T1] - 1;    if (r3 < 0) r3 += n_rel;
            const int b0 = h0 >> 6, b1 = h1 >> 6, b2 = h2 >> 6, b3 = h3 >> 6;
            const int l0 = atomicAdd(&cur[b0], 1);
            const int l1 = atomicAdd(&cur[b1], 1);
            const int l2 = atomicAdd(&cur[b2], 1);
            const int l3 = atomicAdd(&cur[b3], 1);
            pcode_e[exb[b0] + l0] = ((h0 & 63) << 22) | (r0 << 17) | t0;
            pcode_e[exb[b1] + l1] = ((h1 & 63) << 22) | (r1 << 17) | t1;
            pcode_e[exb[b2] + l2] = ((h2 & 63) << 22) | (r2 << 17) | t2;
            pcode_e[exb[b3] + l3] = ((h3 & 63) << 22) | (r3 << 17) | t3;
        }
        for (; e < i1; e += T1) {
            const int h = edge_index[e];
            const int b = h >> 6;
            const int loc = atomicAdd(&cur[b], 1);
            const int pos = exb[b] + loc;
            const int t = edge_index[(size_t)E + e];
            int r = edge_type[e] - 1;
            if (r < 0) r += n_rel;
            pcode_e[pos] = ((h & 63) << 22) | (r << 17) | t;
        }
    } else {
        const int chunk = (NNZ + NB - 1) / NB;
        const int i0 = rb * chunk;
        const int i1 = min(i0 + chunk, NNZ);
        int i = i0 + (int)threadIdx.x;
        for (; i + 3 * T1 < i1; i += 4 * T1) {
            const int u0 = irows[i];
            const int u1 = irows[i + T1];
            const int u2 = irows[i + 2 * T1];
            const int u3 = irows[i + 3 * T1];
            const int c0 = icols[i];
            const int c1 = icols[i + T1];
            const int c2 = icols[i + 2 * T1];
            const int c3 = icols[i + 3 * T1];
            const float v0 = ivals[i];
            const float v1 = ivals[i + T1];
            const float v2 = ivals[i + 2 * T1];
            const float v3 = ivals[i + 3 * T1];
            const int b0 = u0 >> 6, b1 = u1 >> 6, b2 = u2 >> 6, b3 = u3 >> 6;
            const int l0 = atomicAdd(&cur[b0], 1);
            const int l1 = atomicAdd(&cur[b1], 1);
            const int l2 = atomicAdd(&cur[b2], 1);
            const int l3 = atomicAdd(&cur[b3], 1);
            uint2 cv;
            cv.x = ((unsigned)(u0 & 63) << 17) | (unsigned)c0;
            cv.y = __float_as_uint(v0);
            pcode_u[exb[b0] + l0] = cv;
            cv.x = ((unsigned)(u1 & 63) << 17) | (unsigned)c1;
            cv.y = __float_as_uint(v1);
            pcode_u[exb[b1] + l1] = cv;
            cv.x = ((unsigned)(u2 & 63) << 17) | (unsigned)c2;
            cv.y = __float_as_uint(v2);
            pcode_u[exb[b2] + l2] = cv;
            cv.x = ((unsigned)(u3 & 63) << 17) | (unsigned)c3;
            cv.y = __float_as_uint(v3);
            pcode_u[exb[b3] + l3] = cv;
        }
        for (; i < i1; i += T1) {
            const int u = irows[i];
            const int b = u >> 6;
            const int loc = atomicAdd(&cur[b], 1);
            const int pos = exb[b] + loc;
            uint2 cv;
            cv.x = ((unsigned)(u & 63) << 17) | (unsigned)icols[i];
            cv.y = __float_as_uint(ivals[i]);
            pcode_u[pos] = cv;
        }
    }
}

// =========================================================================
// Combined per-bucket counting sort (R20-proven)
// =========================================================================
__global__ void bucket_sort2_kernel(const int* __restrict__ pcode_e,
                                    const int* __restrict__ exbase_e,
                                    int* __restrict__ sorted_tr,
                                    int* __restrict__ offs_e,
                                    int n_entities, int nbe,
                                    const uint2* __restrict__ pcode_u,
                                    const int* __restrict__ exbase_u,
                                    uint2* __restrict__ upack,
                                    int* __restrict__ offs_u,
                                    int n_users, int nbu) {
    __shared__ int cnt[64];
    __shared__ int off[64];
    __shared__ int cur[64];
    const bool is_u = (blockIdx.x >= (unsigned)nbe);
    const int  b    = is_u ? (blockIdx.x - nbe) : blockIdx.x;
    const int* exbase = is_u ? exbase_u : exbase_e;
    const int bstart = exbase[(size_t)b * NB];
    const int bend   = exbase[(size_t)(b + 1) * NB];
    if (threadIdx.x < 64) { cnt[threadIdx.x] = 0; cur[threadIdx.x] = 0; }
    __syncthreads();

    if (!is_u) {
        for (int i = bstart + (int)threadIdx.x; i < bend; i += blockDim.x)
            atomicAdd(&cnt[(pcode_e[i] >> 22) & 63], 1);
    } else {
        for (int i = bstart + (int)threadIdx.x; i < bend; i += blockDim.x)
            atomicAdd(&cnt[(pcode_u[i].x >> 17) & 63], 1);
    }
    __syncthreads();
    if (threadIdx.x == 0) {
        int s = 0;
#pragma unroll
        for (int i = 0; i < 64; ++i) { off[i] = s; s += cnt[i]; }
    }
    __syncthreads();

    if (!is_u) {
        const int h0 = b * 64;
        if (threadIdx.x < 64) {
            const int h = h0 + (int)threadIdx.x;
            if (h < n_entities) offs_e[h] = bstart + off[threadIdx.x];
        }
        if (b == nbe - 1 && threadIdx.x == 0) offs_e[n_entities] = bend;
        for (int i = bstart + (int)threadIdx.x; i < bend; i += blockDim.x) {
            const int p  = pcode_e[i];
            const int lh = (p >> 22) & 63;
            const int pos = bstart + off[lh] + atomicAdd(&cur[lh], 1);
            sorted_tr[pos] = p & 0x3FFFFF;
        }
    } else {
        const int u0 = b * 64;
        if (threadIdx.x < 64) {
            const int u = u0 + (int)threadIdx.x;
            if (u < n_users) offs_u[u] = bstart + off[threadIdx.x];
        }
        if (b == nbu - 1 && threadIdx.x == 0) offs_u[n_users] = bend;
        for (int i = bstart + (int)threadIdx.x; i < bend; i += blockDim.x) {
            const uint2 cv = pcode_u[i];
            const int lr = (int)(cv.x >> 17) & 63;
            const int pos = bstart + off[lr] + atomicAdd(&cur[lr], 1);
            uint2 o;
            o.x = cv.x & 0x1FFFFu;
            o.y = cv.y;
            upack[pos] = o;
        }
    }
}

// =========================================================================
// bf16 gather kernels v3 (R22-proven): 8 lanes/row x uint4, x2 unroll
// =========================================================================
__global__ void kg_gather_bf_kernel(const ushort_t* __restrict__ ebf,
                                    const int* __restrict__ sorted_tr,
                                    const int* __restrict__ offs,
                                    const float* __restrict__ weight,
                                    float* __restrict__ out_ent,
                                    int n_entities, int n_rel) {
    extern __shared__ float wl[];   // n_rel * CH
    for (int i = threadIdx.x; i < n_rel * CH; i += blockDim.x) wl[i] = weight[i];
    __syncthreads();
    const float4* wl4 = reinterpret_cast<const float4*>(wl);

    const int wid  = (blockIdx.x * blockDim.x + threadIdx.x) >> 6;
    const int lane = threadIdx.x & 63;
    const int g    = lane >> 3;     // edge slot 0..7
    const int q8   = lane & 7;      // channel octet 0..7
    if (wid >= n_entities) return;

    const int s0 = offs[wid], s1 = offs[wid + 1];
    float a0[8], a1[8];
#pragma unroll
    for (int j = 0; j < 8; ++j) { a0[j] = 0.f; a1[j] = 0.f; }

    int base = s0;
    for (; base + 16 <= s1; base += 16) {
        const int tr0 = sorted_tr[base + g];
        const int tr1 = sorted_tr[base + 8 + g];
        const uint4 p0 = *reinterpret_cast<const uint4*>(
            ebf + (size_t)(tr0 & 0x1FFFF) * CH + q8 * 8);
        const uint4 p1 = *reinterpret_cast<const uint4*>(
            ebf + (size_t)(tr1 & 0x1FFFF) * CH + q8 * 8);
        const float4 w0a = wl4[(tr0 >> 17) * 16 + q8 * 2];
        const float4 w0b = wl4[(tr0 >> 17) * 16 + q8 * 2 + 1];
        const float4 w1a = wl4[(tr1 >> 17) * 16 + q8 * 2];
        const float4 w1b = wl4[(tr1 >> 17) * 16 + q8 * 2 + 1];
        a0[0] = fmaf(bf_lo(p0.x), w0a.x, a0[0]);
        a0[1] = fmaf(bf_hi(p0.x), w0a.y, a0[1]);
        a0[2] = fmaf(bf_lo(p0.y), w0a.z, a0[2]);
        a0[3] = fmaf(bf_hi(p0.y), w0a.w, a0[3]);
        a0[4] = fmaf(bf_lo(p0.z), w0b.x, a0[4]);
        a0[5] = fmaf(bf_hi(p0.z), w0b.y, a0[5]);
        a0[6] = fmaf(bf_lo(p0.w), w0b.z, a0[6]);
        a0[7] = fmaf(bf_hi(p0.w), w0b.w, a0[7]);
        a1[0] = fmaf(bf_lo(p1.x), w1a.x, a1[0]);
        a1[1] = fmaf(bf_hi(p1.x), w1a.y, a1[1]);
        a1[2] = fmaf(bf_lo(p1.y), w1a.z, a1[2]);
        a1[3] = fmaf(bf_hi(p1.y), w1a.w, a1[3]);
        a1[4] = fmaf(bf_lo(p1.z), w1b.x, a1[4]);
        a1[5] = fmaf(bf_hi(p1.z), w1b.y, a1[5]);
        a1[6] = fmaf(bf_lo(p1.w), w1b.z, a1[6]);
        a1[7] = fmaf(bf_hi(p1.w), w1b.w, a1[7]);
    }
    for (; base < s1; base += 8) {
        const int e = base + g;
        const bool valid = (e < s1);
        const int tr = valid ? sorted_tr[e] : 0;
        uint4 p; p.x = 0u; p.y = 0u; p.z = 0u; p.w = 0u;
        if (valid)
            p = *reinterpret_cast<const uint4*>(
                ebf + (size_t)(tr & 0x1FFFF) * CH + q8 * 8);
        const float4 wa = wl4[(tr >> 17) * 16 + q8 * 2];
        const float4 wb = wl4[(tr >> 17) * 16 + q8 * 2 + 1];
        a0[0] = fmaf(bf_lo(p.x), wa.x, a0[0]);
        a0[1] = fmaf(bf_hi(p.x), wa.y, a0[1]);
        a0[2] = fmaf(bf_lo(p.y), wa.z, a0[2]);
        a0[3] = fmaf(bf_hi(p.y), wa.w, a0[3]);
        a0[4] = fmaf(bf_lo(p.z), wb.x, a0[4]);
        a0[5] = fmaf(bf_hi(p.z), wb.y, a0[5]);
        a0[6] = fmaf(bf_lo(p.w), wb.z, a0[6]);
        a0[7] = fmaf(bf_hi(p.w), wb.w, a0[7]);
    }
#pragma unroll
    for (int j = 0; j < 8; ++j) a0[j] += a1[j];

#pragma unroll
    for (int j = 0; j < 8; ++j) {
        a0[j] += __shfl_xor(a0[j], 8);
        a0[j] += __shfl_xor(a0[j], 16);
        a0[j] += __shfl_xor(a0[j], 32);
    }

    if (g == 0) {
        const int deg = s1 - s0;
        const float inv = 1.0f / (float)(deg > 0 ? deg : 1);
        float4 o0, o1;
        o0.x = a0[0] * inv; o0.y = a0[1] * inv; o0.z = a0[2] * inv; o0.w = a0[3] * inv;
        o1.x = a0[4] * inv; o1.y = a0[5] * inv; o1.z = a0[6] * inv; o1.w = a0[7] * inv;
        float* op = out_ent + (size_t)wid * CH + q8 * 8;
        *reinterpret_cast<float4*>(op)     = o0;
        *reinterpret_cast<float4*>(op + 4) = o1;
    }
}

__global__ void user_gather_bf_kernel(const ushort_t* __restrict__ ebf,
                                      const uint2* __restrict__ upack,
                                      const int* __restrict__ offs,
                                      float* __restrict__ out_user,
                                      int n_users) {
    const int wid  = (blockIdx.x * blockDim.x + threadIdx.x) >> 6;
    const int lane = threadIdx.x & 63;
    const int g    = lane >> 3;
    const int q8   = lane & 7;
    if (wid >= n_users) return;

    const int s0 = offs[wid], s1 = offs[wid + 1];
    float a0[8], a1[8];
#pragma unroll
    for (int j = 0; j < 8; ++j) { a0[j] = 0.f; a1[j] = 0.f; }

    int base = s0;
    for (; base + 16 <= s1; base += 16) {
        const uint2 cv0 = upack[base + g];
        const uint2 cv1 = upack[base + 8 + g];
        const float v0 = __uint_as_float(cv0.y);
        const float v1 = __uint_as_float(cv1.y);
        const uint4 p0 = *reinterpret_cast<const uint4*>(
            ebf + (size_t)cv0.x * CH + q8 * 8);
        const uint4 p1 = *reinterpret_cast<const uint4*>(
            ebf + (size_t)cv1.x * CH + q8 * 8);
        a0[0] = fmaf(v0, bf_lo(p0.x), a0[0]);
        a0[1] = fmaf(v0, bf_hi(p0.x), a0[1]);
        a0[2] = fmaf(v0, bf_lo(p0.y), a0[2]);
        a0[3] = fmaf(v0, bf_hi(p0.y), a0[3]);
        a0[4] = fmaf(v0, bf_lo(p0.z), a0[4]);
        a0[5] = fmaf(v0, bf_hi(p0.z), a0[5]);
        a0[6] = fmaf(v0, bf_lo(p0.w), a0[6]);
        a0[7] = fmaf(v0, bf_hi(p0.w), a0[7]);
        a1[0] = fmaf(v1, bf_lo(p1.x), a1[0]);
        a1[1] = fmaf(v1, bf_hi(p1.x), a1[1]);
        a1[2] = fmaf(v1, bf_lo(p1.y), a1[2]);
        a1[3] = fmaf(v1, bf_hi(p1.y), a1[3]);
        a1[4] = fmaf(v1, bf_lo(p1.z), a1[4]);
        a1[5] = fmaf(v1, bf_hi(p1.z), a1[5]);
        a1[6] = fmaf(v1, bf_lo(p1.w), a1[6]);
        a1[7] = fmaf(v1, bf_hi(p1.w), a1[7]);
    }
    for (; base < s1; base += 8) {
        const int e = base + g;
        const bool valid = (e < s1);
        uint2 cv; cv.x = 0u; cv.y = 0u;
        if (valid) cv = upack[e];
        const float v = __uint_as_float(cv.y);   // 0 when invalid
        const uint4 p = *reinterpret_cast<const uint4*>(
            ebf + (size_t)cv.x * CH + q8 * 8);   // row 0 valid memory
        a0[0] = fmaf(v, bf_lo(p.x), a0[0]);
        a0[1] = fmaf(v, bf_hi(p.x), a0[1]);
        a0[2] = fmaf(v, bf_lo(p.y), a0[2]);
        a0[3] = fmaf(v, bf_hi(p.y), a0[3]);
        a0[4] = fmaf(v, bf_lo(p.z), a0[4]);
        a0[5] = fmaf(v, bf_hi(p.z), a0[5]);
        a0[6] = fmaf(v, bf_lo(p.w), a0[6]);
        a0[7] = fmaf(v, bf_hi(p.w), a0[7]);
    }
#pragma unroll
    for (int j = 0; j < 8; ++j) a0[j] += a1[j];

#pragma unroll
    for (int j = 0; j < 8; ++j) {
        a0[j] += __shfl_xor(a0[j], 8);
        a0[j] += __shfl_xor(a0[j], 16);
        a0[j] += __shfl_xor(a0[j], 32);
    }

    if (g == 0) {
        float4 o0, o1;
        o0.x = a0[0]; o0.y = a0[1]; o0.z = a0[2]; o0.w = a0[3];
        o1.x = a0[4]; o1.y = a0[5]; o1.z = a0[6]; o1.w = a0[7];
        float* op = out_user + (size_t)wid * CH + q8 * 8;
        *reinterpret_cast<float4*>(op)     = o0;
        *reinterpret_cast<float4*>(op + 4) = o1;
    }
}

// =========================================================================
// Tier-2 (R14 CSR path): sliced hist/scatter
// =========================================================================
__global__ void hist_sliced_kernel(const int* __restrict__ keys,
                                   int* __restrict__ counts, int n, unsigned smul) {
    const int slice = blockIdx.x & (NSLICE - 1);
    const int rb    = blockIdx.x >> 3;
    const int nrb   = gridDim.x >> 3;
    const int per   = (n + nrb - 1) / nrb;
    const int i0    = rb * per;
    const int i1    = min(i0 + per, n);
    for (int i = i0 + (int)threadIdx.x; i < i1; i += blockDim.x) {
        const int k = keys[i];
        if ((int)__umulhi((unsigned)k, smul) == slice)
            atomicAdd(&counts[k], 1);
    }
}

__global__ void scatter_e_sliced_kernel(const int* __restrict__ edge_index,
                                        const int* __restrict__ edge_type,
                                        const int* __restrict__ offs,
                                        int* __restrict__ cursor,
                                        int* __restrict__ sorted_tr,
                                        int E, int n_rel, unsigned smul) {
    const int slice = blockIdx.x & (NSLICE - 1);
    const int rb    = blockIdx.x >> 3;
    const int nrb   = gridDim.x >> 3;
    const int per   = (E + nrb - 1) / nrb;
    const int e0    = rb * per;
    const int e1    = min(e0 + per, E);
    for (int e = e0 + (int)threadIdx.x; e < e1; e += blockDim.x) {
        const int h = edge_index[e];
        if ((int)__umulhi((unsigned)h, smul) != slice) continue;
        const int t = edge_index[(size_t)E + e];
        int r = edge_type[e] - 1;
        if (r < 0) r += n_rel;
        const int pos = offs[h] + atomicAdd(&cursor[h], 1);
        sorted_tr[pos] = t | (r << 17);
    }
}

__global__ void scatter_u_sliced_kernel(const int* __restrict__ irows,
                                        const int* __restrict__ icols,
                                        const float* __restrict__ ivals,
                                        const int* __restrict__ offs,
                                        int* __restrict__ cursor,
                                        uint2* __restrict__ upack,
                                        int NNZ, unsigned smul) {
    const int slice = blockIdx.x & (NSLICE - 1);
    const int rb    = blockIdx.x >> 3;
    const int nrb   = gridDim.x >> 3;
    const int per   = (NNZ + nrb - 1) / nrb;
    const int i0    = rb * per;
    const int i1    = min(i0 + per, NNZ);
    for (int i = i0 + (int)threadIdx.x; i < i1; i += blockDim.x) {
        const int u = irows[i];
        if ((int)__umulhi((unsigned)u, smul) != slice) continue;
        const int pos = offs[u] + atomicAdd(&cursor[u], 1);
        uint2 cv;
        cv.x = (unsigned)icols[i];
        cv.y = __float_as_uint(ivals[i]);
        upack[pos] = cv;
    }
}

// =========================================================================
// Tier-3 (atomic fallback)
// =========================================================================
__global__ void kg_agg_atomic_kernel(const float* __restrict__ emb,
                                     const float* __restrict__ region_ent,
                                     const int* __restrict__ edge_index,
                                     const int* __restrict__ edge_type,
                                     const float* __restrict__ weight,
                                     float* __restrict__ out_ent,
                                     float* __restrict__ counts,
                                     int E, int n_rel) {
    const long long gid = (long long)blockIdx.x * blockDim.x + threadIdx.x;
    const long long e = gid >> 6;
    if (e >= E) return;
    const int c = (int)gid & 63;
    const int h = edge_index[e];
    const int t = edge_index[(size_t)E + e];
    int r = edge_type[e] - 1;
    if (r < 0) r += n_rel;
    const float v = ent_val(emb, region_ent, t, c) * weight[(size_t)r * CH + c];
    unsafeAtomicAdd(out_ent + (size_t)h * CH + c, v);
    if (c == 0) unsafeAtomicAdd(counts + h, 1.0f);
}

__global__ void user_agg_atomic_kernel(const float* __restrict__ emb,
                                       const float* __restrict__ region_ent,
                                       const int* __restrict__ irows,
                                       const int* __restrict__ icols,
                                       const float* __restrict__ ivals,
                                       float* __restrict__ out_user, int NNZ) {
    const long long gid = (long long)blockIdx.x * blockDim.x + threadIdx.x;
    const long long i = gid >> 6;
    if (i >= NNZ) return;
    const int c = (int)gid & 63;
    const float v = ivals[i] * ent_val(emb, region_ent, icols[i], c);
    unsafeAtomicAdd(out_user + (size_t)irows[i] * CH + c, v);
}

__global__ void finalize_kernel(float* __restrict__ out_ent,
                                const float* __restrict__ counts, int n_entities) {
    const int gid = blockIdx.x * blockDim.x + threadIdx.x;
    if (gid >= n_entities * CH) return;
    out_ent[gid] /= fmaxf(counts[gid >> 6], 1.0f);
}

// =========================================================================
extern "C" void kernel_launch(void* const* d_in, const int* in_sizes, int n_in,
                              void* d_out, int out_size, void* d_ws, size_t ws_size,
                              hipStream_t stream) {
    const float* entity_emb = (const float*)d_in[0];
    const int*   edge_index = (const int*)d_in[2];
    const int*   edge_type  = (const int*)d_in[3];
    const int*   irows      = (const int*)d_in[4];
    const int*   icols      = (const int*)d_in[5];
    const float* ivals      = (const float*)d_in[6];
    const float* Wreg       = (const float*)d_in[7];
    const float* weight     = (const float*)d_in[8];

    const int n_entities = in_sizes[0] / CH;
    const int n_users    = in_sizes[1] / CH;
    const int E          = in_sizes[3];
    const int NNZ        = in_sizes[4];
    const int n_rel      = in_sizes[8] / CH;

    float* out_ent  = (float*)d_out;
    float* out_user = out_ent + (size_t)n_entities * CH;

    const int NBUK_E = (n_entities + 63) >> 6;
    const int NBUK_U = (n_users + 63) >> 6;
    const int n_e = NBUK_E * NB;
    const int n_u = NBUK_U * NB;
    const int nbse = (n_e + SCAN_B - 1) / SCAN_B;
    const int nbsu = (n_u + SCAN_B - 1) / SCAN_B;

    // ---- tier-1 (bucket) layout ----
    char* w = (char*)d_ws;
    auto take = [&](size_t bytes) {
        char* p = w;
        w += (bytes + 7) & ~(size_t)7;
        return p;
    };
    float*    region_ent = (float*)take((size_t)RN * CH * 4);
    ushort_t* e_t        = (ushort_t*)take((size_t)CH * KP * 2);
    ushort_t* ebf        = (ushort_t*)take((size_t)n_entities * CH * 2);
    int*      sorted_tr  = (int*)take((size_t)E * 4);
    uint2*    upack      = (uint2*)take((size_t)NNZ * 8);
    int*      offs_e     = (int*)take((size_t)(n_entities + 1) * 4);
    int*      offs_u     = (int*)take((size_t)(n_users + 1) * 4);
    int*      bsums      = (int*)take(512 * 4);
    int*      hist_e     = (int*)take((size_t)n_e * 4);
    int*      exbase_e   = (int*)take((size_t)(n_e + 1) * 4);
    int*      hist_u     = (int*)take((size_t)n_u * 4);
    int*      exbase_u   = (int*)take((size_t)(n_u + 1) * 4);
    int*      pcode_e    = (int*)take((size_t)E * 4);
    uint2*    pcode_u    = (uint2*)take((size_t)NNZ * 8);
    const size_t need_bucket = (size_t)(w - (char*)d_ws);

    const bool common_ok = (n_entities < (1 << 17)) && (n_rel <= 32);
    const bool use_bucket = common_ok && (ws_size >= need_bucket) &&
                            (NBUK_E <= MAXBUK) && (NBUK_U <= MAXBUK) &&
                            (nbse <= 512) && (nbsu <= 512);

    // ---- tier-2 (csr) layout ----
    char* w2 = (char*)d_ws;
    auto take2 = [&](size_t bytes) {
        char* p = w2;
        w2 += (bytes + 7) & ~(size_t)7;
        return p;
    };
    float*    c_region  = (float*)take2((size_t)RN * CH * 4);
    int*      c_offs_e  = (int*)take2((size_t)(n_entities + 1) * 4);
    int*      c_cur_e   = (int*)take2((size_t)n_entities * 4);
    int*      c_offs_u  = (int*)take2((size_t)(n_users + 1) * 4);
    int*      c_cur_u   = (int*)take2((size_t)n_users * 4);
    int*      c_bsums   = (int*)take2(512 * 4);
    int*      c_sorted  = (int*)take2((size_t)E * 4);
    uint2*    c_upack   = (uint2*)take2((size_t)NNZ * 8);
    ushort_t* c_et      = (ushort_t*)take2((size_t)CH * KP * 2);
    ushort_t* c_ebf     = (ushort_t*)take2((size_t)n_entities * CH * 2);
    const size_t need_csr = (size_t)(w2 - (char*)d_ws);
    const int nb_e = (n_entities + SCAN_B - 1) / SCAN_B;
    const int nb_u = (n_users + SCAN_B - 1) / SCAN_B;
    const bool use_csr = common_ok && (ws_size >= need_csr) &&
                         (nb_e <= 512) && (nb_u <= 512);

    if (use_bucket) {
        region_init_kernel<<<(RN * CH / 4 + 255) / 256, 256, 0, stream>>>(entity_emb, region_ent);
        {
            const int tot = CH * (KP / 8);
            build_et_kernel<<<(tot + 255) / 256, 256, 0, stream>>>(entity_emb, e_t);
        }
        region_gemm_mfma_kernel<<<MT_BLKS * KCHUNKS, 256, 0, stream>>>(
            Wreg, e_t, region_ent);
        {
            const int tot = n_entities * (CH / 8);
            build_ebf_kernel<<<(tot + 255) / 256, 256, 0, stream>>>(
                entity_emb, region_ent, ebf, n_entities);
        }

        bucket_hist2_kernel<<<2 * NB, T1, 0, stream>>>(
            edge_index, E, NBUK_E, irows, NNZ, NBUK_U, hist_e, hist_u);

        scan_block_kernel<<<nbse, SCAN_B, 0, stream>>>(hist_e, exbase_e, bsums, n_e);
        scan_top_kernel<<<1, 512, 0, stream>>>(bsums, nbse);
        scan_add_kernel<<<nbse, SCAN_B, 0, stream>>>(exbase_e, bsums, n_e);

        scan_block_kernel<<<nbsu, SCAN_B, 0, stream>>>(hist_u, exbase_u, bsums, n_u);
        scan_top_kernel<<<1, 512, 0, stream>>>(bsums, nbsu);
        scan_add_kernel<<<nbsu, SCAN_B, 0, stream>>>(exbase_u, bsums, n_u);

        pass2_combined_kernel<<<2 * NB, T1, 0, stream>>>(
            edge_index, edge_type, exbase_e, pcode_e, E, n_rel, NBUK_E,
            irows, icols, ivals, exbase_u, pcode_u, NNZ, NBUK_U);

        bucket_sort2_kernel<<<NBUK_E + NBUK_U, 256, 0, stream>>>(
            pcode_e, exbase_e, sorted_tr, offs_e, n_entities, NBUK_E,
            pcode_u, exbase_u, upack, offs_u, n_users, NBUK_U);

        kg_gather_bf_kernel<<<(n_entities + 3) / 4, 256, n_rel * CH * 4, stream>>>(
            ebf, sorted_tr, offs_e, weight, out_ent, n_entities, n_rel);
        user_gather_bf_kernel<<<(n_users + 3) / 4, 256, 0, stream>>>(
            ebf, upack, offs_u, out_user, n_users);
    } else if (use_csr) {
        const unsigned smul_e = (unsigned)((8ULL << 32) / (unsigned long long)n_entities);
        const unsigned smul_u = (unsigned)((8ULL << 32) / (unsigned long long)n_users);

        region_init_kernel<<<(RN * CH / 4 + 255) / 256, 256, 0, stream>>>(entity_emb, c_region);
        {
            const int tot = CH * (KP / 8);
            build_et_kernel<<<(tot + 255) / 256, 256, 0, stream>>>(entity_emb, c_et);
        }
        region_gemm_mfma_kernel<<<MT_BLKS * KCHUNKS, 256, 0, stream>>>(
            Wreg, c_et, c_region);
        {
            const int tot = n_entities * (CH / 8);
            build_ebf_kernel<<<(tot + 255) / 256, 256, 0, stream>>>(
                entity_emb, c_region, c_ebf, n_entities);
        }

        hipMemsetAsync(c_cur_e, 0, (size_t)n_entities * 4, stream);
        hipMemsetAsync(c_cur_u, 0, (size_t)n_users * 4, stream);
        hist_sliced_kernel<<<NSLICE * SLICE_RB, 256, 0, stream>>>(
            edge_index, c_cur_e, E, smul_e);
        hist_sliced_kernel<<<NSLICE * SLICE_RB, 256, 0, stream>>>(
            irows, c_cur_u, NNZ, smul_u);

        scan_block_kernel<<<nb_e, SCAN_B, 0, stream>>>(c_cur_e, c_offs_e, c_bsums, n_entities);
        scan_top_kernel<<<1, 512, 0, stream>>>(c_bsums, nb_e);
        scan_add_kernel<<<nb_e, SCAN_B, 0, stream>>>(c_offs_e, c_bsums, n_entities);

        scan_block_kernel<<<nb_u, SCAN_B, 0, stream>>>(c_cur_u, c_offs_u, c_bsums, n_users);
        scan_top_kernel<<<1, 512, 0, stream>>>(c_bsums, nb_u);
        scan_add_kernel<<<nb_u, SCAN_B, 0, stream>>>(c_offs_u, c_bsums, n_users);

        hipMemsetAsync(c_cur_e, 0, (size_t)n_entities * 4, stream);
        hipMemsetAsync(c_cur_u, 0, (size_t)n_users * 4, stream);
        scatter_e_sliced_kernel<<<NSLICE * SLICE_RB, 256, 0, stream>>>(
            edge_index, edge_type, c_offs_e, c_cur_e, c_sorted, E, n_rel, smul_e);
        scatter_u_sliced_kernel<<<NSLICE * SLICE_RB, 256, 0, stream>>>(
            irows, icols, ivals, c_offs_u, c_cur_u, c_upack, NNZ, smul_u);

        kg_gather_bf_kernel<<<(n_entities + 3) / 4, 256, n_rel * CH * 4, stream>>>(
            c_ebf, c_sorted, c_offs_e, weight, out_ent, n_entities, n_rel);
        user_gather_bf_kernel<<<(n_users + 3) / 4, 256, 0, stream>>>(
            c_ebf, c_upack, c_offs_u, out_user, n_users);
    } else {
        // tier-3: atomic fallback
        float* region3 = (float*)d_ws;
        float* counts  = region3 + (size_t)RN * CH;
        region_init_kernel<<<(RN * CH / 4 + 255) / 256, 256, 0, stream>>>(entity_emb, region3);
        region_gemm_kernel<<<ROW_TILES * KSPLIT, 256, 0, stream>>>(
            entity_emb, Wreg, region3);
        hipMemsetAsync(d_out, 0, (size_t)out_size * sizeof(float), stream);
        hipMemsetAsync(counts, 0, (size_t)n_entities * sizeof(float), stream);
        {
            const long long tot = (long long)E * CH;
            kg_agg_atomic_kernel<<<(int)((tot + 255) / 256), 256, 0, stream>>>(
                entity_emb, region3, edge_index, edge_type, weight,
                out_ent, counts, E, n_rel);
        }
        {
            const long long tot = (long long)NNZ * CH;
            user_agg_atomic_kernel<<<(int)((tot + 255) / 256), 256, 0, stream>>>(
                entity_emb, region3, irows, icols, ivals, out_user, NNZ);
        }
        finalize_kernel<<<(n_entities * CH + 255) / 256, 256, 0, stream>>>(
            out_ent, counts, n_entities);
    }
}